// Round 2
// baseline (12381.287 us; speedup 1.0000x reference)
//
#include <hip/hip_runtime.h>
#include <math.h>

#define FLAG_ACC  1
#define FLAG_RELU 2
#define FLAG_GELU 4

// ---------------- generic fp32 tiled GEMM: C[M,N] = A[M,K] @ B[K,N] ----------------
// a_shift: virtual C-row r reads A row (r + a_shift); OOB rows load 0 (conv shifts).
// gridDim.z > 1 => split-K partials atomicAdd'ed into pre-initialized C (flags ignored).
__global__ __launch_bounds__(256) void gemm_f32(
    const float* __restrict__ A, const float* __restrict__ B, float* __restrict__ C,
    int M, int N, int K, int a_shift,
    const float* __restrict__ bias, const float* __restrict__ residual, int flags)
{
  __shared__ float As[16][65];   // [k][m], padded
  __shared__ float Bs[16][64];   // [k][n]
  const int tid = threadIdx.x;
  const int tx = tid & 15, ty = tid >> 4;
  const int row0 = blockIdx.y * 64;
  const int col0 = blockIdx.x * 64;
  int kbeg = 0, kend = K;
  if ((int)gridDim.z > 1) {
    int kchunk = ((K + (int)gridDim.z - 1) / (int)gridDim.z + 15) & ~15;
    kbeg = (int)blockIdx.z * kchunk;
    kend = min(K, kbeg + kchunk);
  }
  float acc[4][4] = {};
  const int a_m = tid >> 2;
  const int a_k = (tid & 3) << 2;
  const int b_n = (tid & 15) << 2;
  const int b_k = tid >> 4;
  for (int k0 = kbeg; k0 < kend; k0 += 16) {
    int srow = row0 + a_m + a_shift;
    float4 av = make_float4(0.f, 0.f, 0.f, 0.f);
    if (srow >= 0 && srow < M)
      av = *reinterpret_cast<const float4*>(A + (long long)srow * K + (k0 + a_k));
    As[a_k + 0][a_m] = av.x; As[a_k + 1][a_m] = av.y;
    As[a_k + 2][a_m] = av.z; As[a_k + 3][a_m] = av.w;
    float4 bv = make_float4(0.f, 0.f, 0.f, 0.f);
    int brow = k0 + b_k;
    if (brow < K)
      bv = *reinterpret_cast<const float4*>(B + (long long)brow * N + (col0 + b_n));
    Bs[b_k][b_n + 0] = bv.x; Bs[b_k][b_n + 1] = bv.y;
    Bs[b_k][b_n + 2] = bv.z; Bs[b_k][b_n + 3] = bv.w;
    __syncthreads();
#pragma unroll
    for (int kk = 0; kk < 16; kk++) {
      float ar[4], br[4];
#pragma unroll
      for (int i = 0; i < 4; i++) ar[i] = As[kk][ty * 4 + i];
#pragma unroll
      for (int j = 0; j < 4; j++) br[j] = Bs[kk][tx * 4 + j];
#pragma unroll
      for (int i = 0; i < 4; i++)
#pragma unroll
        for (int j = 0; j < 4; j++)
          acc[i][j] += ar[i] * br[j];
    }
    __syncthreads();
  }
  if ((int)gridDim.z > 1) {
#pragma unroll
    for (int i = 0; i < 4; i++) {
      int r = row0 + ty * 4 + i; if (r >= M) continue;
#pragma unroll
      for (int j = 0; j < 4; j++) {
        int c = col0 + tx * 4 + j; if (c >= N) continue;
        atomicAdd(&C[(long long)r * N + c], acc[i][j]);
      }
    }
    return;
  }
#pragma unroll
  for (int i = 0; i < 4; i++) {
    int r = row0 + ty * 4 + i; if (r >= M) continue;
#pragma unroll
    for (int j = 0; j < 4; j++) {
      int c = col0 + tx * 4 + j; if (c >= N) continue;
      float v = acc[i][j];
      if (bias)     v += bias[c];
      if (residual) v += residual[(long long)r * N + c];
      if (flags & FLAG_ACC)  v += C[(long long)r * N + c];
      if (flags & FLAG_RELU) v = fmaxf(v, 0.f);
      if (flags & FLAG_GELU) v = 0.5f * v * (1.f + erff(v * 0.70710678118654752f));
      C[(long long)r * N + c] = v;
    }
  }
}

// ------------- conv weight re-layout: w[O=256][I][3] -> out[k][I][256] -------------
__global__ void convw_transpose(const float* __restrict__ w, float* __restrict__ out, int I)
{
  long long total = (long long)256 * I * 3;
  for (long long idx = blockIdx.x * 256LL + threadIdx.x; idx < total;
       idx += (long long)gridDim.x * 256LL) {
    int o = (int)(idx & 255);
    long long t = idx >> 8;
    int i = (int)(t % I);
    int kk = (int)(t / I);
    out[idx] = w[((long long)o * I + i) * 3 + kk];
  }
}

// ------------- generic transpose: in[R][Cc] -> out[Cc][R] -------------
__global__ void transpose_kernel(const float* __restrict__ in, float* __restrict__ out,
                                 int R, int Cc)
{
  long long total = (long long)R * Cc;
  for (long long i = blockIdx.x * 256LL + threadIdx.x; i < total;
       i += (long long)gridDim.x * 256LL) {
    int r = (int)(i / Cc), c = (int)(i % Cc);
    out[(long long)c * R + r] = in[i];
  }
}

// ------------- conv batch-boundary fixup: recompute rows l=0 and l=1023 -------------
__global__ void fixup_conv(float* __restrict__ h, const float* __restrict__ src,
                           const float* __restrict__ w, const float* __restrict__ bias,
                           int I, int do_relu)
{
  int b = blockIdx.x >> 1;
  int l = (blockIdx.x & 1) ? 1023 : 0;
  int o = threadIdx.x;   // 256 output channels
  float acc = bias[o];
  for (int kk = 0; kk < 3; kk++) {
    int t = l + kk - 1;
    if (t < 0 || t > 1023) continue;
    const float* srow = src + ((long long)b * 1024 + t) * I;
    const float* wrow = w + (long long)o * I * 3 + kk;
    for (int i = 0; i < I; i++) acc += srow[i] * wrow[(long long)i * 3];
  }
  if (do_relu) acc = fmaxf(acc, 0.f);
  h[((long long)b * 1024 + l) * 256 + o] = acc;
}

// ------------- LayerNorm over 256 channels (optional pre-ReLU, strided output) -------------
__global__ __launch_bounds__(256) void ln_rows(
    const float* __restrict__ in, float* __restrict__ out,
    const float* __restrict__ g, const float* __restrict__ b,
    int prerelu, int out_stride, int out_off)
{
  __shared__ float red[4];
  int row = blockIdx.x, tid = threadIdx.x;
  float x = in[(long long)row * 256 + tid];
  if (prerelu) x = fmaxf(x, 0.f);
  float s = x;
#pragma unroll
  for (int o = 32; o > 0; o >>= 1) s += __shfl_down(s, o, 64);
  if ((tid & 63) == 0) red[tid >> 6] = s;
  __syncthreads();
  float mean = (red[0] + red[1] + red[2] + red[3]) * (1.f / 256.f);
  float d = x - mean;
  float s2 = d * d;
#pragma unroll
  for (int o = 32; o > 0; o >>= 1) s2 += __shfl_down(s2, o, 64);
  __syncthreads();
  if ((tid & 63) == 0) red[tid >> 6] = s2;
  __syncthreads();
  float var = (red[0] + red[1] + red[2] + red[3]) * (1.f / 256.f);
  out[(long long)row * out_stride + out_off + tid] =
      d * rsqrtf(var + 1e-5f) * g[tid] + b[tid];
}

// ------------- series_decomp: out = in - moving_avg_25(replicate-pad) -------------
__global__ void decomp_kernel(const float* __restrict__ in, float* __restrict__ out)
{
  int idx = blockIdx.x * 256 + threadIdx.x;   // total 64*1024*256
  int c = idx & 255;
  int bl = idx >> 8;
  int l = bl & 1023;
  int bbase = (bl >> 10) << 18;               // b*1024*256
  const float* base = in + bbase + c;
  float s = 0.f;
#pragma unroll
  for (int j = -12; j <= 12; j++) {
    int t = l + j;
    t = t < 0 ? 0 : (t > 1023 ? 1023 : t);
    s += base[t << 8];
  }
  out[idx] = in[idx] - s * (1.f / 25.f);
}

// ------------- circular correlation mean: mv[b,tau] = (1/256) sum_t <q_t, k_(t-tau)> -------------
// grid (32 tau-tiles, 64 b), 256 threads. LDS ~48KB.
__global__ __launch_bounds__(256) void corr_mean(
    const float* __restrict__ q, const float* __restrict__ k, float* __restrict__ mv)
{
  __shared__ float qs[32][129];
  __shared__ float ks[63][129];
  int b = blockIdx.y;
  int tau0 = blockIdx.x * 32;
  int tid = threadIdx.x;
  int tsl = tid & 31;    // t within t-tile
  int gsl = tid >> 5;    // tau group (4 taus each)
  int rb = tsl - 4 * gsl + 31;   // band row for j=0
  float acc0 = 0.f, acc1 = 0.f, acc2 = 0.f, acc3 = 0.f;
  const float* qb = q + (long long)b * 1024 * 256;
  const float* kb = k + (long long)b * 1024 * 256;
  for (int t0 = 0; t0 < 1024; t0 += 32) {
    int base = t0 - tau0 - 31;
    for (int d0 = 0; d0 < 256; d0 += 128) {
      __syncthreads();
      // load q tile: 32 rows x 128 cols
#pragma unroll
      for (int u = 0; u < 16; u++) {
        int e = u * 256 + tid;
        int r = e >> 7, d = e & 127;
        qs[r][d] = qb[(long long)(t0 + r) * 256 + d0 + d];
      }
      // load k band: 63 rows x 128 cols
#pragma unroll
      for (int u = 0; u < 32; u++) {
        int e = u * 256 + tid;
        if (e < 63 * 128) {
          int r = e >> 7, d = e & 127;
          int ar = (base + r) & 1023;
          ks[r][d] = kb[(long long)ar * 256 + d0 + d];
        }
      }
      __syncthreads();
      const float* qrow = qs[tsl];
      const float* k0p = ks[rb];
      const float* k1p = ks[rb - 1];
      const float* k2p = ks[rb - 2];
      const float* k3p = ks[rb - 3];
      for (int d = 0; d < 128; d++) {
        float qv = qrow[d];
        acc0 += qv * k0p[d];
        acc1 += qv * k1p[d];
        acc2 += qv * k2p[d];
        acc3 += qv * k3p[d];
      }
    }
  }
#pragma unroll
  for (int o = 16; o > 0; o >>= 1) {
    acc0 += __shfl_xor(acc0, o, 64);
    acc1 += __shfl_xor(acc1, o, 64);
    acc2 += __shfl_xor(acc2, o, 64);
    acc3 += __shfl_xor(acc3, o, 64);
  }
  if ((tid & 31) == 0) {
    int tau = tau0 + 4 * gsl;
    float* o = mv + b * 1024 + tau;
    o[0] = acc0 * (1.f / 256.f);
    o[1] = acc1 * (1.f / 256.f);
    o[2] = acc2 * (1.f / 256.f);
    o[3] = acc3 * (1.f / 256.f);
  }
}

// ------------- top-20 + softmax per batch -------------
__global__ void topk_softmax(const float* __restrict__ mv, float* __restrict__ wts,
                             int* __restrict__ dly)
{
  __shared__ float vals[1024];
  __shared__ float lv[256];
  __shared__ int   li[256];
  __shared__ float selw[20];
  __shared__ int   seli[20];
  int b = blockIdx.x, tid = threadIdx.x;
#pragma unroll
  for (int u = 0; u < 4; u++) vals[u * 256 + tid] = mv[b * 1024 + u * 256 + tid];
  __syncthreads();
  for (int it = 0; it < 20; it++) {
    float bvv = -1e30f; int bi = 0;
#pragma unroll
    for (int u = 0; u < 4; u++) {
      int i2 = tid + u * 256;
      float v = vals[i2];
      if (v > bvv) { bvv = v; bi = i2; }
    }
    lv[tid] = bvv; li[tid] = bi;
    __syncthreads();
    if (tid == 0) {
      float best = -1e30f; int besti = 1 << 20;
      for (int u = 0; u < 256; u++) {
        if (lv[u] > best || (lv[u] == best && li[u] < besti)) { best = lv[u]; besti = li[u]; }
      }
      selw[it] = best; seli[it] = besti;
      vals[besti] = -1e30f;
    }
    __syncthreads();
  }
  if (tid == 0) {
    float mx = selw[0];
    float e[20], sum = 0.f;
    for (int i = 0; i < 20; i++) { e[i] = expf(selw[i] - mx); sum += e[i]; }
    float inv = 1.f / sum;
    for (int i = 0; i < 20; i++) { wts[b * 20 + i] = e[i] * inv; dly[b * 20 + i] = seli[i]; }
  }
}

// ------------- delay aggregation: out[b,l,:] = sum_k w_k * v[b,(l+d_k)%L,:] -------------
__global__ void agg_kernel(const float* __restrict__ v, const float* __restrict__ wts,
                           const int* __restrict__ dly, float* __restrict__ out)
{
  int b = blockIdx.y, l = blockIdx.x, tid = threadIdx.x;
  const float* vb = v + (long long)b * 1024 * 256;
  float acc = 0.f;
  for (int kk = 0; kk < 20; kk++) {
    int d = dly[b * 20 + kk];
    float w = wts[b * 20 + kk];
    acc += w * vb[(long long)((l + d) & 1023) * 256 + tid];
  }
  out[((long long)b * 1024 + l) * 256 + tid] = acc;
}

// ------------- small helpers -------------
__global__ void pool_copy(const float* __restrict__ enc, float* __restrict__ fin, int off)
{
  int b = blockIdx.x, tid = threadIdx.x;
  fin[(long long)b * 768 + off + tid] = enc[((long long)b * 1024 + 1023) * 256 + tid];
}

__global__ void init_bias(float* __restrict__ C, const float* __restrict__ bias)
{
  C[(long long)blockIdx.x * 256 + threadIdx.x] = bias[threadIdx.x];
}

__global__ void rp2_kernel(const float* __restrict__ x, const float* __restrict__ w,
                           const float* __restrict__ bias, float* __restrict__ out)
{
  __shared__ float red[4];
  int b = blockIdx.x, tid = threadIdx.x;
  float p = x[b * 256 + tid] * w[tid];
#pragma unroll
  for (int o = 32; o > 0; o >>= 1) p += __shfl_down(p, o, 64);
  if ((tid & 63) == 0) red[tid >> 6] = p;
  __syncthreads();
  if (tid == 0) out[b] = red[0] + red[1] + red[2] + red[3] + bias[0];
}

// =========================== host launch ===========================
static inline void gemm(hipStream_t s, const float* A, const float* B, float* C,
                        int M, int N, int K, int shift, const float* bias,
                        const float* res, int flags, int splitz = 1)
{
  dim3 g((N + 63) / 64, (M + 63) / 64, splitz);
  gemm_f32<<<g, dim3(256), 0, s>>>(A, B, C, M, N, K, shift, bias, res, flags);
}

extern "C" void kernel_launch(void* const* d_in, const int* in_sizes, int n_in,
                              void* d_out, int out_size, void* d_ws, size_t ws_size,
                              hipStream_t stream)
{
  const float* x_enc  = (const float*)d_in[0];
  const float* conv1_w= (const float*)d_in[1];
  const float* conv1_b= (const float*)d_in[2];
  const float* conv2_w= (const float*)d_in[3];
  const float* conv2_b= (const float*)d_in[4];
  const float* cnn_g  = (const float*)d_in[5];
  const float* cnn_b  = (const float*)d_in[6];
  const float* proj_w = (const float*)d_in[7];
  const float* proj_b = (const float*)d_in[8];
  const float* pln_g  = (const float*)d_in[9];
  const float* pln_b  = (const float*)d_in[10];
  const float* Wq     = (const float*)d_in[11];
  const float* bq     = (const float*)d_in[12];
  const float* Wk     = (const float*)d_in[13];
  const float* bk     = (const float*)d_in[14];
  const float* Wv     = (const float*)d_in[15];
  const float* bv     = (const float*)d_in[16];
  const float* Wo     = (const float*)d_in[17];
  const float* bo     = (const float*)d_in[18];
  const float* Wff1   = (const float*)d_in[19];
  const float* Wff2   = (const float*)d_in[20];
  const float* rp1_w  = (const float*)d_in[21];
  const float* rp1_b  = (const float*)d_in[22];
  const float* rln_g  = (const float*)d_in[23];
  const float* rln_b  = (const float*)d_in[24];
  const float* rp2_w  = (const float*)d_in[25];
  const float* rp2_b  = (const float*)d_in[26];
  (void)in_sizes; (void)n_in;

  // ---- workspace layout: 3 big [B*L,D] buffers + small extras (~197.4 MB) ----
  const size_t BLD = 64ull * 1024 * 256;   // 16,777,216 floats
  size_t need = 0;
  {
    size_t o = 3 * BLD + 2 * 262144 + 2 * 262144 + 3 * 16 * 256 + 3 * 256 * 256
             + 64 * 1024 + 64 * 20 + 64 * 20 + 64 * 256 + 64 * 768 + 64 * 256 + 64 * 256;
    need = o * sizeof(float);
  }
  if (ws_size < need) {
    // Workspace too small: emit zeros (diagnosable absmax failure, not a fault).
    hipMemsetAsync(d_out, 0, (size_t)out_size * sizeof(float), stream);
    return;
  }

  float* ws = (float*)d_ws;
  size_t off = 0;
  auto alloc = [&](size_t n) { float* p = ws + off; off += n; return p; };
  float* BUF0 = alloc(BLD);
  float* BUF1 = alloc(BLD);
  float* BUF2 = alloc(BLD);
  float* W1T  = alloc(2 * 262144);
  float* W2T  = alloc(2 * 262144);
  float* CB1  = alloc(3 * 16 * 256);
  float* CB2  = alloc(3 * 256 * 256);
  float* MV   = alloc(64 * 1024);
  float* WTS  = alloc(64 * 20);
  int*   DLY  = (int*)alloc(64 * 20);
  float* PE   = alloc(64 * 256);
  float* FIN  = alloc(64 * 768);
  float* O1   = alloc(64 * 256);
  float* O2   = alloc(64 * 256);

  const int M = 65536;   // B*L
  dim3 blk(256);

  // --- weight re-layouts (recomputed every call: ws is re-poisoned) ---
  convw_transpose<<<48, blk, 0, stream>>>(conv1_w, CB1, 16);
  convw_transpose<<<768, blk, 0, stream>>>(conv2_w, CB2, 256);
  for (int i = 0; i < 2; i++) {
    transpose_kernel<<<1024, blk, 0, stream>>>(Wff1 + (size_t)i * 262144, W1T + (size_t)i * 262144, 1024, 256);
    transpose_kernel<<<1024, blk, 0, stream>>>(Wff2 + (size_t)i * 262144, W2T + (size_t)i * 262144, 256, 1024);
  }

  // --- CNN frontend: x_enc -> BUF0 (conv1+relu) -> BUF1 (conv2+relu) -> BUF2 (LN) ---
  for (int kk = 0; kk < 3; kk++)
    gemm(stream, x_enc, CB1 + kk * 4096, BUF0, M, 256, 16, kk - 1,
         kk == 0 ? conv1_b : nullptr, nullptr,
         (kk == 0 ? 0 : FLAG_ACC) | (kk == 2 ? FLAG_RELU : 0));
  fixup_conv<<<128, blk, 0, stream>>>(BUF0, x_enc, conv1_w, conv1_b, 16, 1);
  for (int kk = 0; kk < 3; kk++)
    gemm(stream, BUF0, CB2 + kk * 65536, BUF1, M, 256, 256, kk - 1,
         kk == 0 ? conv2_b : nullptr, nullptr,
         (kk == 0 ? 0 : FLAG_ACC) | (kk == 2 ? FLAG_RELU : 0));
  fixup_conv<<<128, blk, 0, stream>>>(BUF1, BUF0, conv2_w, conv2_b, 256, 1);
  ln_rows<<<65536, blk, 0, stream>>>(BUF1, BUF2, cnn_g, cnn_b, 0, 256, 0);

  // --- encoder layers (enc lives in BUF2 at loop entry) ---
  for (int i = 0; i < 2; i++) {
    const float* Wq_i = Wq + (size_t)i * 65536;
    const float* Wk_i = Wk + (size_t)i * 65536;
    const float* Wv_i = Wv + (size_t)i * 65536;
    const float* Wo_i = Wo + (size_t)i * 65536;
    // q -> BUF0, k -> BUF1
    gemm(stream, BUF2, Wq_i, BUF0, M, 256, 256, 0, bq + i * 256, nullptr, 0);
    gemm(stream, BUF2, Wk_i, BUF1, M, 256, 256, 0, bk + i * 256, nullptr, 0);
    corr_mean<<<dim3(32, 64), blk, 0, stream>>>(BUF0, BUF1, MV);
    topk_softmax<<<64, blk, 0, stream>>>(MV, WTS, DLY);
    // v -> BUF0 (q dead), agg -> BUF1 (k dead)
    gemm(stream, BUF2, Wv_i, BUF0, M, 256, 256, 0, bv + i * 256, nullptr, 0);
    agg_kernel<<<dim3(1024, 64), blk, 0, stream>>>(BUF0, WTS, DLY, BUF1);
    // x = enc + ac@Wo + bo -> BUF0
    gemm(stream, BUF1, Wo_i, BUF0, M, 256, 256, 0, bo + i * 256, BUF2, 0);
    decomp_kernel<<<65536, blk, 0, stream>>>(BUF0, BUF1);   // xd -> BUF1; enc dead
    // FFN in 4 M-chunks: hidden (16384x1024) reuses BUF2; out chunks -> BUF0
    for (int c = 0; c < 4; c++) {
      const float* xd = BUF1 + (size_t)c * 16384 * 256;
      gemm(stream, xd, W1T + (size_t)i * 262144, BUF2, 16384, 1024, 256, 0,
           nullptr, nullptr, FLAG_GELU);
      gemm(stream, BUF2, W2T + (size_t)i * 262144, BUF0 + (size_t)c * 16384 * 256,
           16384, 256, 1024, 0, nullptr, xd, 0);
    }
    decomp_kernel<<<65536, blk, 0, stream>>>(BUF0, BUF2);   // new enc -> BUF2
    pool_copy<<<64, blk, 0, stream>>>(BUF2, FIN, i * 256);
  }

  // --- head ---
  init_bias<<<64, blk, 0, stream>>>(PE, proj_b);
  gemm(stream, x_enc, proj_w, PE, 64, 256, 16384, 0, nullptr, nullptr, 0, 32);
  ln_rows<<<64, blk, 0, stream>>>(PE, FIN, pln_g, pln_b, 1, 768, 512);
  init_bias<<<64, blk, 0, stream>>>(O1, rp1_b);
  gemm(stream, FIN, rp1_w, O1, 64, 256, 768, 0, nullptr, nullptr, 0, 4);
  ln_rows<<<64, blk, 0, stream>>>(O1, O2, rln_g, rln_b, 1, 256, 0);
  rp2_kernel<<<64, blk, 0, stream>>>(O2, rp2_w, rp2_b, (float*)d_out);
}

// Round 3
// 6764.381 us; speedup vs baseline: 1.8304x; 1.8304x over previous
//
#include <hip/hip_runtime.h>
#include <math.h>

#define FLAG_ACC  1
#define FLAG_RELU 2
#define FLAG_GELU 4

typedef __attribute__((ext_vector_type(8))) short short8;
typedef __attribute__((ext_vector_type(4))) float f32x4;

__device__ __forceinline__ short f2bf(float f) {
  unsigned u = __builtin_bit_cast(unsigned, f);
  unsigned r = u + 0x7fffu + ((u >> 16) & 1u);
  return (short)(r >> 16);
}

// ---------------- generic fp32 tiled GEMM: C[M,N] = A[M,K] @ B[K,N] ----------------
__global__ __launch_bounds__(256) void gemm_f32(
    const float* __restrict__ A, const float* __restrict__ B, float* __restrict__ C,
    int M, int N, int K, int a_shift,
    const float* __restrict__ bias, const float* __restrict__ residual, int flags)
{
  __shared__ float As[16][65];
  __shared__ float Bs[16][64];
  const int tid = threadIdx.x;
  const int tx = tid & 15, ty = tid >> 4;
  const int row0 = blockIdx.y * 64;
  const int col0 = blockIdx.x * 64;
  int kbeg = 0, kend = K;
  if ((int)gridDim.z > 1) {
    int kchunk = ((K + (int)gridDim.z - 1) / (int)gridDim.z + 15) & ~15;
    kbeg = (int)blockIdx.z * kchunk;
    kend = min(K, kbeg + kchunk);
  }
  float acc[4][4] = {};
  const int a_m = tid >> 2;
  const int a_k = (tid & 3) << 2;
  const int b_n = (tid & 15) << 2;
  const int b_k = tid >> 4;
  for (int k0 = kbeg; k0 < kend; k0 += 16) {
    int srow = row0 + a_m + a_shift;
    float4 av = make_float4(0.f, 0.f, 0.f, 0.f);
    if (srow >= 0 && srow < M)
      av = *reinterpret_cast<const float4*>(A + (long long)srow * K + (k0 + a_k));
    As[a_k + 0][a_m] = av.x; As[a_k + 1][a_m] = av.y;
    As[a_k + 2][a_m] = av.z; As[a_k + 3][a_m] = av.w;
    float4 bv = make_float4(0.f, 0.f, 0.f, 0.f);
    int brow = k0 + b_k;
    if (brow < K)
      bv = *reinterpret_cast<const float4*>(B + (long long)brow * N + (col0 + b_n));
    Bs[b_k][b_n + 0] = bv.x; Bs[b_k][b_n + 1] = bv.y;
    Bs[b_k][b_n + 2] = bv.z; Bs[b_k][b_n + 3] = bv.w;
    __syncthreads();
#pragma unroll
    for (int kk = 0; kk < 16; kk++) {
      float ar[4], br[4];
#pragma unroll
      for (int i = 0; i < 4; i++) ar[i] = As[kk][ty * 4 + i];
#pragma unroll
      for (int j = 0; j < 4; j++) br[j] = Bs[kk][tx * 4 + j];
#pragma unroll
      for (int i = 0; i < 4; i++)
#pragma unroll
        for (int j = 0; j < 4; j++)
          acc[i][j] += ar[i] * br[j];
    }
    __syncthreads();
  }
  if ((int)gridDim.z > 1) {
#pragma unroll
    for (int i = 0; i < 4; i++) {
      int r = row0 + ty * 4 + i; if (r >= M) continue;
#pragma unroll
      for (int j = 0; j < 4; j++) {
        int c = col0 + tx * 4 + j; if (c >= N) continue;
        atomicAdd(&C[(long long)r * N + c], acc[i][j]);
      }
    }
    return;
  }
#pragma unroll
  for (int i = 0; i < 4; i++) {
    int r = row0 + ty * 4 + i; if (r >= M) continue;
#pragma unroll
    for (int j = 0; j < 4; j++) {
      int c = col0 + tx * 4 + j; if (c >= N) continue;
      float v = acc[i][j];
      if (bias)     v += bias[c];
      if (residual) v += residual[(long long)r * N + c];
      if (flags & FLAG_ACC)  v += C[(long long)r * N + c];
      if (flags & FLAG_RELU) v = fmaxf(v, 0.f);
      if (flags & FLAG_GELU) v = 0.5f * v * (1.f + erff(v * 0.70710678118654752f));
      C[(long long)r * N + c] = v;
    }
  }
}

// ---------------- bf16 MFMA GEMM: C[M,N] = A[M,K] @ Bt[N,K]^T (+res)(gelu) ----------
// A, Bt fp32 in global; converted to bf16 (RNE) inline during LDS staging.
// M % 128 == 0, N % 128 == 0, K % 32 == 0 required.
__global__ __launch_bounds__(256) void gemm_bf16_bt(
    const float* __restrict__ A, const float* __restrict__ Bt, float* __restrict__ C,
    const float* __restrict__ residual, int M, int N, int K, int gelu)
{
  __shared__ short Asl[128][40];   // [m][k], +8 pad
  __shared__ short Bsl[128][40];   // [n][k]
  const int tid = threadIdx.x;
  const int row0 = blockIdx.y * 128;
  const int col0 = blockIdx.x * 128;
  const int lane = tid & 63;
  const int wave = tid >> 6;
  const int wm = (wave >> 1) * 64;
  const int wn = (wave & 1) * 64;
  const int fm = lane & 15;
  const int k8 = (lane >> 4) * 8;
  const int srow = tid >> 1;
  const int scol = (tid & 1) * 16;

  f32x4 acc[4][4] = {};
  for (int k0 = 0; k0 < K; k0 += 32) {
    __syncthreads();
    {
      const float* ga = A + (long long)(row0 + srow) * K + k0 + scol;
      const float* gb = Bt + (long long)(col0 + srow) * K + k0 + scol;
#pragma unroll
      for (int u = 0; u < 2; u++) {
        float4 f0 = *(const float4*)(ga + u * 8);
        float4 f1 = *(const float4*)(ga + u * 8 + 4);
        short8 v;
        v[0] = f2bf(f0.x); v[1] = f2bf(f0.y); v[2] = f2bf(f0.z); v[3] = f2bf(f0.w);
        v[4] = f2bf(f1.x); v[5] = f2bf(f1.y); v[6] = f2bf(f1.z); v[7] = f2bf(f1.w);
        *(short8*)&Asl[srow][scol + u * 8] = v;
        float4 g0 = *(const float4*)(gb + u * 8);
        float4 g1 = *(const float4*)(gb + u * 8 + 4);
        short8 w;
        w[0] = f2bf(g0.x); w[1] = f2bf(g0.y); w[2] = f2bf(g0.z); w[3] = f2bf(g0.w);
        w[4] = f2bf(g1.x); w[5] = f2bf(g1.y); w[6] = f2bf(g1.z); w[7] = f2bf(g1.w);
        *(short8*)&Bsl[srow][scol + u * 8] = w;
      }
    }
    __syncthreads();
    short8 af[4], bf[4];
#pragma unroll
    for (int i = 0; i < 4; i++) af[i] = *(short8*)&Asl[wm + i * 16 + fm][k8];
#pragma unroll
    for (int j = 0; j < 4; j++) bf[j] = *(short8*)&Bsl[wn + j * 16 + fm][k8];
#pragma unroll
    for (int i = 0; i < 4; i++)
#pragma unroll
      for (int j = 0; j < 4; j++)
        acc[i][j] = __builtin_amdgcn_mfma_f32_16x16x32_bf16(af[i], bf[j], acc[i][j], 0, 0, 0);
  }
  // epilogue: C/D layout col=lane&15, row=(lane>>4)*4+r
#pragma unroll
  for (int i = 0; i < 4; i++) {
    const int mbase = row0 + wm + i * 16 + (lane >> 4) * 4;
#pragma unroll
    for (int j = 0; j < 4; j++) {
      const int n = col0 + wn + j * 16 + (lane & 15);
#pragma unroll
      for (int r = 0; r < 4; r++) {
        long long idx = (long long)(mbase + r) * N + n;
        float v = acc[i][j][r];
        if (residual) v += residual[idx];
        if (gelu) v = 0.5f * v * (1.f + erff(v * 0.70710678118654752f));
        C[idx] = v;
      }
    }
  }
}

// ------------- conv weight re-layout: w[O=256][I][3] -> out[k][I][256] -------------
__global__ void convw_transpose(const float* __restrict__ w, float* __restrict__ out, int I)
{
  long long total = (long long)256 * I * 3;
  for (long long idx = blockIdx.x * 256LL + threadIdx.x; idx < total;
       idx += (long long)gridDim.x * 256LL) {
    int o = (int)(idx & 255);
    long long t = idx >> 8;
    int i = (int)(t % I);
    int kk = (int)(t / I);
    out[idx] = w[((long long)o * I + i) * 3 + kk];
  }
}

// ------------- conv batch-boundary fixup: recompute rows l=0 and l=1023 -------------
__global__ void fixup_conv(float* __restrict__ h, const float* __restrict__ src,
                           const float* __restrict__ w, const float* __restrict__ bias,
                           int I, int do_relu)
{
  int b = blockIdx.x >> 1;
  int l = (blockIdx.x & 1) ? 1023 : 0;
  int o = threadIdx.x;
  float acc = bias[o];
  for (int kk = 0; kk < 3; kk++) {
    int t = l + kk - 1;
    if (t < 0 || t > 1023) continue;
    const float* srow = src + ((long long)b * 1024 + t) * I;
    const float* wrow = w + (long long)o * I * 3 + kk;
    for (int i = 0; i < I; i++) acc += srow[i] * wrow[(long long)i * 3];
  }
  if (do_relu) acc = fmaxf(acc, 0.f);
  h[((long long)b * 1024 + l) * 256 + o] = acc;
}

// ------------- LayerNorm over 256 channels -------------
__global__ __launch_bounds__(256) void ln_rows(
    const float* __restrict__ in, float* __restrict__ out,
    const float* __restrict__ g, const float* __restrict__ b,
    int prerelu, int out_stride, int out_off)
{
  __shared__ float red[4];
  int row = blockIdx.x, tid = threadIdx.x;
  float x = in[(long long)row * 256 + tid];
  if (prerelu) x = fmaxf(x, 0.f);
  float s = x;
#pragma unroll
  for (int o = 32; o > 0; o >>= 1) s += __shfl_down(s, o, 64);
  if ((tid & 63) == 0) red[tid >> 6] = s;
  __syncthreads();
  float mean = (red[0] + red[1] + red[2] + red[3]) * (1.f / 256.f);
  float d = x - mean;
  float s2 = d * d;
#pragma unroll
  for (int o = 32; o > 0; o >>= 1) s2 += __shfl_down(s2, o, 64);
  __syncthreads();
  if ((tid & 63) == 0) red[tid >> 6] = s2;
  __syncthreads();
  float var = (red[0] + red[1] + red[2] + red[3]) * (1.f / 256.f);
  out[(long long)row * out_stride + out_off + tid] =
      d * rsqrtf(var + 1e-5f) * g[tid] + b[tid];
}

// ------------- series_decomp -------------
__global__ void decomp_kernel(const float* __restrict__ in, float* __restrict__ out)
{
  int idx = blockIdx.x * 256 + threadIdx.x;
  int c = idx & 255;
  int bl = idx >> 8;
  int l = bl & 1023;
  int bbase = (bl >> 10) << 18;
  const float* base = in + bbase + c;
  float s = 0.f;
#pragma unroll
  for (int j = -12; j <= 12; j++) {
    int t = l + j;
    t = t < 0 ? 0 : (t > 1023 ? 1023 : t);
    s += base[t << 8];
  }
  out[idx] = in[idx] - s * (1.f / 25.f);
}

// ------------- circular correlation mean, register-blocked -------------
// mv[b,tau] = (1/256) sum_t <q_t, k_(t-tau)>. Each thread: 4 t x 4 tau x float4 d.
// grid (16 tau-tiles of 64, 64 b), 256 threads. LDS ~50.7 KB.
__global__ __launch_bounds__(256) void corr_mean2(
    const float* __restrict__ q, const float* __restrict__ k, float* __restrict__ mv)
{
  __shared__ float qs[64][68];
  __shared__ float ks[127][68];
  const int b = blockIdx.y;
  const int tau0 = blockIdx.x * 64;
  const int tid = threadIdx.x;
  const int tg = tid & 15;         // t-group: rows tg*4..tg*4+3 of t-tile
  const int ug = tid >> 4;         // tau-group: taus ug*4..ug*4+3 of tau-tile
  const int rbase = 4 * (tg - ug) + 63;
  const float* qb = q + (long long)b * 262144;
  const float* kb = k + (long long)b * 262144;
  float acc[4][4] = {};
  for (int t0 = 0; t0 < 1024; t0 += 64) {
    const int base = t0 - tau0 - 63;
    for (int d0 = 0; d0 < 256; d0 += 64) {
      __syncthreads();
#pragma unroll
      for (int u = 0; u < 4; u++) {
        int idx = tid + u * 256;               // 64*16 float4
        int r = idx >> 4, c = (idx & 15) * 4;
        *(float4*)&qs[r][c] = *(const float4*)(qb + (long long)(t0 + r) * 256 + d0 + c);
      }
#pragma unroll
      for (int u = 0; u < 8; u++) {
        int idx = tid + u * 256;               // 127*16 float4
        if (idx < 2032) {
          int r = idx >> 4, c = (idx & 15) * 4;
          int ar = (base + r) & 1023;
          *(float4*)&ks[r][c] = *(const float4*)(kb + (long long)ar * 256 + d0 + c);
        }
      }
      __syncthreads();
      for (int d = 0; d < 64; d += 4) {
        float4 qv[4], kv[7];
#pragma unroll
        for (int i = 0; i < 4; i++) qv[i] = *(const float4*)&qs[tg * 4 + i][d];
#pragma unroll
        for (int s = 0; s < 7; s++) kv[s] = *(const float4*)&ks[rbase - 3 + s][d];
#pragma unroll
        for (int i = 0; i < 4; i++)
#pragma unroll
          for (int j = 0; j < 4; j++) {
            const float4 kvv = kv[i - j + 3];
            acc[i][j] += qv[i].x * kvv.x + qv[i].y * kvv.y
                       + qv[i].z * kvv.z + qv[i].w * kvv.w;
          }
      }
    }
  }
  float s[4];
#pragma unroll
  for (int j = 0; j < 4; j++) s[j] = acc[0][j] + acc[1][j] + acc[2][j] + acc[3][j];
#pragma unroll
  for (int off = 1; off < 16; off <<= 1) {
#pragma unroll
    for (int j = 0; j < 4; j++) s[j] += __shfl_xor(s[j], off, 64);
  }
  if (tg == 0) {
    float* o = mv + b * 1024 + tau0 + ug * 4;
#pragma unroll
    for (int j = 0; j < 4; j++) o[j] = s[j] * (1.f / 256.f);
  }
}

// ------------- top-20 + softmax per batch -------------
__global__ void topk_softmax(const float* __restrict__ mv, float* __restrict__ wts,
                             int* __restrict__ dly)
{
  __shared__ float vals[1024];
  __shared__ float lv[256];
  __shared__ int   li[256];
  __shared__ float selw[20];
  __shared__ int   seli[20];
  int b = blockIdx.x, tid = threadIdx.x;
#pragma unroll
  for (int u = 0; u < 4; u++) vals[u * 256 + tid] = mv[b * 1024 + u * 256 + tid];
  __syncthreads();
  for (int it = 0; it < 20; it++) {
    float bvv = -1e30f; int bi = 0;
#pragma unroll
    for (int u = 0; u < 4; u++) {
      int i2 = tid + u * 256;
      float v = vals[i2];
      if (v > bvv) { bvv = v; bi = i2; }
    }
    lv[tid] = bvv; li[tid] = bi;
    __syncthreads();
    if (tid == 0) {
      float best = -1e30f; int besti = 1 << 20;
      for (int u = 0; u < 256; u++) {
        if (lv[u] > best || (lv[u] == best && li[u] < besti)) { best = lv[u]; besti = li[u]; }
      }
      selw[it] = best; seli[it] = besti;
      vals[besti] = -1e30f;
    }
    __syncthreads();
  }
  if (tid == 0) {
    float mx = selw[0];
    float e[20], sum = 0.f;
    for (int i = 0; i < 20; i++) { e[i] = expf(selw[i] - mx); sum += e[i]; }
    float inv = 1.f / sum;
    for (int i = 0; i < 20; i++) { wts[b * 20 + i] = e[i] * inv; dly[b * 20 + i] = seli[i]; }
  }
}

// ------------- delay aggregation -------------
__global__ void agg_kernel(const float* __restrict__ v, const float* __restrict__ wts,
                           const int* __restrict__ dly, float* __restrict__ out)
{
  int b = blockIdx.y, l = blockIdx.x, tid = threadIdx.x;
  const float* vb = v + (long long)b * 1024 * 256;
  float acc = 0.f;
  for (int kk = 0; kk < 20; kk++) {
    int d = dly[b * 20 + kk];
    float w = wts[b * 20 + kk];
    acc += w * vb[(long long)((l + d) & 1023) * 256 + tid];
  }
  out[((long long)b * 1024 + l) * 256 + tid] = acc;
}

// ------------- small helpers -------------
__global__ void pool_copy(const float* __restrict__ enc, float* __restrict__ fin, int off)
{
  int b = blockIdx.x, tid = threadIdx.x;
  fin[(long long)b * 768 + off + tid] = enc[((long long)b * 1024 + 1023) * 256 + tid];
}

__global__ void init_bias(float* __restrict__ C, const float* __restrict__ bias)
{
  C[(long long)blockIdx.x * 256 + threadIdx.x] = bias[threadIdx.x];
}

__global__ void rp2_kernel(const float* __restrict__ x, const float* __restrict__ w,
                           const float* __restrict__ bias, float* __restrict__ out)
{
  __shared__ float red[4];
  int b = blockIdx.x, tid = threadIdx.x;
  float p = x[b * 256 + tid] * w[tid];
#pragma unroll
  for (int o = 32; o > 0; o >>= 1) p += __shfl_down(p, o, 64);
  if ((tid & 63) == 0) red[tid >> 6] = p;
  __syncthreads();
  if (tid == 0) out[b] = red[0] + red[1] + red[2] + red[3] + bias[0];
}

// =========================== host launch ===========================
static inline void gemm(hipStream_t s, const float* A, const float* B, float* C,
                        int M, int N, int K, int shift, const float* bias,
                        const float* res, int flags, int splitz = 1)
{
  dim3 g((N + 63) / 64, (M + 63) / 64, splitz);
  gemm_f32<<<g, dim3(256), 0, s>>>(A, B, C, M, N, K, shift, bias, res, flags);
}

extern "C" void kernel_launch(void* const* d_in, const int* in_sizes, int n_in,
                              void* d_out, int out_size, void* d_ws, size_t ws_size,
                              hipStream_t stream)
{
  const float* x_enc  = (const float*)d_in[0];
  const float* conv1_w= (const float*)d_in[1];
  const float* conv1_b= (const float*)d_in[2];
  const float* conv2_w= (const float*)d_in[3];
  const float* conv2_b= (const float*)d_in[4];
  const float* cnn_g  = (const float*)d_in[5];
  const float* cnn_b  = (const float*)d_in[6];
  const float* proj_w = (const float*)d_in[7];
  const float* proj_b = (const float*)d_in[8];
  const float* pln_g  = (const float*)d_in[9];
  const float* pln_b  = (const float*)d_in[10];
  const float* Wq     = (const float*)d_in[11];
  const float* bq     = (const float*)d_in[12];
  const float* Wk     = (const float*)d_in[13];
  const float* bk     = (const float*)d_in[14];
  const float* Wv     = (const float*)d_in[15];
  const float* bv     = (const float*)d_in[16];
  const float* Wo     = (const float*)d_in[17];
  const float* bo     = (const float*)d_in[18];
  const float* Wff1   = (const float*)d_in[19];
  const float* Wff2   = (const float*)d_in[20];
  const float* rp1_w  = (const float*)d_in[21];
  const float* rp1_b  = (const float*)d_in[22];
  const float* rln_g  = (const float*)d_in[23];
  const float* rln_b  = (const float*)d_in[24];
  const float* rp2_w  = (const float*)d_in[25];
  const float* rp2_b  = (const float*)d_in[26];
  (void)in_sizes; (void)n_in;

  const size_t BLD = 64ull * 1024 * 256;
  size_t need;
  {
    size_t o = 3 * BLD + 3 * 16 * 256 + 3 * 256 * 256
             + 64 * 1024 + 64 * 20 + 64 * 20 + 64 * 256 + 64 * 768 + 64 * 256 + 64 * 256;
    need = o * sizeof(float);
  }
  if (ws_size < need) {
    hipMemsetAsync(d_out, 0, (size_t)out_size * sizeof(float), stream);
    return;
  }

  float* ws = (float*)d_ws;
  size_t off = 0;
  auto alloc = [&](size_t n) { float* p = ws + off; off += n; return p; };
  float* BUF0 = alloc(BLD);
  float* BUF1 = alloc(BLD);
  float* BUF2 = alloc(BLD);
  float* CB1  = alloc(3 * 16 * 256);
  float* CB2  = alloc(3 * 256 * 256);
  float* MV   = alloc(64 * 1024);
  float* WTS  = alloc(64 * 20);
  int*   DLY  = (int*)alloc(64 * 20);
  float* PE   = alloc(64 * 256);
  float* FIN  = alloc(64 * 768);
  float* O1   = alloc(64 * 256);
  float* O2   = alloc(64 * 256);

  const int M = 65536;
  dim3 blk(256);

  convw_transpose<<<48, blk, 0, stream>>>(conv1_w, CB1, 16);
  convw_transpose<<<768, blk, 0, stream>>>(conv2_w, CB2, 256);

  // --- CNN frontend ---
  for (int kk = 0; kk < 3; kk++)
    gemm(stream, x_enc, CB1 + kk * 4096, BUF0, M, 256, 16, kk - 1,
         kk == 0 ? conv1_b : nullptr, nullptr,
         (kk == 0 ? 0 : FLAG_ACC) | (kk == 2 ? FLAG_RELU : 0));
  fixup_conv<<<128, blk, 0, stream>>>(BUF0, x_enc, conv1_w, conv1_b, 16, 1);
  for (int kk = 0; kk < 3; kk++)
    gemm(stream, BUF0, CB2 + kk * 65536, BUF1, M, 256, 256, kk - 1,
         kk == 0 ? conv2_b : nullptr, nullptr,
         (kk == 0 ? 0 : FLAG_ACC) | (kk == 2 ? FLAG_RELU : 0));
  fixup_conv<<<128, blk, 0, stream>>>(BUF1, BUF0, conv2_w, conv2_b, 256, 1);
  ln_rows<<<65536, blk, 0, stream>>>(BUF1, BUF2, cnn_g, cnn_b, 0, 256, 0);

  // --- encoder layers (enc in BUF2) ---
  for (int i = 0; i < 2; i++) {
    const float* Wq_i = Wq + (size_t)i * 65536;
    const float* Wk_i = Wk + (size_t)i * 65536;
    const float* Wv_i = Wv + (size_t)i * 65536;
    const float* Wo_i = Wo + (size_t)i * 65536;
    gemm(stream, BUF2, Wq_i, BUF0, M, 256, 256, 0, bq + i * 256, nullptr, 0);
    gemm(stream, BUF2, Wk_i, BUF1, M, 256, 256, 0, bk + i * 256, nullptr, 0);
    corr_mean2<<<dim3(16, 64), blk, 0, stream>>>(BUF0, BUF1, MV);
    topk_softmax<<<64, blk, 0, stream>>>(MV, WTS, DLY);
    gemm(stream, BUF2, Wv_i, BUF0, M, 256, 256, 0, bv + i * 256, nullptr, 0);
    agg_kernel<<<dim3(1024, 64), blk, 0, stream>>>(BUF0, WTS, DLY, BUF1);
    gemm(stream, BUF1, Wo_i, BUF0, M, 256, 256, 0, bo + i * 256, BUF2, 0);
    decomp_kernel<<<65536, blk, 0, stream>>>(BUF0, BUF1);   // xd -> BUF1
    // FFN (bf16 MFMA), 4 M-chunks; hidden fp32 in BUF2
    for (int c = 0; c < 4; c++) {
      const float* xd = BUF1 + (size_t)c * 16384 * 256;
      gemm_bf16_bt<<<dim3(8, 128), blk, 0, stream>>>(
          xd, Wff1 + (size_t)i * 262144, BUF2, nullptr, 16384, 1024, 256, 1);
      gemm_bf16_bt<<<dim3(2, 128), blk, 0, stream>>>(
          BUF2, Wff2 + (size_t)i * 262144, BUF0 + (size_t)c * 16384 * 256, xd,
          16384, 256, 1024, 0);
    }
    decomp_kernel<<<65536, blk, 0, stream>>>(BUF0, BUF2);   // new enc -> BUF2
    pool_copy<<<64, blk, 0, stream>>>(BUF2, FIN, i * 256);
  }

  // --- head ---
  init_bias<<<64, blk, 0, stream>>>(PE, proj_b);
  gemm(stream, x_enc, proj_w, PE, 64, 256, 16384, 0, nullptr, nullptr, 0, 32);
  ln_rows<<<64, blk, 0, stream>>>(PE, FIN, pln_g, pln_b, 1, 768, 512);
  init_bias<<<64, blk, 0, stream>>>(O1, rp1_b);
  gemm(stream, FIN, rp1_w, O1, 64, 256, 768, 0, nullptr, nullptr, 0, 4);
  ln_rows<<<64, blk, 0, stream>>>(O1, O2, rln_g, rln_b, 1, 256, 0);
  rp2_kernel<<<64, blk, 0, stream>>>(O2, rp2_w, rp2_b, (float*)d_out);
}

// Round 4
// 5999.844 us; speedup vs baseline: 2.0636x; 1.1274x over previous
//
#include <hip/hip_runtime.h>
#include <math.h>

#define FLAG_ACC  1
#define FLAG_RELU 2
#define FLAG_GELU 4

typedef __attribute__((ext_vector_type(8))) short short8;
typedef __attribute__((ext_vector_type(4))) float f32x4;

__device__ __forceinline__ short f2bf(float f) {
  unsigned u = __builtin_bit_cast(unsigned, f);
  unsigned r = u + 0x7fffu + ((u >> 16) & 1u);
  return (short)(r >> 16);
}

// ---------------- generic fp32 tiled GEMM: C[M,N] = A[M,K] @ B[K,N] ----------------
__global__ __launch_bounds__(256) void gemm_f32(
    const float* __restrict__ A, const float* __restrict__ B, float* __restrict__ C,
    int M, int N, int K, int a_shift,
    const float* __restrict__ bias, const float* __restrict__ residual, int flags)
{
  __shared__ float As[16][65];
  __shared__ float Bs[16][64];
  const int tid = threadIdx.x;
  const int tx = tid & 15, ty = tid >> 4;
  const int row0 = blockIdx.y * 64;
  const int col0 = blockIdx.x * 64;
  int kbeg = 0, kend = K;
  if ((int)gridDim.z > 1) {
    int kchunk = ((K + (int)gridDim.z - 1) / (int)gridDim.z + 15) & ~15;
    kbeg = (int)blockIdx.z * kchunk;
    kend = min(K, kbeg + kchunk);
  }
  float acc[4][4] = {};
  const int a_m = tid >> 2;
  const int a_k = (tid & 3) << 2;
  const int b_n = (tid & 15) << 2;
  const int b_k = tid >> 4;
  for (int k0 = kbeg; k0 < kend; k0 += 16) {
    int srow = row0 + a_m + a_shift;
    float4 av = make_float4(0.f, 0.f, 0.f, 0.f);
    if (srow >= 0 && srow < M)
      av = *reinterpret_cast<const float4*>(A + (long long)srow * K + (k0 + a_k));
    As[a_k + 0][a_m] = av.x; As[a_k + 1][a_m] = av.y;
    As[a_k + 2][a_m] = av.z; As[a_k + 3][a_m] = av.w;
    float4 bv = make_float4(0.f, 0.f, 0.f, 0.f);
    int brow = k0 + b_k;
    if (brow < K)
      bv = *reinterpret_cast<const float4*>(B + (long long)brow * N + (col0 + b_n));
    Bs[b_k][b_n + 0] = bv.x; Bs[b_k][b_n + 1] = bv.y;
    Bs[b_k][b_n + 2] = bv.z; Bs[b_k][b_n + 3] = bv.w;
    __syncthreads();
#pragma unroll
    for (int kk = 0; kk < 16; kk++) {
      float ar[4], br[4];
#pragma unroll
      for (int i = 0; i < 4; i++) ar[i] = As[kk][ty * 4 + i];
#pragma unroll
      for (int j = 0; j < 4; j++) br[j] = Bs[kk][tx * 4 + j];
#pragma unroll
      for (int i = 0; i < 4; i++)
#pragma unroll
        for (int j = 0; j < 4; j++)
          acc[i][j] += ar[i] * br[j];
    }
    __syncthreads();
  }
  if ((int)gridDim.z > 1) {
#pragma unroll
    for (int i = 0; i < 4; i++) {
      int r = row0 + ty * 4 + i; if (r >= M) continue;
#pragma unroll
      for (int j = 0; j < 4; j++) {
        int c = col0 + tx * 4 + j; if (c >= N) continue;
        atomicAdd(&C[(long long)r * N + c], acc[i][j]);
      }
    }
    return;
  }
#pragma unroll
  for (int i = 0; i < 4; i++) {
    int r = row0 + ty * 4 + i; if (r >= M) continue;
#pragma unroll
    for (int j = 0; j < 4; j++) {
      int c = col0 + tx * 4 + j; if (c >= N) continue;
      float v = acc[i][j];
      if (bias)     v += bias[c];
      if (residual) v += residual[(long long)r * N + c];
      if (flags & FLAG_ACC)  v += C[(long long)r * N + c];
      if (flags & FLAG_RELU) v = fmaxf(v, 0.f);
      if (flags & FLAG_GELU) v = 0.5f * v * (1.f + erff(v * 0.70710678118654752f));
      C[(long long)r * N + c] = v;
    }
  }
}

// ---------------- bf16 MFMA GEMM: C[M,N] = A[M,K] @ Bt[N,K]^T (+bias)(+res)(gelu) ----
// A, Bt fp32 in global; converted to bf16 (RNE) inline during LDS staging.
// M % 128 == 0, N % 128 == 0, K % 32 == 0 required.
__global__ __launch_bounds__(256) void gemm_bf16_bt(
    const float* __restrict__ A, const float* __restrict__ Bt, float* __restrict__ C,
    const float* __restrict__ residual, const float* __restrict__ bias,
    int M, int N, int K, int gelu)
{
  __shared__ short Asl[128][40];   // [m][k], +8 pad
  __shared__ short Bsl[128][40];   // [n][k]
  const int tid = threadIdx.x;
  const int row0 = blockIdx.y * 128;
  const int col0 = blockIdx.x * 128;
  const int lane = tid & 63;
  const int wave = tid >> 6;
  const int wm = (wave >> 1) * 64;
  const int wn = (wave & 1) * 64;
  const int fm = lane & 15;
  const int k8 = (lane >> 4) * 8;
  const int srow = tid >> 1;
  const int scol = (tid & 1) * 16;

  f32x4 acc[4][4] = {};
  for (int k0 = 0; k0 < K; k0 += 32) {
    __syncthreads();
    {
      const float* ga = A + (long long)(row0 + srow) * K + k0 + scol;
      const float* gb = Bt + (long long)(col0 + srow) * K + k0 + scol;
#pragma unroll
      for (int u = 0; u < 2; u++) {
        float4 f0 = *(const float4*)(ga + u * 8);
        float4 f1 = *(const float4*)(ga + u * 8 + 4);
        short8 v;
        v[0] = f2bf(f0.x); v[1] = f2bf(f0.y); v[2] = f2bf(f0.z); v[3] = f2bf(f0.w);
        v[4] = f2bf(f1.x); v[5] = f2bf(f1.y); v[6] = f2bf(f1.z); v[7] = f2bf(f1.w);
        *(short8*)&Asl[srow][scol + u * 8] = v;
        float4 g0 = *(const float4*)(gb + u * 8);
        float4 g1 = *(const float4*)(gb + u * 8 + 4);
        short8 w;
        w[0] = f2bf(g0.x); w[1] = f2bf(g0.y); w[2] = f2bf(g0.z); w[3] = f2bf(g0.w);
        w[4] = f2bf(g1.x); w[5] = f2bf(g1.y); w[6] = f2bf(g1.z); w[7] = f2bf(g1.w);
        *(short8*)&Bsl[srow][scol + u * 8] = w;
      }
    }
    __syncthreads();
    short8 af[4], bf[4];
#pragma unroll
    for (int i = 0; i < 4; i++) af[i] = *(short8*)&Asl[wm + i * 16 + fm][k8];
#pragma unroll
    for (int j = 0; j < 4; j++) bf[j] = *(short8*)&Bsl[wn + j * 16 + fm][k8];
#pragma unroll
    for (int i = 0; i < 4; i++)
#pragma unroll
      for (int j = 0; j < 4; j++)
        acc[i][j] = __builtin_amdgcn_mfma_f32_16x16x32_bf16(af[i], bf[j], acc[i][j], 0, 0, 0);
  }
  // epilogue: C/D layout col=lane&15, row=(lane>>4)*4+r
#pragma unroll
  for (int i = 0; i < 4; i++) {
    const int mbase = row0 + wm + i * 16 + (lane >> 4) * 4;
#pragma unroll
    for (int j = 0; j < 4; j++) {
      const int n = col0 + wn + j * 16 + (lane & 15);
      const float bs = bias ? bias[n] : 0.f;
#pragma unroll
      for (int r = 0; r < 4; r++) {
        long long idx = (long long)(mbase + r) * N + n;
        float v = acc[i][j][r] + bs;
        if (residual) v += residual[idx];
        if (gelu) v = 0.5f * v * (1.f + erff(v * 0.70710678118654752f));
        C[idx] = v;
      }
    }
  }
}

// ------------- conv weight re-layout: w[O=256][I][3] -> out[k][I][256] -------------
__global__ void convw_transpose(const float* __restrict__ w, float* __restrict__ out, int I)
{
  long long total = (long long)256 * I * 3;
  for (long long idx = blockIdx.x * 256LL + threadIdx.x; idx < total;
       idx += (long long)gridDim.x * 256LL) {
    int o = (int)(idx & 255);
    long long t = idx >> 8;
    int i = (int)(t % I);
    int kk = (int)(t / I);
    out[idx] = w[((long long)o * I + i) * 3 + kk];
  }
}

// ------------- generic transpose: in[R][Cc] -> out[Cc][R] -------------
__global__ void transpose_kernel(const float* __restrict__ in, float* __restrict__ out,
                                 int R, int Cc)
{
  long long total = (long long)R * Cc;
  for (long long i = blockIdx.x * 256LL + threadIdx.x; i < total;
       i += (long long)gridDim.x * 256LL) {
    int r = (int)(i / Cc), c = (int)(i % Cc);
    out[(long long)c * R + r] = in[i];
  }
}

// ------------- conv batch-boundary fixup: recompute rows l=0 and l=1023 -------------
__global__ void fixup_conv(float* __restrict__ h, const float* __restrict__ src,
                           const float* __restrict__ w, const float* __restrict__ bias,
                           int I, int do_relu)
{
  int b = blockIdx.x >> 1;
  int l = (blockIdx.x & 1) ? 1023 : 0;
  int o = threadIdx.x;
  float acc = bias[o];
  for (int kk = 0; kk < 3; kk++) {
    int t = l + kk - 1;
    if (t < 0 || t > 1023) continue;
    const float* srow = src + ((long long)b * 1024 + t) * I;
    const float* wrow = w + (long long)o * I * 3 + kk;
    for (int i = 0; i < I; i++) acc += srow[i] * wrow[(long long)i * 3];
  }
  if (do_relu) acc = fmaxf(acc, 0.f);
  h[((long long)b * 1024 + l) * 256 + o] = acc;
}

// ------------- LayerNorm over 256 channels -------------
__global__ __launch_bounds__(256) void ln_rows(
    const float* __restrict__ in, float* __restrict__ out,
    const float* __restrict__ g, const float* __restrict__ b,
    int prerelu, int out_stride, int out_off)
{
  __shared__ float red[4];
  int row = blockIdx.x, tid = threadIdx.x;
  float x = in[(long long)row * 256 + tid];
  if (prerelu) x = fmaxf(x, 0.f);
  float s = x;
#pragma unroll
  for (int o = 32; o > 0; o >>= 1) s += __shfl_down(s, o, 64);
  if ((tid & 63) == 0) red[tid >> 6] = s;
  __syncthreads();
  float mean = (red[0] + red[1] + red[2] + red[3]) * (1.f / 256.f);
  float d = x - mean;
  float s2 = d * d;
#pragma unroll
  for (int o = 32; o > 0; o >>= 1) s2 += __shfl_down(s2, o, 64);
  __syncthreads();
  if ((tid & 63) == 0) red[tid >> 6] = s2;
  __syncthreads();
  float var = (red[0] + red[1] + red[2] + red[3]) * (1.f / 256.f);
  out[(long long)row * out_stride + out_off + tid] =
      d * rsqrtf(var + 1e-5f) * g[tid] + b[tid];
}

// ------------- series_decomp -------------
__global__ void decomp_kernel(const float* __restrict__ in, float* __restrict__ out)
{
  int idx = blockIdx.x * 256 + threadIdx.x;
  int c = idx & 255;
  int bl = idx >> 8;
  int l = bl & 1023;
  int bbase = (bl >> 10) << 18;
  const float* base = in + bbase + c;
  float s = 0.f;
#pragma unroll
  for (int j = -12; j <= 12; j++) {
    int t = l + j;
    t = t < 0 ? 0 : (t > 1023 ? 1023 : t);
    s += base[t << 8];
  }
  out[idx] = in[idx] - s * (1.f / 25.f);
}

// ------------- circular correlation mean, register-blocked + XOR-swizzled LDS ------
// mv[b,tau] = (1/256) sum_t <q_t, k_(t-tau)>. Thread: 4 t x 4 tau x float4 d.
// LDS float4 tiles; physical col4 = c4 ^ ((row>>2)&7) -> bank-conflict-free reads.
__global__ __launch_bounds__(256) void corr_mean3(
    const float* __restrict__ q, const float* __restrict__ k, float* __restrict__ mv)
{
  __shared__ float4 qs4[64 * 16];
  __shared__ float4 ks4[127 * 16];
  const int b = blockIdx.y;
  const int tau0 = blockIdx.x * 64;
  const int tid = threadIdx.x;
  const int tg = tid & 15;         // t-group: rows tg*4..tg*4+3 of t-tile
  const int ug = tid >> 4;         // tau-group: taus ug*4..ug*4+3 of tau-tile
  const int rbase = 4 * (tg - ug) + 63;   // band row for (i=0, j=0)
  const int qswz = tg & 7;                // (row>>2)&7 for rows tg*4+i, i<4
  const float* qb = q + (long long)b * 262144;
  const float* kb = k + (long long)b * 262144;
  float acc[4][4] = {};
  for (int t0 = 0; t0 < 1024; t0 += 64) {
    const int base = t0 - tau0 - 63;
    for (int d0 = 0; d0 < 256; d0 += 64) {
      __syncthreads();
#pragma unroll
      for (int u = 0; u < 4; u++) {
        int idx = tid + u * 256;               // 64*16 float4
        int r = idx >> 4, c = idx & 15;
        qs4[r * 16 + (c ^ ((r >> 2) & 7))] =
            *(const float4*)(qb + (long long)(t0 + r) * 256 + d0 + c * 4);
      }
#pragma unroll
      for (int u = 0; u < 8; u++) {
        int idx = tid + u * 256;               // 127*16 float4
        if (idx < 2032) {
          int r = idx >> 4, c = idx & 15;
          int ar = (base + r) & 1023;
          ks4[r * 16 + (c ^ ((r >> 2) & 7))] =
              *(const float4*)(kb + (long long)ar * 256 + d0 + c * 4);
        }
      }
      __syncthreads();
      for (int c4 = 0; c4 < 16; c4++) {
        float4 qv[4], kv[7];
#pragma unroll
        for (int i = 0; i < 4; i++)
          qv[i] = qs4[(tg * 4 + i) * 16 + (c4 ^ qswz)];
#pragma unroll
        for (int s = 0; s < 7; s++) {
          int r = rbase - 3 + s;
          kv[s] = ks4[r * 16 + (c4 ^ ((r >> 2) & 7))];
        }
#pragma unroll
        for (int i = 0; i < 4; i++)
#pragma unroll
          for (int j = 0; j < 4; j++) {
            const float4 kvv = kv[i - j + 3];
            acc[i][j] += qv[i].x * kvv.x + qv[i].y * kvv.y
                       + qv[i].z * kvv.z + qv[i].w * kvv.w;
          }
      }
    }
  }
  float s[4];
#pragma unroll
  for (int j = 0; j < 4; j++) s[j] = acc[0][j] + acc[1][j] + acc[2][j] + acc[3][j];
#pragma unroll
  for (int off = 1; off < 16; off <<= 1) {
#pragma unroll
    for (int j = 0; j < 4; j++) s[j] += __shfl_xor(s[j], off, 64);
  }
  if (tg == 0) {
    float* o = mv + b * 1024 + tau0 + ug * 4;
#pragma unroll
    for (int j = 0; j < 4; j++) o[j] = s[j] * (1.f / 256.f);
  }
}

// ------------- top-20 + softmax per batch -------------
__global__ void topk_softmax(const float* __restrict__ mv, float* __restrict__ wts,
                             int* __restrict__ dly)
{
  __shared__ float vals[1024];
  __shared__ float lv[256];
  __shared__ int   li[256];
  __shared__ float selw[20];
  __shared__ int   seli[20];
  int b = blockIdx.x, tid = threadIdx.x;
#pragma unroll
  for (int u = 0; u < 4; u++) vals[u * 256 + tid] = mv[b * 1024 + u * 256 + tid];
  __syncthreads();
  for (int it = 0; it < 20; it++) {
    float bvv = -1e30f; int bi = 0;
#pragma unroll
    for (int u = 0; u < 4; u++) {
      int i2 = tid + u * 256;
      float v = vals[i2];
      if (v > bvv) { bvv = v; bi = i2; }
    }
    lv[tid] = bvv; li[tid] = bi;
    __syncthreads();
    if (tid == 0) {
      float best = -1e30f; int besti = 1 << 20;
      for (int u = 0; u < 256; u++) {
        if (lv[u] > best || (lv[u] == best && li[u] < besti)) { best = lv[u]; besti = li[u]; }
      }
      selw[it] = best; seli[it] = besti;
      vals[besti] = -1e30f;
    }
    __syncthreads();
  }
  if (tid == 0) {
    float mx = selw[0];
    float e[20], sum = 0.f;
    for (int i = 0; i < 20; i++) { e[i] = expf(selw[i] - mx); sum += e[i]; }
    float inv = 1.f / sum;
    for (int i = 0; i < 20; i++) { wts[b * 20 + i] = e[i] * inv; dly[b * 20 + i] = seli[i]; }
  }
}

// ------------- delay aggregation -------------
__global__ void agg_kernel(const float* __restrict__ v, const float* __restrict__ wts,
                           const int* __restrict__ dly, float* __restrict__ out)
{
  int b = blockIdx.y, l = blockIdx.x, tid = threadIdx.x;
  const float* vb = v + (long long)b * 1024 * 256;
  float acc = 0.f;
  for (int kk = 0; kk < 20; kk++) {
    int d = dly[b * 20 + kk];
    float w = wts[b * 20 + kk];
    acc += w * vb[(long long)((l + d) & 1023) * 256 + tid];
  }
  out[((long long)b * 1024 + l) * 256 + tid] = acc;
}

// ------------- small helpers -------------
__global__ void pool_copy(const float* __restrict__ enc, float* __restrict__ fin, int off)
{
  int b = blockIdx.x, tid = threadIdx.x;
  fin[(long long)b * 768 + off + tid] = enc[((long long)b * 1024 + 1023) * 256 + tid];
}

__global__ void init_bias(float* __restrict__ C, const float* __restrict__ bias)
{
  C[(long long)blockIdx.x * 256 + threadIdx.x] = bias[threadIdx.x];
}

__global__ void rp2_kernel(const float* __restrict__ x, const float* __restrict__ w,
                           const float* __restrict__ bias, float* __restrict__ out)
{
  __shared__ float red[4];
  int b = blockIdx.x, tid = threadIdx.x;
  float p = x[b * 256 + tid] * w[tid];
#pragma unroll
  for (int o = 32; o > 0; o >>= 1) p += __shfl_down(p, o, 64);
  if ((tid & 63) == 0) red[tid >> 6] = p;
  __syncthreads();
  if (tid == 0) out[b] = red[0] + red[1] + red[2] + red[3] + bias[0];
}

// =========================== host launch ===========================
static inline void gemm(hipStream_t s, const float* A, const float* B, float* C,
                        int M, int N, int K, int shift, const float* bias,
                        const float* res, int flags, int splitz = 1)
{
  dim3 g((N + 63) / 64, (M + 63) / 64, splitz);
  gemm_f32<<<g, dim3(256), 0, s>>>(A, B, C, M, N, K, shift, bias, res, flags);
}

extern "C" void kernel_launch(void* const* d_in, const int* in_sizes, int n_in,
                              void* d_out, int out_size, void* d_ws, size_t ws_size,
                              hipStream_t stream)
{
  const float* x_enc  = (const float*)d_in[0];
  const float* conv1_w= (const float*)d_in[1];
  const float* conv1_b= (const float*)d_in[2];
  const float* conv2_w= (const float*)d_in[3];
  const float* conv2_b= (const float*)d_in[4];
  const float* cnn_g  = (const float*)d_in[5];
  const float* cnn_b  = (const float*)d_in[6];
  const float* proj_w = (const float*)d_in[7];
  const float* proj_b = (const float*)d_in[8];
  const float* pln_g  = (const float*)d_in[9];
  const float* pln_b  = (const float*)d_in[10];
  const float* Wq     = (const float*)d_in[11];
  const float* bq     = (const float*)d_in[12];
  const float* Wk     = (const float*)d_in[13];
  const float* bk     = (const float*)d_in[14];
  const float* Wv     = (const float*)d_in[15];
  const float* bv     = (const float*)d_in[16];
  const float* Wo     = (const float*)d_in[17];
  const float* bo     = (const float*)d_in[18];
  const float* Wff1   = (const float*)d_in[19];
  const float* Wff2   = (const float*)d_in[20];
  const float* rp1_w  = (const float*)d_in[21];
  const float* rp1_b  = (const float*)d_in[22];
  const float* rln_g  = (const float*)d_in[23];
  const float* rln_b  = (const float*)d_in[24];
  const float* rp2_w  = (const float*)d_in[25];
  const float* rp2_b  = (const float*)d_in[26];
  (void)in_sizes; (void)n_in;

  const size_t BLD = 64ull * 1024 * 256;
  size_t need;
  {
    size_t o = 3 * BLD + 3 * 16 * 256 + 3 * 256 * 256 + 2 * 65536
             + 64 * 1024 + 64 * 20 + 64 * 20 + 64 * 256 + 64 * 768 + 64 * 256 + 64 * 256;
    need = o * sizeof(float);
  }
  if (ws_size < need) {
    hipMemsetAsync(d_out, 0, (size_t)out_size * sizeof(float), stream);
    return;
  }

  float* ws = (float*)d_ws;
  size_t off = 0;
  auto alloc = [&](size_t n) { float* p = ws + off; off += n; return p; };
  float* BUF0 = alloc(BLD);
  float* BUF1 = alloc(BLD);
  float* BUF2 = alloc(BLD);
  float* CB1  = alloc(3 * 16 * 256);
  float* CB2  = alloc(3 * 256 * 256);
  float* WVT  = alloc(65536);
  float* WOT  = alloc(65536);
  float* MV   = alloc(64 * 1024);
  float* WTS  = alloc(64 * 20);
  int*   DLY  = (int*)alloc(64 * 20);
  float* PE   = alloc(64 * 256);
  float* FIN  = alloc(64 * 768);
  float* O1   = alloc(64 * 256);
  float* O2   = alloc(64 * 256);

  const int M = 65536;
  dim3 blk(256);

  convw_transpose<<<48, blk, 0, stream>>>(conv1_w, CB1, 16);
  convw_transpose<<<768, blk, 0, stream>>>(conv2_w, CB2, 256);

  // --- CNN frontend ---
  for (int kk = 0; kk < 3; kk++)
    gemm(stream, x_enc, CB1 + kk * 4096, BUF0, M, 256, 16, kk - 1,
         kk == 0 ? conv1_b : nullptr, nullptr,
         (kk == 0 ? 0 : FLAG_ACC) | (kk == 2 ? FLAG_RELU : 0));
  fixup_conv<<<128, blk, 0, stream>>>(BUF0, x_enc, conv1_w, conv1_b, 16, 1);
  for (int kk = 0; kk < 3; kk++)
    gemm(stream, BUF0, CB2 + kk * 65536, BUF1, M, 256, 256, kk - 1,
         kk == 0 ? conv2_b : nullptr, nullptr,
         (kk == 0 ? 0 : FLAG_ACC) | (kk == 2 ? FLAG_RELU : 0));
  fixup_conv<<<128, blk, 0, stream>>>(BUF1, BUF0, conv2_w, conv2_b, 256, 1);
  ln_rows<<<65536, blk, 0, stream>>>(BUF1, BUF2, cnn_g, cnn_b, 0, 256, 0);

  // --- encoder layers (enc in BUF2) ---
  for (int i = 0; i < 2; i++) {
    const float* Wq_i = Wq + (size_t)i * 65536;
    const float* Wk_i = Wk + (size_t)i * 65536;
    const float* Wv_i = Wv + (size_t)i * 65536;
    const float* Wo_i = Wo + (size_t)i * 65536;
    // q, k in fp32 (top-k path precision)
    gemm(stream, BUF2, Wq_i, BUF0, M, 256, 256, 0, bq + i * 256, nullptr, 0);
    gemm(stream, BUF2, Wk_i, BUF1, M, 256, 256, 0, bk + i * 256, nullptr, 0);
    corr_mean3<<<dim3(16, 64), blk, 0, stream>>>(BUF0, BUF1, MV);
    topk_softmax<<<64, blk, 0, stream>>>(MV, WTS, DLY);
    // v, o in bf16 MFMA (output path)
    transpose_kernel<<<256, blk, 0, stream>>>(Wv_i, WVT, 256, 256);
    transpose_kernel<<<256, blk, 0, stream>>>(Wo_i, WOT, 256, 256);
    gemm_bf16_bt<<<dim3(2, 512), blk, 0, stream>>>(
        BUF2, WVT, BUF0, nullptr, bv + i * 256, M, 256, 256, 0);
    agg_kernel<<<dim3(1024, 64), blk, 0, stream>>>(BUF0, WTS, DLY, BUF1);
    gemm_bf16_bt<<<dim3(2, 512), blk, 0, stream>>>(
        BUF1, WOT, BUF0, BUF2, bo + i * 256, M, 256, 256, 0);
    decomp_kernel<<<65536, blk, 0, stream>>>(BUF0, BUF1);   // xd -> BUF1
    // FFN (bf16 MFMA), 4 M-chunks; hidden fp32 in BUF2
    for (int c = 0; c < 4; c++) {
      const float* xd = BUF1 + (size_t)c * 16384 * 256;
      gemm_bf16_bt<<<dim3(8, 128), blk, 0, stream>>>(
          xd, Wff1 + (size_t)i * 262144, BUF2, nullptr, nullptr, 16384, 1024, 256, 1);
      gemm_bf16_bt<<<dim3(2, 128), blk, 0, stream>>>(
          BUF2, Wff2 + (size_t)i * 262144, BUF0 + (size_t)c * 16384 * 256, xd, nullptr,
          16384, 256, 1024, 0);
    }
    decomp_kernel<<<65536, blk, 0, stream>>>(BUF0, BUF2);   // new enc -> BUF2
    pool_copy<<<64, blk, 0, stream>>>(BUF2, FIN, i * 256);
  }

  // --- head ---
  init_bias<<<64, blk, 0, stream>>>(PE, proj_b);
  gemm(stream, x_enc, proj_w, PE, 64, 256, 16384, 0, nullptr, nullptr, 0, 32);
  ln_rows<<<64, blk, 0, stream>>>(PE, FIN, pln_g, pln_b, 1, 768, 512);
  init_bias<<<64, blk, 0, stream>>>(O1, rp1_b);
  gemm(stream, FIN, rp1_w, O1, 64, 256, 768, 0, nullptr, nullptr, 0, 4);
  ln_rows<<<64, blk, 0, stream>>>(O1, O2, rln_g, rln_b, 1, 256, 0);
  rp2_kernel<<<64, blk, 0, stream>>>(O2, rp2_w, rp2_b, (float*)d_out);
}

// Round 5
// 3975.940 us; speedup vs baseline: 3.1141x; 1.5090x over previous
//
#include <hip/hip_runtime.h>
#include <math.h>

#define FLAG_ACC  1
#define FLAG_RELU 2
#define FLAG_GELU 4

typedef __attribute__((ext_vector_type(8))) short short8;
typedef __attribute__((ext_vector_type(4))) short short4v;
typedef __attribute__((ext_vector_type(4))) float f32x4;

__device__ __forceinline__ short f2bf(float f) {
  unsigned u = __builtin_bit_cast(unsigned, f);
  unsigned r = u + 0x7fffu + ((u >> 16) & 1u);
  return (short)(r >> 16);
}
__device__ __forceinline__ float bf2f(short s) {
  unsigned u = ((unsigned)(unsigned short)s) << 16;
  return __builtin_bit_cast(float, u);
}

// ---------------- generic fp32 tiled GEMM: C[M,N] = A[M,K] @ B[K,N] ----------------
__global__ __launch_bounds__(256) void gemm_f32(
    const float* __restrict__ A, const float* __restrict__ B, float* __restrict__ C,
    int M, int N, int K, int a_shift,
    const float* __restrict__ bias, const float* __restrict__ residual, int flags)
{
  __shared__ float As[16][65];
  __shared__ float Bs[16][64];
  const int tid = threadIdx.x;
  const int tx = tid & 15, ty = tid >> 4;
  const int row0 = blockIdx.y * 64;
  const int col0 = blockIdx.x * 64;
  int kbeg = 0, kend = K;
  if ((int)gridDim.z > 1) {
    int kchunk = ((K + (int)gridDim.z - 1) / (int)gridDim.z + 15) & ~15;
    kbeg = (int)blockIdx.z * kchunk;
    kend = min(K, kbeg + kchunk);
  }
  float acc[4][4] = {};
  const int a_m = tid >> 2;
  const int a_k = (tid & 3) << 2;
  const int b_n = (tid & 15) << 2;
  const int b_k = tid >> 4;
  for (int k0 = kbeg; k0 < kend; k0 += 16) {
    int srow = row0 + a_m + a_shift;
    float4 av = make_float4(0.f, 0.f, 0.f, 0.f);
    if (srow >= 0 && srow < M)
      av = *reinterpret_cast<const float4*>(A + (long long)srow * K + (k0 + a_k));
    As[a_k + 0][a_m] = av.x; As[a_k + 1][a_m] = av.y;
    As[a_k + 2][a_m] = av.z; As[a_k + 3][a_m] = av.w;
    float4 bv = make_float4(0.f, 0.f, 0.f, 0.f);
    int brow = k0 + b_k;
    if (brow < K)
      bv = *reinterpret_cast<const float4*>(B + (long long)brow * N + (col0 + b_n));
    Bs[b_k][b_n + 0] = bv.x; Bs[b_k][b_n + 1] = bv.y;
    Bs[b_k][b_n + 2] = bv.z; Bs[b_k][b_n + 3] = bv.w;
    __syncthreads();
#pragma unroll
    for (int kk = 0; kk < 16; kk++) {
      float ar[4], br[4];
#pragma unroll
      for (int i = 0; i < 4; i++) ar[i] = As[kk][ty * 4 + i];
#pragma unroll
      for (int j = 0; j < 4; j++) br[j] = Bs[kk][tx * 4 + j];
#pragma unroll
      for (int i = 0; i < 4; i++)
#pragma unroll
        for (int j = 0; j < 4; j++)
          acc[i][j] += ar[i] * br[j];
    }
    __syncthreads();
  }
  if ((int)gridDim.z > 1) {
#pragma unroll
    for (int i = 0; i < 4; i++) {
      int r = row0 + ty * 4 + i; if (r >= M) continue;
#pragma unroll
      for (int j = 0; j < 4; j++) {
        int c = col0 + tx * 4 + j; if (c >= N) continue;
        atomicAdd(&C[(long long)r * N + c], acc[i][j]);
      }
    }
    return;
  }
#pragma unroll
  for (int i = 0; i < 4; i++) {
    int r = row0 + ty * 4 + i; if (r >= M) continue;
#pragma unroll
    for (int j = 0; j < 4; j++) {
      int c = col0 + tx * 4 + j; if (c >= N) continue;
      float v = acc[i][j];
      if (bias)     v += bias[c];
      if (residual) v += residual[(long long)r * N + c];
      if (flags & FLAG_ACC)  v += C[(long long)r * N + c];
      if (flags & FLAG_RELU) v = fmaxf(v, 0.f);
      if (flags & FLAG_GELU) v = 0.5f * v * (1.f + erff(v * 0.70710678118654752f));
      C[(long long)r * N + c] = v;
    }
  }
}

// ---------------- bf16 MFMA GEMM: C[M,N] = A[M,K] @ Bt[N,K]^T ----------------------
// flags: ACC (C += ...), RELU, GELU. a_shift: C-row r reads A row r+a_shift (OOB=0).
// M%128==0, N%128==0, K%32==0 required.
__global__ __launch_bounds__(256) void gemm_bf16_bt(
    const float* __restrict__ A, const float* __restrict__ Bt, float* __restrict__ C,
    const float* __restrict__ residual, const float* __restrict__ bias,
    int M, int N, int K, int flags, int a_shift)
{
  __shared__ short Asl[128][40];
  __shared__ short Bsl[128][40];
  const int tid = threadIdx.x;
  const int row0 = blockIdx.y * 128;
  const int col0 = blockIdx.x * 128;
  const int lane = tid & 63;
  const int wave = tid >> 6;
  const int wm = (wave >> 1) * 64;
  const int wn = (wave & 1) * 64;
  const int fm = lane & 15;
  const int k8 = (lane >> 4) * 8;
  const int srow = tid >> 1;
  const int scol = (tid & 1) * 16;
  const int arow = row0 + srow + a_shift;
  const bool avalid = (arow >= 0 && arow < M);

  f32x4 acc[4][4] = {};
  for (int k0 = 0; k0 < K; k0 += 32) {
    __syncthreads();
    {
      const float* ga = A + (long long)arow * K + k0 + scol;
      const float* gb = Bt + (long long)(col0 + srow) * K + k0 + scol;
#pragma unroll
      for (int u = 0; u < 2; u++) {
        float4 f0 = make_float4(0.f, 0.f, 0.f, 0.f), f1 = f0;
        if (avalid) { f0 = *(const float4*)(ga + u * 8); f1 = *(const float4*)(ga + u * 8 + 4); }
        short8 v;
        v[0] = f2bf(f0.x); v[1] = f2bf(f0.y); v[2] = f2bf(f0.z); v[3] = f2bf(f0.w);
        v[4] = f2bf(f1.x); v[5] = f2bf(f1.y); v[6] = f2bf(f1.z); v[7] = f2bf(f1.w);
        *(short8*)&Asl[srow][scol + u * 8] = v;
        float4 g0 = *(const float4*)(gb + u * 8);
        float4 g1 = *(const float4*)(gb + u * 8 + 4);
        short8 w;
        w[0] = f2bf(g0.x); w[1] = f2bf(g0.y); w[2] = f2bf(g0.z); w[3] = f2bf(g0.w);
        w[4] = f2bf(g1.x); w[5] = f2bf(g1.y); w[6] = f2bf(g1.z); w[7] = f2bf(g1.w);
        *(short8*)&Bsl[srow][scol + u * 8] = w;
      }
    }
    __syncthreads();
    short8 af[4], bf[4];
#pragma unroll
    for (int i = 0; i < 4; i++) af[i] = *(short8*)&Asl[wm + i * 16 + fm][k8];
#pragma unroll
    for (int j = 0; j < 4; j++) bf[j] = *(short8*)&Bsl[wn + j * 16 + fm][k8];
#pragma unroll
    for (int i = 0; i < 4; i++)
#pragma unroll
      for (int j = 0; j < 4; j++)
        acc[i][j] = __builtin_amdgcn_mfma_f32_16x16x32_bf16(af[i], bf[j], acc[i][j], 0, 0, 0);
  }
#pragma unroll
  for (int i = 0; i < 4; i++) {
    const int mbase = row0 + wm + i * 16 + (lane >> 4) * 4;
#pragma unroll
    for (int j = 0; j < 4; j++) {
      const int n = col0 + wn + j * 16 + fm;
      const float bs = bias ? bias[n] : 0.f;
#pragma unroll
      for (int r = 0; r < 4; r++) {
        long long idx = (long long)(mbase + r) * N + n;
        float v = acc[i][j][r] + bs;
        if (residual) v += residual[idx];
        if (flags & FLAG_ACC)  v += C[idx];
        if (flags & FLAG_RELU) v = fmaxf(v, 0.f);
        if (flags & FLAG_GELU) v = 0.5f * v * (1.f + erff(v * 0.70710678118654752f));
        C[idx] = v;
      }
    }
  }
}

// ------------- circular-correlation mean via split-bf16 MFMA --------------------
// S[t,s] = <q_t, k_s> computed as qh*kh + qh*kl + ql*kh (bf16x3, rel err ~4e-6).
// mv[b,tau] += (1/256) * sum over diagonal t-s = tau (mod 1024).
// grid (8 s-tiles, 8 t-tiles, 64 b), 256 threads, 64 KB LDS.
__global__ __launch_bounds__(256) void corr_mfma(
    const float* __restrict__ q, const float* __restrict__ k, float* __restrict__ mv)
{
  __shared__ __align__(16) char smem[65536];
  short (*Ahi)[40] = (short(*)[40])(smem);
  short (*Alo)[40] = (short(*)[40])(smem + 10240);
  short (*Bhi)[40] = (short(*)[40])(smem + 20480);
  short (*Blo)[40] = (short(*)[40])(smem + 30720);
  float* Sf = (float*)smem;   // 128x128 fp32, reused after MFMA phase

  const int b  = blockIdx.z;
  const int t0 = blockIdx.y * 128;
  const int s0 = blockIdx.x * 128;
  const int tid = threadIdx.x;
  const int lane = tid & 63;
  const int wave = tid >> 6;
  const int wm = (wave >> 1) * 64;
  const int wn = (wave & 1) * 64;
  const int fm = lane & 15;
  const int k8 = (lane >> 4) * 8;
  const int srow = tid >> 1;
  const int scol = (tid & 1) * 16;
  const float* gq0 = q + (long long)b * 262144 + (long long)(t0 + srow) * 256 + scol;
  const float* gk0 = k + (long long)b * 262144 + (long long)(s0 + srow) * 256 + scol;

  f32x4 acc[4][4] = {};
  for (int k0 = 0; k0 < 256; k0 += 32) {
    __syncthreads();
#pragma unroll
    for (int u = 0; u < 4; u++) {
      float4 f = *(const float4*)(gq0 + k0 + u * 4);
      short4v h, l;
      h[0] = f2bf(f.x); h[1] = f2bf(f.y); h[2] = f2bf(f.z); h[3] = f2bf(f.w);
      l[0] = f2bf(f.x - bf2f(h[0])); l[1] = f2bf(f.y - bf2f(h[1]));
      l[2] = f2bf(f.z - bf2f(h[2])); l[3] = f2bf(f.w - bf2f(h[3]));
      *(short4v*)&Ahi[srow][scol + u * 4] = h;
      *(short4v*)&Alo[srow][scol + u * 4] = l;
      float4 g = *(const float4*)(gk0 + k0 + u * 4);
      short4v hb, lb;
      hb[0] = f2bf(g.x); hb[1] = f2bf(g.y); hb[2] = f2bf(g.z); hb[3] = f2bf(g.w);
      lb[0] = f2bf(g.x - bf2f(hb[0])); lb[1] = f2bf(g.y - bf2f(hb[1]));
      lb[2] = f2bf(g.z - bf2f(hb[2])); lb[3] = f2bf(g.w - bf2f(hb[3]));
      *(short4v*)&Bhi[srow][scol + u * 4] = hb;
      *(short4v*)&Blo[srow][scol + u * 4] = lb;
    }
    __syncthreads();
    short8 ah[4], al[4], bh[4], bl[4];
#pragma unroll
    for (int i = 0; i < 4; i++) {
      ah[i] = *(short8*)&Ahi[wm + i * 16 + fm][k8];
      al[i] = *(short8*)&Alo[wm + i * 16 + fm][k8];
    }
#pragma unroll
    for (int j = 0; j < 4; j++) {
      bh[j] = *(short8*)&Bhi[wn + j * 16 + fm][k8];
      bl[j] = *(short8*)&Blo[wn + j * 16 + fm][k8];
    }
#pragma unroll
    for (int i = 0; i < 4; i++)
#pragma unroll
      for (int j = 0; j < 4; j++) {
        acc[i][j] = __builtin_amdgcn_mfma_f32_16x16x32_bf16(ah[i], bh[j], acc[i][j], 0, 0, 0);
        acc[i][j] = __builtin_amdgcn_mfma_f32_16x16x32_bf16(ah[i], bl[j], acc[i][j], 0, 0, 0);
        acc[i][j] = __builtin_amdgcn_mfma_f32_16x16x32_bf16(al[i], bh[j], acc[i][j], 0, 0, 0);
      }
  }
  __syncthreads();   // staging reads done; reuse LDS as S
#pragma unroll
  for (int i = 0; i < 4; i++) {
    const int row = wm + i * 16 + (lane >> 4) * 4;
#pragma unroll
    for (int j = 0; j < 4; j++) {
      const int col = wn + j * 16 + fm;
#pragma unroll
      for (int r = 0; r < 4; r++)
        Sf[(row + r) * 128 + col] = acc[i][j][r] * (1.f / 256.f);
    }
  }
  __syncthreads();
  if (tid < 255) {
    const int delta = tid - 127;
    const int mlo = delta > 0 ? delta : 0;
    const int mhi = 128 + (delta < 0 ? delta : 0);
    float ssum = 0.f;
    for (int m = mlo; m < mhi; m++) ssum += Sf[m * 128 + (m - delta)];
    const int tau = (t0 - s0 + delta) & 1023;
    atomicAdd(&mv[b * 1024 + tau], ssum);
  }
}

// ------------- conv weight re-layout: w[O=256][I][3] -> out[k][I][256] -------------
__global__ void convw_transpose(const float* __restrict__ w, float* __restrict__ out, int I)
{
  long long total = (long long)256 * I * 3;
  for (long long idx = blockIdx.x * 256LL + threadIdx.x; idx < total;
       idx += (long long)gridDim.x * 256LL) {
    int o = (int)(idx & 255);
    long long t = idx >> 8;
    int i = (int)(t % I);
    int kk = (int)(t / I);
    out[idx] = w[((long long)o * I + i) * 3 + kk];
  }
}

// ------------- conv2 tap extraction: w[o][i][kk] -> out[kk][o][i]  (Bt layout) -----
__global__ void convw2_bt(const float* __restrict__ w, float* __restrict__ out)
{
  for (int idx = blockIdx.x * 256 + threadIdx.x; idx < 196608;
       idx += gridDim.x * 256) {
    int kk = idx >> 16;
    int o = (idx >> 8) & 255;
    int i = idx & 255;
    out[idx] = w[(o * 256 + i) * 3 + kk];
  }
}

// ------------- generic transpose: in[R][Cc] -> out[Cc][R] -------------
__global__ void transpose_kernel(const float* __restrict__ in, float* __restrict__ out,
                                 int R, int Cc)
{
  long long total = (long long)R * Cc;
  for (long long i = blockIdx.x * 256LL + threadIdx.x; i < total;
       i += (long long)gridDim.x * 256LL) {
    int r = (int)(i / Cc), c = (int)(i % Cc);
    out[(long long)c * R + r] = in[i];
  }
}

// ------------- conv batch-boundary fixup: recompute rows l=0 and l=1023 ------------
__global__ void fixup_conv(float* __restrict__ h, const float* __restrict__ src,
                           const float* __restrict__ w, const float* __restrict__ bias,
                           int I, int do_relu)
{
  int b = blockIdx.x >> 1;
  int l = (blockIdx.x & 1) ? 1023 : 0;
  int o = threadIdx.x;
  float acc = bias[o];
  for (int kk = 0; kk < 3; kk++) {
    int t = l + kk - 1;
    if (t < 0 || t > 1023) continue;
    const float* srow = src + ((long long)b * 1024 + t) * I;
    const float* wrow = w + (long long)o * I * 3 + kk;
    for (int i = 0; i < I; i++) acc += srow[i] * wrow[(long long)i * 3];
  }
  if (do_relu) acc = fmaxf(acc, 0.f);
  h[((long long)b * 1024 + l) * 256 + o] = acc;
}

// ------------- LayerNorm over 256 channels -------------
__global__ __launch_bounds__(256) void ln_rows(
    const float* __restrict__ in, float* __restrict__ out,
    const float* __restrict__ g, const float* __restrict__ b,
    int prerelu, int out_stride, int out_off)
{
  __shared__ float red[4];
  int row = blockIdx.x, tid = threadIdx.x;
  float x = in[(long long)row * 256 + tid];
  if (prerelu) x = fmaxf(x, 0.f);
  float s = x;
#pragma unroll
  for (int o = 32; o > 0; o >>= 1) s += __shfl_down(s, o, 64);
  if ((tid & 63) == 0) red[tid >> 6] = s;
  __syncthreads();
  float mean = (red[0] + red[1] + red[2] + red[3]) * (1.f / 256.f);
  float d = x - mean;
  float s2 = d * d;
#pragma unroll
  for (int o = 32; o > 0; o >>= 1) s2 += __shfl_down(s2, o, 64);
  __syncthreads();
  if ((tid & 63) == 0) red[tid >> 6] = s2;
  __syncthreads();
  float var = (red[0] + red[1] + red[2] + red[3]) * (1.f / 256.f);
  out[(long long)row * out_stride + out_off + tid] =
      d * rsqrtf(var + 1e-5f) * g[tid] + b[tid];
}

// ------------- series_decomp -------------
__global__ void decomp_kernel(const float* __restrict__ in, float* __restrict__ out)
{
  int idx = blockIdx.x * 256 + threadIdx.x;
  int c = idx & 255;
  int bl = idx >> 8;
  int l = bl & 1023;
  int bbase = (bl >> 10) << 18;
  const float* base = in + bbase + c;
  float s = 0.f;
#pragma unroll
  for (int j = -12; j <= 12; j++) {
    int t = l + j;
    t = t < 0 ? 0 : (t > 1023 ? 1023 : t);
    s += base[t << 8];
  }
  out[idx] = in[idx] - s * (1.f / 25.f);
}

// ------------- top-20 + softmax per batch -------------
__global__ void topk_softmax(const float* __restrict__ mv, float* __restrict__ wts,
                             int* __restrict__ dly)
{
  __shared__ float vals[1024];
  __shared__ float lv[256];
  __shared__ int   li[256];
  __shared__ float selw[20];
  __shared__ int   seli[20];
  int b = blockIdx.x, tid = threadIdx.x;
#pragma unroll
  for (int u = 0; u < 4; u++) vals[u * 256 + tid] = mv[b * 1024 + u * 256 + tid];
  __syncthreads();
  for (int it = 0; it < 20; it++) {
    float bvv = -1e30f; int bi = 0;
#pragma unroll
    for (int u = 0; u < 4; u++) {
      int i2 = tid + u * 256;
      float v = vals[i2];
      if (v > bvv) { bvv = v; bi = i2; }
    }
    lv[tid] = bvv; li[tid] = bi;
    __syncthreads();
    if (tid == 0) {
      float best = -1e30f; int besti = 1 << 20;
      for (int u = 0; u < 256; u++) {
        if (lv[u] > best || (lv[u] == best && li[u] < besti)) { best = lv[u]; besti = li[u]; }
      }
      selw[it] = best; seli[it] = besti;
      vals[besti] = -1e30f;
    }
    __syncthreads();
  }
  if (tid == 0) {
    float mx = selw[0];
    float e[20], sum = 0.f;
    for (int i = 0; i < 20; i++) { e[i] = expf(selw[i] - mx); sum += e[i]; }
    float inv = 1.f / sum;
    for (int i = 0; i < 20; i++) { wts[b * 20 + i] = e[i] * inv; dly[b * 20 + i] = seli[i]; }
  }
}

// ------------- delay aggregation -------------
__global__ void agg_kernel(const float* __restrict__ v, const float* __restrict__ wts,
                           const int* __restrict__ dly, float* __restrict__ out)
{
  int b = blockIdx.y, l = blockIdx.x, tid = threadIdx.x;
  const float* vb = v + (long long)b * 1024 * 256;
  float acc = 0.f;
  for (int kk = 0; kk < 20; kk++) {
    int d = dly[b * 20 + kk];
    float w = wts[b * 20 + kk];
    acc += w * vb[(long long)((l + d) & 1023) * 256 + tid];
  }
  out[((long long)b * 1024 + l) * 256 + tid] = acc;
}

// ------------- small helpers -------------
__global__ void pool_copy(const float* __restrict__ enc, float* __restrict__ fin, int off)
{
  int b = blockIdx.x, tid = threadIdx.x;
  fin[(long long)b * 768 + off + tid] = enc[((long long)b * 1024 + 1023) * 256 + tid];
}

__global__ void init_bias(float* __restrict__ C, const float* __restrict__ bias)
{
  C[(long long)blockIdx.x * 256 + threadIdx.x] = bias[threadIdx.x];
}

__global__ void rp2_kernel(const float* __restrict__ x, const float* __restrict__ w,
                           const float* __restrict__ bias, float* __restrict__ out)
{
  __shared__ float red[4];
  int b = blockIdx.x, tid = threadIdx.x;
  float p = x[b * 256 + tid] * w[tid];
#pragma unroll
  for (int o = 32; o > 0; o >>= 1) p += __shfl_down(p, o, 64);
  if ((tid & 63) == 0) red[tid >> 6] = p;
  __syncthreads();
  if (tid == 0) out[b] = red[0] + red[1] + red[2] + red[3] + bias[0];
}

// =========================== host launch ===========================
static inline void gemm(hipStream_t s, const float* A, const float* B, float* C,
                        int M, int N, int K, int shift, const float* bias,
                        const float* res, int flags, int splitz = 1)
{
  dim3 g((N + 63) / 64, (M + 63) / 64, splitz);
  gemm_f32<<<g, dim3(256), 0, s>>>(A, B, C, M, N, K, shift, bias, res, flags);
}

extern "C" void kernel_launch(void* const* d_in, const int* in_sizes, int n_in,
                              void* d_out, int out_size, void* d_ws, size_t ws_size,
                              hipStream_t stream)
{
  const float* x_enc  = (const float*)d_in[0];
  const float* conv1_w= (const float*)d_in[1];
  const float* conv1_b= (const float*)d_in[2];
  const float* conv2_w= (const float*)d_in[3];
  const float* conv2_b= (const float*)d_in[4];
  const float* cnn_g  = (const float*)d_in[5];
  const float* cnn_b  = (const float*)d_in[6];
  const float* proj_w = (const float*)d_in[7];
  const float* proj_b = (const float*)d_in[8];
  const float* pln_g  = (const float*)d_in[9];
  const float* pln_b  = (const float*)d_in[10];
  const float* Wq     = (const float*)d_in[11];
  const float* bq     = (const float*)d_in[12];
  const float* Wk     = (const float*)d_in[13];
  const float* bk     = (const float*)d_in[14];
  const float* Wv     = (const float*)d_in[15];
  const float* bv     = (const float*)d_in[16];
  const float* Wo     = (const float*)d_in[17];
  const float* bo     = (const float*)d_in[18];
  const float* Wff1   = (const float*)d_in[19];
  const float* Wff2   = (const float*)d_in[20];
  const float* rp1_w  = (const float*)d_in[21];
  const float* rp1_b  = (const float*)d_in[22];
  const float* rln_g  = (const float*)d_in[23];
  const float* rln_b  = (const float*)d_in[24];
  const float* rp2_w  = (const float*)d_in[25];
  const float* rp2_b  = (const float*)d_in[26];
  (void)in_sizes; (void)n_in;

  const size_t BLD = 64ull * 1024 * 256;
  size_t need;
  {
    size_t o = 3 * BLD + 3 * 16 * 256 + 3 * 256 * 256 + 2 * 65536
             + 64 * 1024 + 64 * 20 + 64 * 20 + 64 * 256 + 64 * 768 + 64 * 256 + 64 * 256;
    need = o * sizeof(float);
  }
  if (ws_size < need) {
    hipMemsetAsync(d_out, 0, (size_t)out_size * sizeof(float), stream);
    return;
  }

  float* ws = (float*)d_ws;
  size_t off = 0;
  auto alloc = [&](size_t n) { float* p = ws + off; off += n; return p; };
  float* BUF0 = alloc(BLD);
  float* BUF1 = alloc(BLD);
  float* BUF2 = alloc(BLD);
  float* CB1  = alloc(3 * 16 * 256);
  float* CB2T = alloc(3 * 256 * 256);
  float* WVT  = alloc(65536);
  float* WOT  = alloc(65536);
  float* MV   = alloc(64 * 1024);
  float* WTS  = alloc(64 * 20);
  int*   DLY  = (int*)alloc(64 * 20);
  float* PE   = alloc(64 * 256);
  float* FIN  = alloc(64 * 768);
  float* O1   = alloc(64 * 256);
  float* O2   = alloc(64 * 256);

  const int M = 65536;
  dim3 blk(256);

  convw_transpose<<<48, blk, 0, stream>>>(conv1_w, CB1, 16);
  convw2_bt<<<768, blk, 0, stream>>>(conv2_w, CB2T);

  // --- CNN frontend: conv1 fp32, conv2 bf16 MFMA (3 shifted taps, RMW-acc) ---
  for (int kk = 0; kk < 3; kk++)
    gemm(stream, x_enc, CB1 + kk * 4096, BUF0, M, 256, 16, kk - 1,
         kk == 0 ? conv1_b : nullptr, nullptr,
         (kk == 0 ? 0 : FLAG_ACC) | (kk == 2 ? FLAG_RELU : 0));
  fixup_conv<<<128, blk, 0, stream>>>(BUF0, x_enc, conv1_w, conv1_b, 16, 1);
  for (int kk = 0; kk < 3; kk++)
    gemm_bf16_bt<<<dim3(2, 512), blk, 0, stream>>>(
        BUF0, CB2T + kk * 65536, BUF1, nullptr,
        kk == 0 ? conv2_b : nullptr, M, 256, 256,
        (kk == 0 ? 0 : FLAG_ACC) | (kk == 2 ? FLAG_RELU : 0), kk - 1);
  fixup_conv<<<128, blk, 0, stream>>>(BUF1, BUF0, conv2_w, conv2_b, 256, 1);
  ln_rows<<<65536, blk, 0, stream>>>(BUF1, BUF2, cnn_g, cnn_b, 0, 256, 0);

  // --- encoder layers (enc in BUF2) ---
  for (int i = 0; i < 2; i++) {
    const float* Wq_i = Wq + (size_t)i * 65536;
    const float* Wk_i = Wk + (size_t)i * 65536;
    const float* Wv_i = Wv + (size_t)i * 65536;
    const float* Wo_i = Wo + (size_t)i * 65536;
    // q, k in fp32 (top-k path precision)
    gemm(stream, BUF2, Wq_i, BUF0, M, 256, 256, 0, bq + i * 256, nullptr, 0);
    gemm(stream, BUF2, Wk_i, BUF1, M, 256, 256, 0, bk + i * 256, nullptr, 0);
    hipMemsetAsync(MV, 0, 64 * 1024 * sizeof(float), stream);
    corr_mfma<<<dim3(8, 8, 64), blk, 0, stream>>>(BUF0, BUF1, MV);
    topk_softmax<<<64, blk, 0, stream>>>(MV, WTS, DLY);
    // v, o in bf16 MFMA (output path)
    transpose_kernel<<<256, blk, 0, stream>>>(Wv_i, WVT, 256, 256);
    transpose_kernel<<<256, blk, 0, stream>>>(Wo_i, WOT, 256, 256);
    gemm_bf16_bt<<<dim3(2, 512), blk, 0, stream>>>(
        BUF2, WVT, BUF0, nullptr, bv + i * 256, M, 256, 256, 0, 0);
    agg_kernel<<<dim3(1024, 64), blk, 0, stream>>>(BUF0, WTS, DLY, BUF1);
    gemm_bf16_bt<<<dim3(2, 512), blk, 0, stream>>>(
        BUF1, WOT, BUF0, BUF2, bo + i * 256, M, 256, 256, 0, 0);
    decomp_kernel<<<65536, blk, 0, stream>>>(BUF0, BUF1);   // xd -> BUF1
    // FFN (bf16 MFMA), 4 M-chunks; hidden fp32 in BUF2
    for (int c = 0; c < 4; c++) {
      const float* xd = BUF1 + (size_t)c * 16384 * 256;
      gemm_bf16_bt<<<dim3(8, 128), blk, 0, stream>>>(
          xd, Wff1 + (size_t)i * 262144, BUF2, nullptr, nullptr,
          16384, 1024, 256, FLAG_GELU, 0);
      gemm_bf16_bt<<<dim3(2, 128), blk, 0, stream>>>(
          BUF2, Wff2 + (size_t)i * 262144, BUF0 + (size_t)c * 16384 * 256, xd, nullptr,
          16384, 256, 1024, 0, 0);
    }
    decomp_kernel<<<65536, blk, 0, stream>>>(BUF0, BUF2);   // new enc -> BUF2
    pool_copy<<<64, blk, 0, stream>>>(BUF2, FIN, i * 256);
  }

  // --- head ---
  init_bias<<<64, blk, 0, stream>>>(PE, proj_b);
  gemm(stream, x_enc, proj_w, PE, 64, 256, 16384, 0, nullptr, nullptr, 0, 32);
  ln_rows<<<64, blk, 0, stream>>>(PE, FIN, pln_g, pln_b, 1, 768, 512);
  init_bias<<<64, blk, 0, stream>>>(O1, rp1_b);
  gemm(stream, FIN, rp1_w, O1, 64, 256, 768, 0, nullptr, nullptr, 0, 4);
  ln_rows<<<64, blk, 0, stream>>>(O1, O2, rln_g, rln_b, 1, 256, 0);
  rp2_kernel<<<64, blk, 0, stream>>>(O2, rp2_w, rp2_b, (float*)d_out);
}

// Round 6
// 2870.609 us; speedup vs baseline: 4.3131x; 1.3851x over previous
//
#include <hip/hip_runtime.h>
#include <math.h>

#define FLAG_ACC  1
#define FLAG_RELU 2
#define FLAG_GELU 4

typedef __attribute__((ext_vector_type(8))) short short8;
typedef __attribute__((ext_vector_type(4))) short short4v;
typedef __attribute__((ext_vector_type(4))) float f32x4;

__device__ __forceinline__ short f2bf(float f) {
  unsigned u = __builtin_bit_cast(unsigned, f);
  unsigned r = u + 0x7fffu + ((u >> 16) & 1u);
  return (short)(r >> 16);
}
__device__ __forceinline__ float bf2f(short s) {
  unsigned u = ((unsigned)(unsigned short)s) << 16;
  return __builtin_bit_cast(float, u);
}

// ---------------- generic fp32 tiled GEMM (head path only) ----------------
__global__ __launch_bounds__(256) void gemm_f32(
    const float* __restrict__ A, const float* __restrict__ B, float* __restrict__ C,
    int M, int N, int K, int a_shift,
    const float* __restrict__ bias, const float* __restrict__ residual, int flags)
{
  __shared__ float As[16][65];
  __shared__ float Bs[16][64];
  const int tid = threadIdx.x;
  const int tx = tid & 15, ty = tid >> 4;
  const int row0 = blockIdx.y * 64;
  const int col0 = blockIdx.x * 64;
  int kbeg = 0, kend = K;
  if ((int)gridDim.z > 1) {
    int kchunk = ((K + (int)gridDim.z - 1) / (int)gridDim.z + 15) & ~15;
    kbeg = (int)blockIdx.z * kchunk;
    kend = min(K, kbeg + kchunk);
  }
  float acc[4][4] = {};
  const int a_m = tid >> 2;
  const int a_k = (tid & 3) << 2;
  const int b_n = (tid & 15) << 2;
  const int b_k = tid >> 4;
  for (int k0 = kbeg; k0 < kend; k0 += 16) {
    int srow = row0 + a_m + a_shift;
    float4 av = make_float4(0.f, 0.f, 0.f, 0.f);
    if (srow >= 0 && srow < M)
      av = *reinterpret_cast<const float4*>(A + (long long)srow * K + (k0 + a_k));
    As[a_k + 0][a_m] = av.x; As[a_k + 1][a_m] = av.y;
    As[a_k + 2][a_m] = av.z; As[a_k + 3][a_m] = av.w;
    float4 bv = make_float4(0.f, 0.f, 0.f, 0.f);
    int brow = k0 + b_k;
    if (brow < K)
      bv = *reinterpret_cast<const float4*>(B + (long long)brow * N + (col0 + b_n));
    Bs[b_k][b_n + 0] = bv.x; Bs[b_k][b_n + 1] = bv.y;
    Bs[b_k][b_n + 2] = bv.z; Bs[b_k][b_n + 3] = bv.w;
    __syncthreads();
#pragma unroll
    for (int kk = 0; kk < 16; kk++) {
      float ar[4], br[4];
#pragma unroll
      for (int i = 0; i < 4; i++) ar[i] = As[kk][ty * 4 + i];
#pragma unroll
      for (int j = 0; j < 4; j++) br[j] = Bs[kk][tx * 4 + j];
#pragma unroll
      for (int i = 0; i < 4; i++)
#pragma unroll
        for (int j = 0; j < 4; j++)
          acc[i][j] += ar[i] * br[j];
    }
    __syncthreads();
  }
  if ((int)gridDim.z > 1) {
#pragma unroll
    for (int i = 0; i < 4; i++) {
      int r = row0 + ty * 4 + i; if (r >= M) continue;
#pragma unroll
      for (int j = 0; j < 4; j++) {
        int c = col0 + tx * 4 + j; if (c >= N) continue;
        atomicAdd(&C[(long long)r * N + c], acc[i][j]);
      }
    }
    return;
  }
#pragma unroll
  for (int i = 0; i < 4; i++) {
    int r = row0 + ty * 4 + i; if (r >= M) continue;
#pragma unroll
    for (int j = 0; j < 4; j++) {
      int c = col0 + tx * 4 + j; if (c >= N) continue;
      float v = acc[i][j];
      if (bias)     v += bias[c];
      if (residual) v += residual[(long long)r * N + c];
      if (flags & FLAG_ACC)  v += C[(long long)r * N + c];
      if (flags & FLAG_RELU) v = fmaxf(v, 0.f);
      if (flags & FLAG_GELU) v = 0.5f * v * (1.f + erff(v * 0.70710678118654752f));
      C[(long long)r * N + c] = v;
    }
  }
}

// ---------------- bf16 MFMA GEMM: C[M,N] = A[M,K] @ Bt[N,K]^T ----------------------
__global__ __launch_bounds__(256) void gemm_bf16_bt(
    const float* __restrict__ A, const float* __restrict__ Bt, float* __restrict__ C,
    const float* __restrict__ residual, const float* __restrict__ bias,
    int M, int N, int K, int flags, int a_shift)
{
  __shared__ short Asl[128][40];
  __shared__ short Bsl[128][40];
  const int tid = threadIdx.x;
  const int row0 = blockIdx.y * 128;
  const int col0 = blockIdx.x * 128;
  const int lane = tid & 63;
  const int wave = tid >> 6;
  const int wm = (wave >> 1) * 64;
  const int wn = (wave & 1) * 64;
  const int fm = lane & 15;
  const int k8 = (lane >> 4) * 8;
  const int srow = tid >> 1;
  const int scol = (tid & 1) * 16;
  const int arow = row0 + srow + a_shift;
  const bool avalid = (arow >= 0 && arow < M);

  f32x4 acc[4][4] = {};
  for (int k0 = 0; k0 < K; k0 += 32) {
    __syncthreads();
    {
      const float* ga = A + (long long)arow * K + k0 + scol;
      const float* gb = Bt + (long long)(col0 + srow) * K + k0 + scol;
#pragma unroll
      for (int u = 0; u < 2; u++) {
        float4 f0 = make_float4(0.f, 0.f, 0.f, 0.f), f1 = f0;
        if (avalid) { f0 = *(const float4*)(ga + u * 8); f1 = *(const float4*)(ga + u * 8 + 4); }
        short8 v;
        v[0] = f2bf(f0.x); v[1] = f2bf(f0.y); v[2] = f2bf(f0.z); v[3] = f2bf(f0.w);
        v[4] = f2bf(f1.x); v[5] = f2bf(f1.y); v[6] = f2bf(f1.z); v[7] = f2bf(f1.w);
        *(short8*)&Asl[srow][scol + u * 8] = v;
        float4 g0 = *(const float4*)(gb + u * 8);
        float4 g1 = *(const float4*)(gb + u * 8 + 4);
        short8 w;
        w[0] = f2bf(g0.x); w[1] = f2bf(g0.y); w[2] = f2bf(g0.z); w[3] = f2bf(g0.w);
        w[4] = f2bf(g1.x); w[5] = f2bf(g1.y); w[6] = f2bf(g1.z); w[7] = f2bf(g1.w);
        *(short8*)&Bsl[srow][scol + u * 8] = w;
      }
    }
    __syncthreads();
    short8 af[4], bf[4];
#pragma unroll
    for (int i = 0; i < 4; i++) af[i] = *(short8*)&Asl[wm + i * 16 + fm][k8];
#pragma unroll
    for (int j = 0; j < 4; j++) bf[j] = *(short8*)&Bsl[wn + j * 16 + fm][k8];
#pragma unroll
    for (int i = 0; i < 4; i++)
#pragma unroll
      for (int j = 0; j < 4; j++)
        acc[i][j] = __builtin_amdgcn_mfma_f32_16x16x32_bf16(af[i], bf[j], acc[i][j], 0, 0, 0);
  }
#pragma unroll
  for (int i = 0; i < 4; i++) {
    const int mbase = row0 + wm + i * 16 + (lane >> 4) * 4;
#pragma unroll
    for (int j = 0; j < 4; j++) {
      const int n = col0 + wn + j * 16 + fm;
      const float bs = bias ? bias[n] : 0.f;
#pragma unroll
      for (int r = 0; r < 4; r++) {
        long long idx = (long long)(mbase + r) * N + n;
        float v = acc[i][j][r] + bs;
        if (residual) v += residual[idx];
        if (flags & FLAG_ACC)  v += C[idx];
        if (flags & FLAG_RELU) v = fmaxf(v, 0.f);
        if (flags & FLAG_GELU) v = 0.5f * v * (1.f + erff(v * 0.70710678118654752f));
        C[idx] = v;
      }
    }
  }
}

// ---------------- bf16x3 split MFMA GEMM (high precision): C = A @ Bt^T + bias -----
// A = Ah+Al, Bt = Bh+Bl (bf16 RNE splits); C ~= Ah*Bh + Ah*Bl + Al*Bh, rel err ~1.5e-5.
// Used for q/k projections feeding the top-k path. M%128==0, N%128==0, K%32==0.
__global__ __launch_bounds__(256) void gemm_bf16x3_bt(
    const float* __restrict__ A, const float* __restrict__ Bt, float* __restrict__ C,
    const float* __restrict__ bias, int M, int N, int K)
{
  __shared__ __align__(16) char smem[40960];
  short (*Ahi)[40] = (short(*)[40])(smem);
  short (*Alo)[40] = (short(*)[40])(smem + 10240);
  short (*Bhi)[40] = (short(*)[40])(smem + 20480);
  short (*Blo)[40] = (short(*)[40])(smem + 30720);
  const int tid = threadIdx.x;
  const int row0 = blockIdx.y * 128;
  const int col0 = blockIdx.x * 128;
  const int lane = tid & 63;
  const int wave = tid >> 6;
  const int wm = (wave >> 1) * 64;
  const int wn = (wave & 1) * 64;
  const int fm = lane & 15;
  const int k8 = (lane >> 4) * 8;
  const int srow = tid >> 1;
  const int scol = (tid & 1) * 16;
  const float* ga0 = A + (long long)(row0 + srow) * K + scol;
  const float* gb0 = Bt + (long long)(col0 + srow) * K + scol;

  f32x4 acc[4][4] = {};
  for (int k0 = 0; k0 < K; k0 += 32) {
    __syncthreads();
#pragma unroll
    for (int u = 0; u < 4; u++) {
      float4 f = *(const float4*)(ga0 + k0 + u * 4);
      short4v h, l;
      h[0] = f2bf(f.x); h[1] = f2bf(f.y); h[2] = f2bf(f.z); h[3] = f2bf(f.w);
      l[0] = f2bf(f.x - bf2f(h[0])); l[1] = f2bf(f.y - bf2f(h[1]));
      l[2] = f2bf(f.z - bf2f(h[2])); l[3] = f2bf(f.w - bf2f(h[3]));
      *(short4v*)&Ahi[srow][scol + u * 4] = h;
      *(short4v*)&Alo[srow][scol + u * 4] = l;
      float4 g = *(const float4*)(gb0 + k0 + u * 4);
      short4v hb, lb;
      hb[0] = f2bf(g.x); hb[1] = f2bf(g.y); hb[2] = f2bf(g.z); hb[3] = f2bf(g.w);
      lb[0] = f2bf(g.x - bf2f(hb[0])); lb[1] = f2bf(g.y - bf2f(hb[1]));
      lb[2] = f2bf(g.z - bf2f(hb[2])); lb[3] = f2bf(g.w - bf2f(hb[3]));
      *(short4v*)&Bhi[srow][scol + u * 4] = hb;
      *(short4v*)&Blo[srow][scol + u * 4] = lb;
    }
    __syncthreads();
    short8 ah[4], al[4], bh[4], bl[4];
#pragma unroll
    for (int i = 0; i < 4; i++) {
      ah[i] = *(short8*)&Ahi[wm + i * 16 + fm][k8];
      al[i] = *(short8*)&Alo[wm + i * 16 + fm][k8];
    }
#pragma unroll
    for (int j = 0; j < 4; j++) {
      bh[j] = *(short8*)&Bhi[wn + j * 16 + fm][k8];
      bl[j] = *(short8*)&Blo[wn + j * 16 + fm][k8];
    }
#pragma unroll
    for (int i = 0; i < 4; i++)
#pragma unroll
      for (int j = 0; j < 4; j++) {
        acc[i][j] = __builtin_amdgcn_mfma_f32_16x16x32_bf16(ah[i], bh[j], acc[i][j], 0, 0, 0);
        acc[i][j] = __builtin_amdgcn_mfma_f32_16x16x32_bf16(ah[i], bl[j], acc[i][j], 0, 0, 0);
        acc[i][j] = __builtin_amdgcn_mfma_f32_16x16x32_bf16(al[i], bh[j], acc[i][j], 0, 0, 0);
      }
  }
#pragma unroll
  for (int i = 0; i < 4; i++) {
    const int mbase = row0 + wm + i * 16 + (lane >> 4) * 4;
#pragma unroll
    for (int j = 0; j < 4; j++) {
      const int n = col0 + wn + j * 16 + fm;
      const float bs = bias ? bias[n] : 0.f;
#pragma unroll
      for (int r = 0; r < 4; r++)
        C[(long long)(mbase + r) * N + n] = acc[i][j][r] + bs;
    }
  }
}

// ------------- circular-correlation mean via split-bf16 MFMA --------------------
__global__ __launch_bounds__(256) void corr_mfma(
    const float* __restrict__ q, const float* __restrict__ k, float* __restrict__ mv)
{
  __shared__ __align__(16) char smem[65536];
  short (*Ahi)[40] = (short(*)[40])(smem);
  short (*Alo)[40] = (short(*)[40])(smem + 10240);
  short (*Bhi)[40] = (short(*)[40])(smem + 20480);
  short (*Blo)[40] = (short(*)[40])(smem + 30720);
  float* Sf = (float*)smem;

  const int b  = blockIdx.z;
  const int t0 = blockIdx.y * 128;
  const int s0 = blockIdx.x * 128;
  const int tid = threadIdx.x;
  const int lane = tid & 63;
  const int wave = tid >> 6;
  const int wm = (wave >> 1) * 64;
  const int wn = (wave & 1) * 64;
  const int fm = lane & 15;
  const int k8 = (lane >> 4) * 8;
  const int srow = tid >> 1;
  const int scol = (tid & 1) * 16;
  const float* gq0 = q + (long long)b * 262144 + (long long)(t0 + srow) * 256 + scol;
  const float* gk0 = k + (long long)b * 262144 + (long long)(s0 + srow) * 256 + scol;

  f32x4 acc[4][4] = {};
  for (int k0 = 0; k0 < 256; k0 += 32) {
    __syncthreads();
#pragma unroll
    for (int u = 0; u < 4; u++) {
      float4 f = *(const float4*)(gq0 + k0 + u * 4);
      short4v h, l;
      h[0] = f2bf(f.x); h[1] = f2bf(f.y); h[2] = f2bf(f.z); h[3] = f2bf(f.w);
      l[0] = f2bf(f.x - bf2f(h[0])); l[1] = f2bf(f.y - bf2f(h[1]));
      l[2] = f2bf(f.z - bf2f(h[2])); l[3] = f2bf(f.w - bf2f(h[3]));
      *(short4v*)&Ahi[srow][scol + u * 4] = h;
      *(short4v*)&Alo[srow][scol + u * 4] = l;
      float4 g = *(const float4*)(gk0 + k0 + u * 4);
      short4v hb, lb;
      hb[0] = f2bf(g.x); hb[1] = f2bf(g.y); hb[2] = f2bf(g.z); hb[3] = f2bf(g.w);
      lb[0] = f2bf(g.x - bf2f(hb[0])); lb[1] = f2bf(g.y - bf2f(hb[1]));
      lb[2] = f2bf(g.z - bf2f(hb[2])); lb[3] = f2bf(g.w - bf2f(hb[3]));
      *(short4v*)&Bhi[srow][scol + u * 4] = hb;
      *(short4v*)&Blo[srow][scol + u * 4] = lb;
    }
    __syncthreads();
    short8 ah[4], al[4], bh[4], bl[4];
#pragma unroll
    for (int i = 0; i < 4; i++) {
      ah[i] = *(short8*)&Ahi[wm + i * 16 + fm][k8];
      al[i] = *(short8*)&Alo[wm + i * 16 + fm][k8];
    }
#pragma unroll
    for (int j = 0; j < 4; j++) {
      bh[j] = *(short8*)&Bhi[wn + j * 16 + fm][k8];
      bl[j] = *(short8*)&Blo[wn + j * 16 + fm][k8];
    }
#pragma unroll
    for (int i = 0; i < 4; i++)
#pragma unroll
      for (int j = 0; j < 4; j++) {
        acc[i][j] = __builtin_amdgcn_mfma_f32_16x16x32_bf16(ah[i], bh[j], acc[i][j], 0, 0, 0);
        acc[i][j] = __builtin_amdgcn_mfma_f32_16x16x32_bf16(ah[i], bl[j], acc[i][j], 0, 0, 0);
        acc[i][j] = __builtin_amdgcn_mfma_f32_16x16x32_bf16(al[i], bh[j], acc[i][j], 0, 0, 0);
      }
  }
  __syncthreads();
#pragma unroll
  for (int i = 0; i < 4; i++) {
    const int row = wm + i * 16 + (lane >> 4) * 4;
#pragma unroll
    for (int j = 0; j < 4; j++) {
      const int col = wn + j * 16 + fm;
#pragma unroll
      for (int r = 0; r < 4; r++)
        Sf[(row + r) * 128 + col] = acc[i][j][r] * (1.f / 256.f);
    }
  }
  __syncthreads();
  if (tid < 255) {
    const int delta = tid - 127;
    const int mlo = delta > 0 ? delta : 0;
    const int mhi = 128 + (delta < 0 ? delta : 0);
    float ssum = 0.f;
    for (int m = mlo; m < mhi; m++) ssum += Sf[m * 128 + (m - delta)];
    const int tau = (t0 - s0 + delta) & 1023;
    atomicAdd(&mv[b * 1024 + tau], ssum);
  }
}

// ------------- conv1 direct: x[64,1024,16] -> relu(conv1d(x)) [64*1024,256] --------
// grid (16 lgroups, 64 batches), 256 threads (one per out channel), zero-pad edges.
__global__ __launch_bounds__(256) void conv1_direct(
    const float* __restrict__ x, const float* __restrict__ w,
    const float* __restrict__ bias, float* __restrict__ out)
{
  __shared__ float xs[66][16];
  const int b = blockIdx.y, lg = blockIdx.x, tid = threadIdx.x;
  const int l0 = lg * 64;
  for (int idx = tid; idx < 1056; idx += 256) {
    int r = idx >> 4, c = idx & 15;
    int l = l0 + r - 1;
    xs[r][c] = (l >= 0 && l < 1024) ? x[((long long)b * 1024 + l) * 16 + c] : 0.f;
  }
  float wr[48];
#pragma unroll
  for (int u = 0; u < 48; u++) wr[u] = w[tid * 48 + u];   // w[o][i][t] contiguous
  const float bs = bias[tid];
  __syncthreads();
  for (int r = 0; r < 64; r++) {
    float acc = bs;
#pragma unroll
    for (int i = 0; i < 16; i++) {
      acc += xs[r + 0][i] * wr[i * 3 + 0];
      acc += xs[r + 1][i] * wr[i * 3 + 1];
      acc += xs[r + 2][i] * wr[i * 3 + 2];
    }
    out[((long long)b * 1024 + l0 + r) * 256 + tid] = fmaxf(acc, 0.f);
  }
}

// ------------- conv2 tap extraction: w[o][i][kk] -> out[kk][o][i]  (Bt layout) -----
__global__ void convw2_bt(const float* __restrict__ w, float* __restrict__ out)
{
  for (int idx = blockIdx.x * 256 + threadIdx.x; idx < 196608;
       idx += gridDim.x * 256) {
    int kk = idx >> 16;
    int o = (idx >> 8) & 255;
    int i = idx & 255;
    out[idx] = w[(o * 256 + i) * 3 + kk];
  }
}

// ------------- generic transpose: in[R][Cc] -> out[Cc][R] -------------
__global__ void transpose_kernel(const float* __restrict__ in, float* __restrict__ out,
                                 int R, int Cc)
{
  long long total = (long long)R * Cc;
  for (long long i = blockIdx.x * 256LL + threadIdx.x; i < total;
       i += (long long)gridDim.x * 256LL) {
    int r = (int)(i / Cc), c = (int)(i % Cc);
    out[(long long)c * R + r] = in[i];
  }
}

// ------------- conv batch-boundary fixup: recompute rows l=0 and l=1023 ------------
__global__ void fixup_conv(float* __restrict__ h, const float* __restrict__ src,
                           const float* __restrict__ w, const float* __restrict__ bias,
                           int I, int do_relu)
{
  int b = blockIdx.x >> 1;
  int l = (blockIdx.x & 1) ? 1023 : 0;
  int o = threadIdx.x;
  float acc = bias[o];
  for (int kk = 0; kk < 3; kk++) {
    int t = l + kk - 1;
    if (t < 0 || t > 1023) continue;
    const float* srow = src + ((long long)b * 1024 + t) * I;
    const float* wrow = w + (long long)o * I * 3 + kk;
    for (int i = 0; i < I; i++) acc += srow[i] * wrow[(long long)i * 3];
  }
  if (do_relu) acc = fmaxf(acc, 0.f);
  h[((long long)b * 1024 + l) * 256 + o] = acc;
}

// ------------- LayerNorm over 256 channels -------------
__global__ __launch_bounds__(256) void ln_rows(
    const float* __restrict__ in, float* __restrict__ out,
    const float* __restrict__ g, const float* __restrict__ b,
    int prerelu, int out_stride, int out_off)
{
  __shared__ float red[4];
  int row = blockIdx.x, tid = threadIdx.x;
  float x = in[(long long)row * 256 + tid];
  if (prerelu) x = fmaxf(x, 0.f);
  float s = x;
#pragma unroll
  for (int o = 32; o > 0; o >>= 1) s += __shfl_down(s, o, 64);
  if ((tid & 63) == 0) red[tid >> 6] = s;
  __syncthreads();
  float mean = (red[0] + red[1] + red[2] + red[3]) * (1.f / 256.f);
  float d = x - mean;
  float s2 = d * d;
#pragma unroll
  for (int o = 32; o > 0; o >>= 1) s2 += __shfl_down(s2, o, 64);
  __syncthreads();
  if ((tid & 63) == 0) red[tid >> 6] = s2;
  __syncthreads();
  float var = (red[0] + red[1] + red[2] + red[3]) * (1.f / 256.f);
  out[(long long)row * out_stride + out_off + tid] =
      d * rsqrtf(var + 1e-5f) * g[tid] + b[tid];
}

// ------------- series_decomp -------------
__global__ void decomp_kernel(const float* __restrict__ in, float* __restrict__ out)
{
  int idx = blockIdx.x * 256 + threadIdx.x;
  int c = idx & 255;
  int bl = idx >> 8;
  int l = bl & 1023;
  int bbase = (bl >> 10) << 18;
  const float* base = in + bbase + c;
  float s = 0.f;
#pragma unroll
  for (int j = -12; j <= 12; j++) {
    int t = l + j;
    t = t < 0 ? 0 : (t > 1023 ? 1023 : t);
    s += base[t << 8];
  }
  out[idx] = in[idx] - s * (1.f / 25.f);
}

// ------------- top-20 + softmax, one wave per batch (no barriers) -------------
__global__ __launch_bounds__(64) void topk_softmax_wave(
    const float* __restrict__ mv, float* __restrict__ wts, int* __restrict__ dly)
{
  const int b = blockIdx.x, lane = threadIdx.x;
  float v[16];
#pragma unroll
  for (int j = 0; j < 16; j++) v[j] = mv[b * 1024 + lane + 64 * j];
  float selv = 0.f; int seli = 0;
  for (int it = 0; it < 20; it++) {
    float bv = -1e30f; int bi = 0x7fffffff;
#pragma unroll
    for (int j = 0; j < 16; j++) {
      float x = v[j]; int idx = lane + 64 * j;
      if (x > bv || (x == bv && idx < bi)) { bv = x; bi = idx; }
    }
#pragma unroll
    for (int off = 32; off > 0; off >>= 1) {
      float ov = __shfl_xor(bv, off, 64);
      int   oi = __shfl_xor(bi, off, 64);
      if (ov > bv || (ov == bv && oi < bi)) { bv = ov; bi = oi; }
    }
    if (lane == it) { selv = bv; seli = bi; }
    if ((bi & 63) == lane) v[bi >> 6] = -1e30f;   // bi>>6 uniform per lane hit
  }
  const float w0 = __shfl(selv, 0, 64);
  float e = (lane < 20) ? __expf(selv - w0) : 0.f;
  float s = e;
#pragma unroll
  for (int off = 32; off > 0; off >>= 1) s += __shfl_xor(s, off, 64);
  if (lane < 20) {
    wts[b * 20 + lane] = e / s;
    dly[b * 20 + lane] = seli;
  }
}

// ------------- delay aggregation -------------
__global__ void agg_kernel(const float* __restrict__ v, const float* __restrict__ wts,
                           const int* __restrict__ dly, float* __restrict__ out)
{
  int b = blockIdx.y, l = blockIdx.x, tid = threadIdx.x;
  const float* vb = v + (long long)b * 1024 * 256;
  float acc = 0.f;
  for (int kk = 0; kk < 20; kk++) {
    int d = dly[b * 20 + kk];
    float w = wts[b * 20 + kk];
    acc += w * vb[(long long)((l + d) & 1023) * 256 + tid];
  }
  out[((long long)b * 1024 + l) * 256 + tid] = acc;
}

// ------------- small helpers -------------
__global__ void pool_copy(const float* __restrict__ enc, float* __restrict__ fin, int off)
{
  int b = blockIdx.x, tid = threadIdx.x;
  fin[(long long)b * 768 + off + tid] = enc[((long long)b * 1024 + 1023) * 256 + tid];
}

__global__ void init_bias(float* __restrict__ C, const float* __restrict__ bias)
{
  C[(long long)blockIdx.x * 256 + threadIdx.x] = bias[threadIdx.x];
}

__global__ void rp2_kernel(const float* __restrict__ x, const float* __restrict__ w,
                           const float* __restrict__ bias, float* __restrict__ out)
{
  __shared__ float red[4];
  int b = blockIdx.x, tid = threadIdx.x;
  float p = x[b * 256 + tid] * w[tid];
#pragma unroll
  for (int o = 32; o > 0; o >>= 1) p += __shfl_down(p, o, 64);
  if ((tid & 63) == 0) red[tid >> 6] = p;
  __syncthreads();
  if (tid == 0) out[b] = red[0] + red[1] + red[2] + red[3] + bias[0];
}

// =========================== host launch ===========================
static inline void gemm(hipStream_t s, const float* A, const float* B, float* C,
                        int M, int N, int K, int shift, const float* bias,
                        const float* res, int flags, int splitz = 1)
{
  dim3 g((N + 63) / 64, (M + 63) / 64, splitz);
  gemm_f32<<<g, dim3(256), 0, s>>>(A, B, C, M, N, K, shift, bias, res, flags);
}

extern "C" void kernel_launch(void* const* d_in, const int* in_sizes, int n_in,
                              void* d_out, int out_size, void* d_ws, size_t ws_size,
                              hipStream_t stream)
{
  const float* x_enc  = (const float*)d_in[0];
  const float* conv1_w= (const float*)d_in[1];
  const float* conv1_b= (const float*)d_in[2];
  const float* conv2_w= (const float*)d_in[3];
  const float* conv2_b= (const float*)d_in[4];
  const float* cnn_g  = (const float*)d_in[5];
  const float* cnn_b  = (const float*)d_in[6];
  const float* proj_w = (const float*)d_in[7];
  const float* proj_b = (const float*)d_in[8];
  const float* pln_g  = (const float*)d_in[9];
  const float* pln_b  = (const float*)d_in[10];
  const float* Wq     = (const float*)d_in[11];
  const float* bq     = (const float*)d_in[12];
  const float* Wk     = (const float*)d_in[13];
  const float* bk     = (const float*)d_in[14];
  const float* Wv     = (const float*)d_in[15];
  const float* bv     = (const float*)d_in[16];
  const float* Wo     = (const float*)d_in[17];
  const float* bo     = (const float*)d_in[18];
  const float* Wff1   = (const float*)d_in[19];
  const float* Wff2   = (const float*)d_in[20];
  const float* rp1_w  = (const float*)d_in[21];
  const float* rp1_b  = (const float*)d_in[22];
  const float* rln_g  = (const float*)d_in[23];
  const float* rln_b  = (const float*)d_in[24];
  const float* rp2_w  = (const float*)d_in[25];
  const float* rp2_b  = (const float*)d_in[26];
  (void)in_sizes; (void)n_in;

  const size_t BLD = 64ull * 1024 * 256;
  size_t need;
  {
    size_t o = 3 * BLD + 3 * 256 * 256 + 4 * 65536
             + 64 * 1024 + 64 * 20 + 64 * 20 + 64 * 256 + 64 * 768 + 64 * 256 + 64 * 256;
    need = o * sizeof(float);
  }
  if (ws_size < need) {
    hipMemsetAsync(d_out, 0, (size_t)out_size * sizeof(float), stream);
    return;
  }

  float* ws = (float*)d_ws;
  size_t off = 0;
  auto alloc = [&](size_t n) { float* p = ws + off; off += n; return p; };
  float* BUF0 = alloc(BLD);
  float* BUF1 = alloc(BLD);
  float* BUF2 = alloc(BLD);
  float* CB2T = alloc(3 * 256 * 256);
  float* WQT  = alloc(65536);
  float* WKT  = alloc(65536);
  float* WVT  = alloc(65536);
  float* WOT  = alloc(65536);
  float* MV   = alloc(64 * 1024);
  float* WTS  = alloc(64 * 20);
  int*   DLY  = (int*)alloc(64 * 20);
  float* PE   = alloc(64 * 256);
  float* FIN  = alloc(64 * 768);
  float* O1   = alloc(64 * 256);
  float* O2   = alloc(64 * 256);

  const int M = 65536;
  dim3 blk(256);

  convw2_bt<<<768, blk, 0, stream>>>(conv2_w, CB2T);

  // --- CNN frontend: conv1 direct fp32, conv2 bf16 MFMA taps + fp32 edge fixup ---
  conv1_direct<<<dim3(16, 64), blk, 0, stream>>>(x_enc, conv1_w, conv1_b, BUF0);
  for (int kk = 0; kk < 3; kk++)
    gemm_bf16_bt<<<dim3(2, 512), blk, 0, stream>>>(
        BUF0, CB2T + kk * 65536, BUF1, nullptr,
        kk == 0 ? conv2_b : nullptr, M, 256, 256,
        (kk == 0 ? 0 : FLAG_ACC) | (kk == 2 ? FLAG_RELU : 0), kk - 1);
  fixup_conv<<<128, blk, 0, stream>>>(BUF1, BUF0, conv2_w, conv2_b, 256, 1);
  ln_rows<<<65536, blk, 0, stream>>>(BUF1, BUF2, cnn_g, cnn_b, 0, 256, 0);

  // --- encoder layers (enc in BUF2) ---
  for (int i = 0; i < 2; i++) {
    const float* Wq_i = Wq + (size_t)i * 65536;
    const float* Wk_i = Wk + (size_t)i * 65536;
    const float* Wv_i = Wv + (size_t)i * 65536;
    const float* Wo_i = Wo + (size_t)i * 65536;
    // q, k via bf16x3 split MFMA (rel err ~1.5e-5 -> top-k safe)
    transpose_kernel<<<256, blk, 0, stream>>>(Wq_i, WQT, 256, 256);
    transpose_kernel<<<256, blk, 0, stream>>>(Wk_i, WKT, 256, 256);
    gemm_bf16x3_bt<<<dim3(2, 512), blk, 0, stream>>>(
        BUF2, WQT, BUF0, bq + i * 256, M, 256, 256);
    gemm_bf16x3_bt<<<dim3(2, 512), blk, 0, stream>>>(
        BUF2, WKT, BUF1, bk + i * 256, M, 256, 256);
    hipMemsetAsync(MV, 0, 64 * 1024 * sizeof(float), stream);
    corr_mfma<<<dim3(8, 8, 64), blk, 0, stream>>>(BUF0, BUF1, MV);
    topk_softmax_wave<<<64, dim3(64), 0, stream>>>(MV, WTS, DLY);
    // v, o in bf16 MFMA (output path)
    transpose_kernel<<<256, blk, 0, stream>>>(Wv_i, WVT, 256, 256);
    transpose_kernel<<<256, blk, 0, stream>>>(Wo_i, WOT, 256, 256);
    gemm_bf16_bt<<<dim3(2, 512), blk, 0, stream>>>(
        BUF2, WVT, BUF0, nullptr, bv + i * 256, M, 256, 256, 0, 0);
    agg_kernel<<<dim3(1024, 64), blk, 0, stream>>>(BUF0, WTS, DLY, BUF1);
    gemm_bf16_bt<<<dim3(2, 512), blk, 0, stream>>>(
        BUF1, WOT, BUF0, BUF2, bo + i * 256, M, 256, 256, 0, 0);
    decomp_kernel<<<65536, blk, 0, stream>>>(BUF0, BUF1);   // xd -> BUF1
    // FFN (bf16 MFMA), 4 M-chunks; hidden fp32 in BUF2
    for (int c = 0; c < 4; c++) {
      const float* xd = BUF1 + (size_t)c * 16384 * 256;
      gemm_bf16_bt<<<dim3(8, 128), blk, 0, stream>>>(
          xd, Wff1 + (size_t)i * 262144, BUF2, nullptr, nullptr,
          16384, 1024, 256, FLAG_GELU, 0);
      gemm_bf16_bt<<<dim3(2, 128), blk, 0, stream>>>(
          BUF2, Wff2 + (size_t)i * 262144, BUF0 + (size_t)c * 16384 * 256, xd, nullptr,
          16384, 256, 1024, 0, 0);
    }
    decomp_kernel<<<65536, blk, 0, stream>>>(BUF0, BUF2);   // new enc -> BUF2
    pool_copy<<<64, blk, 0, stream>>>(BUF2, FIN, i * 256);
  }

  // --- head (fp32, exact) ---
  init_bias<<<64, blk, 0, stream>>>(PE, proj_b);
  gemm(stream, x_enc, proj_w, PE, 64, 256, 16384, 0, nullptr, nullptr, 0, 32);
  ln_rows<<<64, blk, 0, stream>>>(PE, FIN, pln_g, pln_b, 1, 768, 512);
  init_bias<<<64, blk, 0, stream>>>(O1, rp1_b);
  gemm(stream, FIN, rp1_w, O1, 64, 256, 768, 0, nullptr, nullptr, 0, 4);
  ln_rows<<<64, blk, 0, stream>>>(O1, O2, rln_g, rln_b, 1, 256, 0);
  rp2_kernel<<<64, blk, 0, stream>>>(O2, rp2_w, rp2_b, (float*)d_out);
}

// Round 7
// 2370.080 us; speedup vs baseline: 5.2240x; 1.2112x over previous
//
#include <hip/hip_runtime.h>
#include <math.h>

#define FLAG_ACC    1
#define FLAG_RELU   2
#define FLAG_GELU   4
#define FLAG_ABF16  8
#define FLAG_OBF16 16

typedef __attribute__((ext_vector_type(8))) short short8;
typedef __attribute__((ext_vector_type(4))) short short4v;
typedef __attribute__((ext_vector_type(4))) float f32x4;

__device__ __forceinline__ short f2bf(float f) {
  unsigned u = __builtin_bit_cast(unsigned, f);
  unsigned r = u + 0x7fffu + ((u >> 16) & 1u);
  return (short)(r >> 16);
}
__device__ __forceinline__ float bf2f(short s) {
  unsigned u = ((unsigned)(unsigned short)s) << 16;
  return __builtin_bit_cast(float, u);
}

// ---------------- generic fp32 tiled GEMM (head path only) ----------------
__global__ __launch_bounds__(256) void gemm_f32(
    const float* __restrict__ A, const float* __restrict__ B, float* __restrict__ C,
    int M, int N, int K, int a_shift,
    const float* __restrict__ bias, const float* __restrict__ residual, int flags)
{
  __shared__ float As[16][65];
  __shared__ float Bs[16][64];
  const int tid = threadIdx.x;
  const int tx = tid & 15, ty = tid >> 4;
  const int row0 = blockIdx.y * 64;
  const int col0 = blockIdx.x * 64;
  int kbeg = 0, kend = K;
  if ((int)gridDim.z > 1) {
    int kchunk = ((K + (int)gridDim.z - 1) / (int)gridDim.z + 15) & ~15;
    kbeg = (int)blockIdx.z * kchunk;
    kend = min(K, kbeg + kchunk);
  }
  float acc[4][4] = {};
  const int a_m = tid >> 2;
  const int a_k = (tid & 3) << 2;
  const int b_n = (tid & 15) << 2;
  const int b_k = tid >> 4;
  for (int k0 = kbeg; k0 < kend; k0 += 16) {
    int srow = row0 + a_m + a_shift;
    float4 av = make_float4(0.f, 0.f, 0.f, 0.f);
    if (srow >= 0 && srow < M)
      av = *reinterpret_cast<const float4*>(A + (long long)srow * K + (k0 + a_k));
    As[a_k + 0][a_m] = av.x; As[a_k + 1][a_m] = av.y;
    As[a_k + 2][a_m] = av.z; As[a_k + 3][a_m] = av.w;
    float4 bv = make_float4(0.f, 0.f, 0.f, 0.f);
    int brow = k0 + b_k;
    if (brow < K)
      bv = *reinterpret_cast<const float4*>(B + (long long)brow * N + (col0 + b_n));
    Bs[b_k][b_n + 0] = bv.x; Bs[b_k][b_n + 1] = bv.y;
    Bs[b_k][b_n + 2] = bv.z; Bs[b_k][b_n + 3] = bv.w;
    __syncthreads();
#pragma unroll
    for (int kk = 0; kk < 16; kk++) {
      float ar[4], br[4];
#pragma unroll
      for (int i = 0; i < 4; i++) ar[i] = As[kk][ty * 4 + i];
#pragma unroll
      for (int j = 0; j < 4; j++) br[j] = Bs[kk][tx * 4 + j];
#pragma unroll
      for (int i = 0; i < 4; i++)
#pragma unroll
        for (int j = 0; j < 4; j++)
          acc[i][j] += ar[i] * br[j];
    }
    __syncthreads();
  }
  if ((int)gridDim.z > 1) {
#pragma unroll
    for (int i = 0; i < 4; i++) {
      int r = row0 + ty * 4 + i; if (r >= M) continue;
#pragma unroll
      for (int j = 0; j < 4; j++) {
        int c = col0 + tx * 4 + j; if (c >= N) continue;
        atomicAdd(&C[(long long)r * N + c], acc[i][j]);
      }
    }
    return;
  }
#pragma unroll
  for (int i = 0; i < 4; i++) {
    int r = row0 + ty * 4 + i; if (r >= M) continue;
#pragma unroll
    for (int j = 0; j < 4; j++) {
      int c = col0 + tx * 4 + j; if (c >= N) continue;
      float v = acc[i][j];
      if (bias)     v += bias[c];
      if (residual) v += residual[(long long)r * N + c];
      if (flags & FLAG_ACC)  v += C[(long long)r * N + c];
      if (flags & FLAG_RELU) v = fmaxf(v, 0.f);
      if (flags & FLAG_GELU) v = 0.5f * v * (1.f + erff(v * 0.70710678118654752f));
      C[(long long)r * N + c] = v;
    }
  }
}

// ---------------- bf16 MFMA GEMM: C[M,N] = A[M,K] @ Bt[N,K]^T ----------------------
// flags: RELU/GELU/ABF16 (A is bf16 shorts)/OBF16 (C stored bf16)/ACC.
// tapped: conv mode — K = 3*256, A row shift = (k0>>8)-1, A col = k0&255, lda=256.
__global__ __launch_bounds__(256) void gemm_bf16_bt(
    const void* __restrict__ Av, const float* __restrict__ Bt, void* __restrict__ Cv,
    const float* __restrict__ residual, const float* __restrict__ bias,
    int M, int N, int K, int lda, int flags, int tapped)
{
  __shared__ short Asl[128][40];
  __shared__ short Bsl[128][40];
  const int tid = threadIdx.x;
  const int row0 = blockIdx.y * 128;
  const int col0 = blockIdx.x * 128;
  const int lane = tid & 63;
  const int wave = tid >> 6;
  const int wm = (wave >> 1) * 64;
  const int wn = (wave & 1) * 64;
  const int fm = lane & 15;
  const int k8 = (lane >> 4) * 8;
  const int srow = tid >> 1;
  const int scol = (tid & 1) * 16;

  f32x4 acc[4][4] = {};
  for (int k0 = 0; k0 < K; k0 += 32) {
    int arow = row0 + srow;
    int acol = k0;
    if (tapped) { arow += (k0 >> 8) - 1; acol = k0 & 255; }
    const bool av = (arow >= 0 && arow < M);
    __syncthreads();
    if (flags & FLAG_ABF16) {
      const short* ga = (const short*)Av + (long long)arow * lda + acol + scol;
      short8 z;
#pragma unroll
      for (int u = 0; u < 8; u++) z[u] = 0;
      *(short8*)&Asl[srow][scol]     = av ? *(const short8*)(ga)     : z;
      *(short8*)&Asl[srow][scol + 8] = av ? *(const short8*)(ga + 8) : z;
    } else {
      const float* ga = (const float*)Av + (long long)arow * lda + acol + scol;
#pragma unroll
      for (int u = 0; u < 2; u++) {
        float4 f0 = make_float4(0.f, 0.f, 0.f, 0.f), f1 = f0;
        if (av) { f0 = *(const float4*)(ga + u * 8); f1 = *(const float4*)(ga + u * 8 + 4); }
        short8 v;
        v[0] = f2bf(f0.x); v[1] = f2bf(f0.y); v[2] = f2bf(f0.z); v[3] = f2bf(f0.w);
        v[4] = f2bf(f1.x); v[5] = f2bf(f1.y); v[6] = f2bf(f1.z); v[7] = f2bf(f1.w);
        *(short8*)&Asl[srow][scol + u * 8] = v;
      }
    }
    {
      const float* gb = Bt + (long long)(col0 + srow) * K + k0 + scol;
#pragma unroll
      for (int u = 0; u < 2; u++) {
        float4 g0 = *(const float4*)(gb + u * 8);
        float4 g1 = *(const float4*)(gb + u * 8 + 4);
        short8 w;
        w[0] = f2bf(g0.x); w[1] = f2bf(g0.y); w[2] = f2bf(g0.z); w[3] = f2bf(g0.w);
        w[4] = f2bf(g1.x); w[5] = f2bf(g1.y); w[6] = f2bf(g1.z); w[7] = f2bf(g1.w);
        *(short8*)&Bsl[srow][scol + u * 8] = w;
      }
    }
    __syncthreads();
    short8 af[4], bf[4];
#pragma unroll
    for (int i = 0; i < 4; i++) af[i] = *(short8*)&Asl[wm + i * 16 + fm][k8];
#pragma unroll
    for (int j = 0; j < 4; j++) bf[j] = *(short8*)&Bsl[wn + j * 16 + fm][k8];
#pragma unroll
    for (int i = 0; i < 4; i++)
#pragma unroll
      for (int j = 0; j < 4; j++)
        acc[i][j] = __builtin_amdgcn_mfma_f32_16x16x32_bf16(af[i], bf[j], acc[i][j], 0, 0, 0);
  }
#pragma unroll
  for (int i = 0; i < 4; i++) {
    const int mbase = row0 + wm + i * 16 + (lane >> 4) * 4;
#pragma unroll
    for (int j = 0; j < 4; j++) {
      const int n = col0 + wn + j * 16 + fm;
      const float bs = bias ? bias[n] : 0.f;
#pragma unroll
      for (int r = 0; r < 4; r++) {
        long long idx = (long long)(mbase + r) * N + n;
        float v = acc[i][j][r] + bs;
        if (residual) v += residual[idx];
        if (flags & FLAG_ACC)  v += ((const float*)Cv)[idx];
        if (flags & FLAG_RELU) v = fmaxf(v, 0.f);
        if (flags & FLAG_GELU) v = 0.5f * v * (1.f + erff(v * 0.70710678118654752f));
        if (flags & FLAG_OBF16) ((short*)Cv)[idx] = f2bf(v);
        else                    ((float*)Cv)[idx] = v;
      }
    }
  }
}

// ---------------- q+k fused bf16x3 GEMM with split-bf16 output ---------------------
// C = A @ Bt^T + bias computed in bf16x3 (rel err ~1.5e-5); each element stored as
// (h, l) bf16 pair (h+l represents value to ~4e-6 rel). N=512 (q cols 0-255, k 256-511).
__global__ __launch_bounds__(256) void gemm_qk(
    const float* __restrict__ A, const float* __restrict__ Bt,
    short* __restrict__ Ch, short* __restrict__ Cl,
    const float* __restrict__ bias, int M, int N, int K)
{
  __shared__ __align__(16) char smem[40960];
  short (*Ahi)[40] = (short(*)[40])(smem);
  short (*Alo)[40] = (short(*)[40])(smem + 10240);
  short (*Bhi)[40] = (short(*)[40])(smem + 20480);
  short (*Blo)[40] = (short(*)[40])(smem + 30720);
  const int tid = threadIdx.x;
  const int row0 = blockIdx.y * 128;
  const int col0 = blockIdx.x * 128;
  const int lane = tid & 63;
  const int wave = tid >> 6;
  const int wm = (wave >> 1) * 64;
  const int wn = (wave & 1) * 64;
  const int fm = lane & 15;
  const int k8 = (lane >> 4) * 8;
  const int srow = tid >> 1;
  const int scol = (tid & 1) * 16;
  const float* ga0 = A + (long long)(row0 + srow) * K + scol;
  const float* gb0 = Bt + (long long)(col0 + srow) * K + scol;

  f32x4 acc[4][4] = {};
  for (int k0 = 0; k0 < K; k0 += 32) {
    __syncthreads();
#pragma unroll
    for (int u = 0; u < 4; u++) {
      float4 f = *(const float4*)(ga0 + k0 + u * 4);
      short4v h, l;
      h[0] = f2bf(f.x); h[1] = f2bf(f.y); h[2] = f2bf(f.z); h[3] = f2bf(f.w);
      l[0] = f2bf(f.x - bf2f(h[0])); l[1] = f2bf(f.y - bf2f(h[1]));
      l[2] = f2bf(f.z - bf2f(h[2])); l[3] = f2bf(f.w - bf2f(h[3]));
      *(short4v*)&Ahi[srow][scol + u * 4] = h;
      *(short4v*)&Alo[srow][scol + u * 4] = l;
      float4 g = *(const float4*)(gb0 + k0 + u * 4);
      short4v hb, lb;
      hb[0] = f2bf(g.x); hb[1] = f2bf(g.y); hb[2] = f2bf(g.z); hb[3] = f2bf(g.w);
      lb[0] = f2bf(g.x - bf2f(hb[0])); lb[1] = f2bf(g.y - bf2f(hb[1]));
      lb[2] = f2bf(g.z - bf2f(hb[2])); lb[3] = f2bf(g.w - bf2f(hb[3]));
      *(short4v*)&Bhi[srow][scol + u * 4] = hb;
      *(short4v*)&Blo[srow][scol + u * 4] = lb;
    }
    __syncthreads();
    short8 ah[4], al[4], bh[4], bl[4];
#pragma unroll
    for (int i = 0; i < 4; i++) {
      ah[i] = *(short8*)&Ahi[wm + i * 16 + fm][k8];
      al[i] = *(short8*)&Alo[wm + i * 16 + fm][k8];
    }
#pragma unroll
    for (int j = 0; j < 4; j++) {
      bh[j] = *(short8*)&Bhi[wn + j * 16 + fm][k8];
      bl[j] = *(short8*)&Blo[wn + j * 16 + fm][k8];
    }
#pragma unroll
    for (int i = 0; i < 4; i++)
#pragma unroll
      for (int j = 0; j < 4; j++) {
        acc[i][j] = __builtin_amdgcn_mfma_f32_16x16x32_bf16(ah[i], bh[j], acc[i][j], 0, 0, 0);
        acc[i][j] = __builtin_amdgcn_mfma_f32_16x16x32_bf16(ah[i], bl[j], acc[i][j], 0, 0, 0);
        acc[i][j] = __builtin_amdgcn_mfma_f32_16x16x32_bf16(al[i], bh[j], acc[i][j], 0, 0, 0);
      }
  }
#pragma unroll
  for (int i = 0; i < 4; i++) {
    const int mbase = row0 + wm + i * 16 + (lane >> 4) * 4;
#pragma unroll
    for (int j = 0; j < 4; j++) {
      const int n = col0 + wn + j * 16 + fm;
      const float bs = bias ? bias[n] : 0.f;
#pragma unroll
      for (int r = 0; r < 4; r++) {
        long long idx = (long long)(mbase + r) * N + n;
        float v = acc[i][j][r] + bs;
        short h = f2bf(v);
        short l = f2bf(v - bf2f(h));
        Ch[idx] = h; Cl[idx] = l;
      }
    }
  }
}

// ------------- circular-correlation mean via MFMA on pre-split q/k -----------------
// qkh/qkl: [b][1024][512] bf16 (q cols 0-255, k cols 256-511). S = qh*kh+qh*kl+ql*kh.
// mv[b,tau] += (1/256) * diagonal sums. grid (8 s, 8 t, 64 b), 256 thr, 64 KB LDS.
__global__ __launch_bounds__(256) void corr_mfma2(
    const short* __restrict__ qkh, const short* __restrict__ qkl, float* __restrict__ mv)
{
  __shared__ __align__(16) char smem[65536];
  short (*Ahi)[40] = (short(*)[40])(smem);
  short (*Alo)[40] = (short(*)[40])(smem + 10240);
  short (*Bhi)[40] = (short(*)[40])(smem + 20480);
  short (*Blo)[40] = (short(*)[40])(smem + 30720);
  float* Sf = (float*)smem;

  const int b  = blockIdx.z;
  const int t0 = blockIdx.y * 128;
  const int s0 = blockIdx.x * 128;
  const int tid = threadIdx.x;
  const int lane = tid & 63;
  const int wave = tid >> 6;
  const int wm = (wave >> 1) * 64;
  const int wn = (wave & 1) * 64;
  const int fm = lane & 15;
  const int k8 = (lane >> 4) * 8;
  const int srow = tid >> 1;
  const int scol = (tid & 1) * 16;
  const long long bb = (long long)b * 524288;
  const short* gqh = qkh + bb + (long long)(t0 + srow) * 512 + scol;
  const short* gql = qkl + bb + (long long)(t0 + srow) * 512 + scol;
  const short* gkh = qkh + bb + (long long)(s0 + srow) * 512 + 256 + scol;
  const short* gkl = qkl + bb + (long long)(s0 + srow) * 512 + 256 + scol;

  f32x4 acc[4][4] = {};
  for (int k0 = 0; k0 < 256; k0 += 32) {
    __syncthreads();
    *(short8*)&Ahi[srow][scol]     = *(const short8*)(gqh + k0);
    *(short8*)&Ahi[srow][scol + 8] = *(const short8*)(gqh + k0 + 8);
    *(short8*)&Alo[srow][scol]     = *(const short8*)(gql + k0);
    *(short8*)&Alo[srow][scol + 8] = *(const short8*)(gql + k0 + 8);
    *(short8*)&Bhi[srow][scol]     = *(const short8*)(gkh + k0);
    *(short8*)&Bhi[srow][scol + 8] = *(const short8*)(gkh + k0 + 8);
    *(short8*)&Blo[srow][scol]     = *(const short8*)(gkl + k0);
    *(short8*)&Blo[srow][scol + 8] = *(const short8*)(gkl + k0 + 8);
    __syncthreads();
    short8 ah[4], al[4], bh[4], bl[4];
#pragma unroll
    for (int i = 0; i < 4; i++) {
      ah[i] = *(short8*)&Ahi[wm + i * 16 + fm][k8];
      al[i] = *(short8*)&Alo[wm + i * 16 + fm][k8];
    }
#pragma unroll
    for (int j = 0; j < 4; j++) {
      bh[j] = *(short8*)&Bhi[wn + j * 16 + fm][k8];
      bl[j] = *(short8*)&Blo[wn + j * 16 + fm][k8];
    }
#pragma unroll
    for (int i = 0; i < 4; i++)
#pragma unroll
      for (int j = 0; j < 4; j++) {
        acc[i][j] = __builtin_amdgcn_mfma_f32_16x16x32_bf16(ah[i], bh[j], acc[i][j], 0, 0, 0);
        acc[i][j] = __builtin_amdgcn_mfma_f32_16x16x32_bf16(ah[i], bl[j], acc[i][j], 0, 0, 0);
        acc[i][j] = __builtin_amdgcn_mfma_f32_16x16x32_bf16(al[i], bh[j], acc[i][j], 0, 0, 0);
      }
  }
  __syncthreads();   // all staging reads done; reuse LDS as Sf
#pragma unroll
  for (int i = 0; i < 4; i++) {
    const int row = wm + i * 16 + (lane >> 4) * 4;
#pragma unroll
    for (int j = 0; j < 4; j++) {
      const int col = wn + j * 16 + fm;
#pragma unroll
      for (int r = 0; r < 4; r++)
        Sf[(row + r) * 128 + col] = acc[i][j][r];
    }
  }
  __syncthreads();
  if (tid < 255) {
    const int delta = tid - 127;
    float ssum = 0.f;
    for (int m = 0; m < 128; m++) {
      int col = m - delta;
      float v = Sf[m * 128 + (col & 127)];        // uniform loop -> conflict-free
      ssum += ((unsigned)col < 128u) ? v : 0.f;
    }
    atomicAdd(&mv[b * 1024 + ((t0 - s0 + delta) & 1023)], ssum * (1.f / 256.f));
  }
}

// ------------- one-shot weight prep (conv2 taps + q/k/v/o transposes + qk bias) ----
__global__ void prep_weights(
    const float* __restrict__ conv2_w, const float* __restrict__ Wq,
    const float* __restrict__ Wk, const float* __restrict__ Wv,
    const float* __restrict__ Wo, const float* __restrict__ bq,
    const float* __restrict__ bk,
    float* __restrict__ CB2T, float* __restrict__ QKT, float* __restrict__ WVT,
    float* __restrict__ WOT, float* __restrict__ BQK)
{
  const int total = 196608 + 262144 + 131072 + 131072 + 1024;
  for (int idx = blockIdx.x * 256 + threadIdx.x; idx < total;
       idx += gridDim.x * 256) {
    int t = idx;
    if (t < 196608) {                 // CB2T[o][kk*256+i]
      int o = t / 768, rem = t % 768, kk = rem >> 8, i = rem & 255;
      CB2T[t] = conv2_w[(o * 256 + i) * 3 + kk];
    } else if ((t -= 196608) < 262144) {   // QKT[L][r][k], r<256: Wq^T, else Wk^T
      int L = t >> 17, rem = t & 131071, r = rem >> 8, k = rem & 255;
      QKT[t] = (r < 256) ? Wq[L * 65536 + k * 256 + r]
                         : Wk[L * 65536 + k * 256 + (r - 256)];
    } else if ((t -= 262144) < 131072) {   // WVT[L][n][k]
      int L = t >> 16, rem = t & 65535, n = rem >> 8, k = rem & 255;
      WVT[t] = Wv[L * 65536 + k * 256 + n];
    } else if ((t -= 131072) < 131072) {   // WOT[L][n][k]
      int L = t >> 16, rem = t & 65535, n = rem >> 8, k = rem & 255;
      WOT[t] = Wo[L * 65536 + k * 256 + n];
    } else {                               // BQK[L][512]
      t -= 131072;
      int L = t >> 9, j = t & 511;
      BQK[t] = (j < 256) ? bq[L * 256 + j] : bk[L * 256 + (j - 256)];
    }
  }
}

// ------------- conv1 direct: x[64,1024,16] -> relu(conv1d(x)) [64*1024,256] --------
__global__ __launch_bounds__(256) void conv1_direct(
    const float* __restrict__ x, const float* __restrict__ w,
    const float* __restrict__ bias, float* __restrict__ out)
{
  __shared__ float xs[66][16];
  const int b = blockIdx.y, lg = blockIdx.x, tid = threadIdx.x;
  const int l0 = lg * 64;
  for (int idx = tid; idx < 1056; idx += 256) {
    int r = idx >> 4, c = idx & 15;
    int l = l0 + r - 1;
    xs[r][c] = (l >= 0 && l < 1024) ? x[((long long)b * 1024 + l) * 16 + c] : 0.f;
  }
  float wr[48];
#pragma unroll
  for (int u = 0; u < 48; u++) wr[u] = w[tid * 48 + u];
  const float bs = bias[tid];
  __syncthreads();
  for (int r = 0; r < 64; r++) {
    float acc = bs;
#pragma unroll
    for (int i = 0; i < 16; i++) {
      acc += xs[r + 0][i] * wr[i * 3 + 0];
      acc += xs[r + 1][i] * wr[i * 3 + 1];
      acc += xs[r + 2][i] * wr[i * 3 + 2];
    }
    out[((long long)b * 1024 + l0 + r) * 256 + tid] = fmaxf(acc, 0.f);
  }
}

// ------------- conv batch-boundary fixup: recompute rows l=0 and l=1023 ------------
__global__ void fixup_conv(float* __restrict__ h, const float* __restrict__ src,
                           const float* __restrict__ w, const float* __restrict__ bias,
                           int I, int do_relu)
{
  int b = blockIdx.x >> 1;
  int l = (blockIdx.x & 1) ? 1023 : 0;
  int o = threadIdx.x;
  float acc = bias[o];
  for (int kk = 0; kk < 3; kk++) {
    int t = l + kk - 1;
    if (t < 0 || t > 1023) continue;
    const float* srow = src + ((long long)b * 1024 + t) * I;
    const float* wrow = w + (long long)o * I * 3 + kk;
    for (int i = 0; i < I; i++) acc += srow[i] * wrow[(long long)i * 3];
  }
  if (do_relu) acc = fmaxf(acc, 0.f);
  h[((long long)b * 1024 + l) * 256 + o] = acc;
}

// ------------- LayerNorm over 256 channels, one wave per row, float4 ---------------
__global__ __launch_bounds__(256) void ln_rows4(
    const float* __restrict__ in, float* __restrict__ out,
    const float* __restrict__ g, const float* __restrict__ b,
    int prerelu, int out_stride, int out_off)
{
  const int row = blockIdx.x * 4 + (threadIdx.x >> 6);
  const int lane = threadIdx.x & 63;
  float4 x = ((const float4*)(in + (long long)row * 256))[lane];
  if (prerelu) {
    x.x = fmaxf(x.x, 0.f); x.y = fmaxf(x.y, 0.f);
    x.z = fmaxf(x.z, 0.f); x.w = fmaxf(x.w, 0.f);
  }
  float s = x.x + x.y + x.z + x.w;
#pragma unroll
  for (int o = 32; o > 0; o >>= 1) s += __shfl_xor(s, o, 64);
  float mean = s * (1.f / 256.f);
  float4 d = make_float4(x.x - mean, x.y - mean, x.z - mean, x.w - mean);
  float s2 = d.x * d.x + d.y * d.y + d.z * d.z + d.w * d.w;
#pragma unroll
  for (int o = 32; o > 0; o >>= 1) s2 += __shfl_xor(s2, o, 64);
  float rsd = rsqrtf(s2 * (1.f / 256.f) + 1e-5f);
  float4 gg = ((const float4*)g)[lane];
  float4 bb = ((const float4*)b)[lane];
  float4 o4 = make_float4(d.x * rsd * gg.x + bb.x, d.y * rsd * gg.y + bb.y,
                          d.z * rsd * gg.z + bb.z, d.w * rsd * gg.w + bb.w);
  ((float4*)(out + (long long)row * out_stride + out_off))[lane] = o4;
}

// ------------- series_decomp, float4 -------------
__global__ void decomp4(const float* __restrict__ in, float* __restrict__ out)
{
  int g = blockIdx.x * 256 + threadIdx.x;   // [0, 4194304)
  int c4 = g & 63;
  int l  = (g >> 6) & 1023;
  int b  = g >> 16;
  const float4* base = (const float4*)(in + (long long)b * 262144);
  float4 s = make_float4(0.f, 0.f, 0.f, 0.f);
#pragma unroll
  for (int j = -12; j <= 12; j++) {
    int t = l + j;
    t = t < 0 ? 0 : (t > 1023 ? 1023 : t);
    float4 x = base[t * 64 + c4];
    s.x += x.x; s.y += x.y; s.z += x.z; s.w += x.w;
  }
  float4 x0 = base[l * 64 + c4];
  float4 o = make_float4(x0.x - s.x * (1.f / 25.f), x0.y - s.y * (1.f / 25.f),
                         x0.z - s.z * (1.f / 25.f), x0.w - s.w * (1.f / 25.f));
  ((float4*)(out + (long long)b * 262144))[l * 64 + c4] = o;
}

// ------------- top-20 + softmax, one wave per batch -------------
__global__ __launch_bounds__(64) void topk_softmax_wave(
    const float* __restrict__ mv, float* __restrict__ wts, int* __restrict__ dly)
{
  const int b = blockIdx.x, lane = threadIdx.x;
  float v[16];
#pragma unroll
  for (int j = 0; j < 16; j++) v[j] = mv[b * 1024 + lane + 64 * j];
  float selv = 0.f; int seli = 0;
  for (int it = 0; it < 20; it++) {
    float bv = -1e30f; int bi = 0x7fffffff;
#pragma unroll
    for (int j = 0; j < 16; j++) {
      float x = v[j]; int idx = lane + 64 * j;
      if (x > bv || (x == bv && idx < bi)) { bv = x; bi = idx; }
    }
#pragma unroll
    for (int off = 32; off > 0; off >>= 1) {
      float ov = __shfl_xor(bv, off, 64);
      int   oi = __shfl_xor(bi, off, 64);
      if (ov > bv || (ov == bv && oi < bi)) { bv = ov; bi = oi; }
    }
    if (lane == it) { selv = bv; seli = bi; }
    if ((bi & 63) == lane) v[bi >> 6] = -1e30f;
  }
  const float w0 = __shfl(selv, 0, 64);
  float e = (lane < 20) ? __expf(selv - w0) : 0.f;
  float s = e;
#pragma unroll
  for (int off = 32; off > 0; off >>= 1) s += __shfl_xor(s, off, 64);
  if (lane < 20) {
    wts[b * 20 + lane] = e / s;
    dly[b * 20 + lane] = seli;
  }
}

// ------------- delay aggregation, float4, 4 rows/block -------------
__global__ void agg4(const float* __restrict__ v, const float* __restrict__ wts,
                     const int* __restrict__ dly, float* __restrict__ out)
{
  const int b = blockIdx.y;
  const int l = blockIdx.x * 4 + (threadIdx.x >> 6);
  const int c4 = threadIdx.x & 63;
  const float4* vb = (const float4*)(v + (long long)b * 262144);
  float4 acc = make_float4(0.f, 0.f, 0.f, 0.f);
  for (int kk = 0; kk < 20; kk++) {
    int d = dly[b * 20 + kk];
    float w = wts[b * 20 + kk];
    float4 x = vb[((l + d) & 1023) * 64 + c4];
    acc.x += w * x.x; acc.y += w * x.y; acc.z += w * x.z; acc.w += w * x.w;
  }
  ((float4*)(out + (long long)b * 262144))[l * 64 + c4] = acc;
}

// ------------- small helpers -------------
__global__ void pool_copy(const float* __restrict__ enc, float* __restrict__ fin, int off)
{
  int b = blockIdx.x, tid = threadIdx.x;
  fin[(long long)b * 768 + off + tid] = enc[((long long)b * 1024 + 1023) * 256 + tid];
}

__global__ void init_bias(float* __restrict__ C, const float* __restrict__ bias)
{
  C[(long long)blockIdx.x * 256 + threadIdx.x] = bias[threadIdx.x];
}

__global__ void rp2_kernel(const float* __restrict__ x, const float* __restrict__ w,
                           const float* __restrict__ bias, float* __restrict__ out)
{
  __shared__ float red[4];
  int b = blockIdx.x, tid = threadIdx.x;
  float p = x[b * 256 + tid] * w[tid];
#pragma unroll
  for (int o = 32; o > 0; o >>= 1) p += __shfl_down(p, o, 64);
  if ((tid & 63) == 0) red[tid >> 6] = p;
  __syncthreads();
  if (tid == 0) out[b] = red[0] + red[1] + red[2] + red[3] + bias[0];
}

// =========================== host launch ===========================
static inline void gemm(hipStream_t s, const float* A, const float* B, float* C,
                        int M, int N, int K, int shift, const float* bias,
                        const float* res, int flags, int splitz = 1)
{
  dim3 g((N + 63) / 64, (M + 63) / 64, splitz);
  gemm_f32<<<g, dim3(256), 0, s>>>(A, B, C, M, N, K, shift, bias, res, flags);
}

extern "C" void kernel_launch(void* const* d_in, const int* in_sizes, int n_in,
                              void* d_out, int out_size, void* d_ws, size_t ws_size,
                              hipStream_t stream)
{
  const float* x_enc  = (const float*)d_in[0];
  const float* conv1_w= (const float*)d_in[1];
  const float* conv1_b= (const float*)d_in[2];
  const float* conv2_w= (const float*)d_in[3];
  const float* conv2_b= (const float*)d_in[4];
  const float* cnn_g  = (const float*)d_in[5];
  const float* cnn_b  = (const float*)d_in[6];
  const float* proj_w = (const float*)d_in[7];
  const float* proj_b = (const float*)d_in[8];
  const float* pln_g  = (const float*)d_in[9];
  const float* pln_b  = (const float*)d_in[10];
  const float* Wq     = (const float*)d_in[11];
  const float* bq     = (const float*)d_in[12];
  const float* Wk     = (const float*)d_in[13];
  const float* bk     = (const float*)d_in[14];
  const float* Wv     = (const float*)d_in[15];
  const float* bv     = (const float*)d_in[16];
  const float* Wo     = (const float*)d_in[17];
  const float* bo     = (const float*)d_in[18];
  const float* Wff1   = (const float*)d_in[19];
  const float* Wff2   = (const float*)d_in[20];
  const float* rp1_w  = (const float*)d_in[21];
  const float* rp1_b  = (const float*)d_in[22];
  const float* rln_g  = (const float*)d_in[23];
  const float* rln_b  = (const float*)d_in[24];
  const float* rp2_w  = (const float*)d_in[25];
  const float* rp2_b  = (const float*)d_in[26];
  (void)in_sizes; (void)n_in;

  const size_t BLD = 64ull * 1024 * 256;
  size_t need;
  {
    size_t o = 3 * BLD + 196608 + 262144 + 131072 + 131072 + 1024
             + 65536 + 1280 + 1280 + 16384 + 49152 + 16384 + 16384;
    need = o * sizeof(float);
  }
  if (ws_size < need) {
    hipMemsetAsync(d_out, 0, (size_t)out_size * sizeof(float), stream);
    return;
  }

  float* ws = (float*)d_ws;
  size_t off = 0;
  auto alloc = [&](size_t n) { float* p = ws + off; off += n; return p; };
  float* BUF0 = alloc(BLD);   // also QKH (shorts) spanning BUF0
  float* BUF1 = alloc(BLD);   // also QKL (shorts)
  float* BUF2 = alloc(BLD);   // also FFN hidden (bf16 shorts)
  float* CB2T = alloc(196608);
  float* QKT  = alloc(262144);
  float* WVT  = alloc(131072);
  float* WOT  = alloc(131072);
  float* BQK  = alloc(1024);
  float* MV   = alloc(65536);
  float* WTS  = alloc(1280);
  int*   DLY  = (int*)alloc(1280);
  float* PE   = alloc(16384);
  float* FIN  = alloc(49152);
  float* O1   = alloc(16384);
  float* O2   = alloc(16384);

  const int M = 65536;
  dim3 blk(256);

  prep_weights<<<1024, blk, 0, stream>>>(conv2_w, Wq, Wk, Wv, Wo, bq, bk,
                                         CB2T, QKT, WVT, WOT, BQK);

  // --- CNN frontend: conv1 direct fp32; conv2 = single tapped bf16 GEMM (K=768) ---
  conv1_direct<<<dim3(16, 64), blk, 0, stream>>>(x_enc, conv1_w, conv1_b, BUF0);
  gemm_bf16_bt<<<dim3(2, 512), blk, 0, stream>>>(
      BUF0, CB2T, BUF1, nullptr, conv2_b, M, 256, 768, 256, FLAG_RELU, 1);
  fixup_conv<<<128, blk, 0, stream>>>(BUF1, BUF0, conv2_w, conv2_b, 256, 1);
  ln_rows4<<<16384, blk, 0, stream>>>(BUF1, BUF2, cnn_g, cnn_b, 0, 256, 0);

  // --- encoder layers (enc in BUF2) ---
  for (int i = 0; i < 2; i++) {
    short* QKH = (short*)BUF0;
    short* QKL = (short*)BUF1;
    // fused q+k projection (bf16x3), split-bf16 output
    gemm_qk<<<dim3(4, 512), blk, 0, stream>>>(
        BUF2, QKT + (size_t)i * 131072, QKH, QKL, BQK + i * 512, M, 512, 256);
    hipMemsetAsync(MV, 0, 64 * 1024 * sizeof(float), stream);
    corr_mfma2<<<dim3(8, 8, 64), blk, 0, stream>>>(QKH, QKL, MV);
    topk_softmax_wave<<<64, dim3(64), 0, stream>>>(MV, WTS, DLY);
    // v, o projections (bf16)
    gemm_bf16_bt<<<dim3(2, 512), blk, 0, stream>>>(
        BUF2, WVT + (size_t)i * 65536, BUF0, nullptr, bv + i * 256,
        M, 256, 256, 256, 0, 0);
    agg4<<<dim3(256, 64), blk, 0, stream>>>(BUF0, WTS, DLY, BUF1);
    gemm_bf16_bt<<<dim3(2, 512), blk, 0, stream>>>(
        BUF1, WOT + (size_t)i * 65536, BUF0, BUF2, bo + i * 256,
        M, 256, 256, 256, 0, 0);
    decomp4<<<16384, blk, 0, stream>>>(BUF0, BUF1);   // xd -> BUF1
    // FFN: 2 chunks of 32768 rows; hidden bf16 in BUF2
    for (int c = 0; c < 2; c++) {
      const float* xd = BUF1 + (size_t)c * 32768 * 256;
      gemm_bf16_bt<<<dim3(8, 256), blk, 0, stream>>>(
          xd, Wff1 + (size_t)i * 262144, BUF2, nullptr, nullptr,
          32768, 1024, 256, 256, FLAG_GELU | FLAG_OBF16, 0);
      gemm_bf16_bt<<<dim3(2, 256), blk, 0, stream>>>(
          BUF2, Wff2 + (size_t)i * 262144, BUF0 + (size_t)c * 32768 * 256, xd, nullptr,
          32768, 256, 1024, 1024, FLAG_ABF16, 0);
    }
    decomp4<<<16384, blk, 0, stream>>>(BUF0, BUF2);   // new enc -> BUF2
    pool_copy<<<64, blk, 0, stream>>>(BUF2, FIN, i * 256);
  }

  // --- head (fp32, exact) ---
  init_bias<<<64, blk, 0, stream>>>(PE, proj_b);
  gemm(stream, x_enc, proj_w, PE, 64, 256, 16384, 0, nullptr, nullptr, 0, 32);
  ln_rows4<<<16, blk, 0, stream>>>(PE, FIN, pln_g, pln_b, 1, 768, 512);
  init_bias<<<64, blk, 0, stream>>>(O1, rp1_b);
  gemm(stream, FIN, rp1_w, O1, 64, 256, 768, 0, nullptr, nullptr, 0, 4);
  ln_rows4<<<16, blk, 0, stream>>>(O1, O2, rln_g, rln_b, 1, 256, 0);
  rp2_kernel<<<64, blk, 0, stream>>>(O2, rp2_w, rp2_b, (float*)d_out);
}

// Round 8
// 2105.472 us; speedup vs baseline: 5.8805x; 1.1257x over previous
//
#include <hip/hip_runtime.h>
#include <math.h>

#define FLAG_ACC    1
#define FLAG_RELU   2
#define FLAG_GELU   4
#define FLAG_ABF16  8
#define FLAG_OBF16 16

typedef __attribute__((ext_vector_type(8))) short short8;
typedef __attribute__((ext_vector_type(4))) short short4v;
typedef __attribute__((ext_vector_type(4))) float f32x4;

__device__ __forceinline__ short f2bf(float f) {
  unsigned u = __builtin_bit_cast(unsigned, f);
  unsigned r = u + 0x7fffu + ((u >> 16) & 1u);
  return (short)(r >> 16);
}
__device__ __forceinline__ float bf2f(short s) {
  unsigned u = ((unsigned)(unsigned short)s) << 16;
  return __builtin_bit_cast(float, u);
}

// ---------------- generic fp32 tiled GEMM (head path only) ----------------
__global__ __launch_bounds__(256) void gemm_f32(
    const float* __restrict__ A, const float* __restrict__ B, float* __restrict__ C,
    int M, int N, int K, int a_shift,
    const float* __restrict__ bias, const float* __restrict__ residual, int flags)
{
  __shared__ float As[16][65];
  __shared__ float Bs[16][64];
  const int tid = threadIdx.x;
  const int tx = tid & 15, ty = tid >> 4;
  const int row0 = blockIdx.y * 64;
  const int col0 = blockIdx.x * 64;
  int kbeg = 0, kend = K;
  if ((int)gridDim.z > 1) {
    int kchunk = ((K + (int)gridDim.z - 1) / (int)gridDim.z + 15) & ~15;
    kbeg = (int)blockIdx.z * kchunk;
    kend = min(K, kbeg + kchunk);
  }
  float acc[4][4] = {};
  const int a_m = tid >> 2;
  const int a_k = (tid & 3) << 2;
  const int b_n = (tid & 15) << 2;
  const int b_k = tid >> 4;
  for (int k0 = kbeg; k0 < kend; k0 += 16) {
    int srow = row0 + a_m + a_shift;
    float4 av = make_float4(0.f, 0.f, 0.f, 0.f);
    if (srow >= 0 && srow < M)
      av = *reinterpret_cast<const float4*>(A + (long long)srow * K + (k0 + a_k));
    As[a_k + 0][a_m] = av.x; As[a_k + 1][a_m] = av.y;
    As[a_k + 2][a_m] = av.z; As[a_k + 3][a_m] = av.w;
    float4 bv = make_float4(0.f, 0.f, 0.f, 0.f);
    int brow = k0 + b_k;
    if (brow < K)
      bv = *reinterpret_cast<const float4*>(B + (long long)brow * N + (col0 + b_n));
    Bs[b_k][b_n + 0] = bv.x; Bs[b_k][b_n + 1] = bv.y;
    Bs[b_k][b_n + 2] = bv.z; Bs[b_k][b_n + 3] = bv.w;
    __syncthreads();
#pragma unroll
    for (int kk = 0; kk < 16; kk++) {
      float ar[4], br[4];
#pragma unroll
      for (int i = 0; i < 4; i++) ar[i] = As[kk][ty * 4 + i];
#pragma unroll
      for (int j = 0; j < 4; j++) br[j] = Bs[kk][tx * 4 + j];
#pragma unroll
      for (int i = 0; i < 4; i++)
#pragma unroll
        for (int j = 0; j < 4; j++)
          acc[i][j] += ar[i] * br[j];
    }
    __syncthreads();
  }
  if ((int)gridDim.z > 1) {
#pragma unroll
    for (int i = 0; i < 4; i++) {
      int r = row0 + ty * 4 + i; if (r >= M) continue;
#pragma unroll
      for (int j = 0; j < 4; j++) {
        int c = col0 + tx * 4 + j; if (c >= N) continue;
        atomicAdd(&C[(long long)r * N + c], acc[i][j]);
      }
    }
    return;
  }
#pragma unroll
  for (int i = 0; i < 4; i++) {
    int r = row0 + ty * 4 + i; if (r >= M) continue;
#pragma unroll
    for (int j = 0; j < 4; j++) {
      int c = col0 + tx * 4 + j; if (c >= N) continue;
      float v = acc[i][j];
      if (bias)     v += bias[c];
      if (residual) v += residual[(long long)r * N + c];
      if (flags & FLAG_ACC)  v += C[(long long)r * N + c];
      if (flags & FLAG_RELU) v = fmaxf(v, 0.f);
      if (flags & FLAG_GELU) v = 0.5f * v * (1.f + erff(v * 0.70710678118654752f));
      C[(long long)r * N + c] = v;
    }
  }
}

// ---------------- bf16 MFMA GEMM: C[M,N] = A[M,K] @ Btb[N,K]^T (B pre-bf16) --------
// flags: RELU/GELU/ABF16 (A bf16 shorts)/OBF16 (C stored bf16)/ACC.
// tapped: conv mode — K = 3*256, A row shift = (k0>>8)-1, A col = k0&255.
__global__ __launch_bounds__(256) void gemm_bf16_bt(
    const void* __restrict__ Av, const short* __restrict__ Btb, void* __restrict__ Cv,
    const float* __restrict__ residual, const float* __restrict__ bias,
    int M, int N, int K, int lda, int flags, int tapped)
{
  __shared__ short Asl[128][40];
  __shared__ short Bsl[128][40];
  const int tid = threadIdx.x;
  const int row0 = blockIdx.y * 128;
  const int col0 = blockIdx.x * 128;
  const int lane = tid & 63;
  const int wave = tid >> 6;
  const int wm = (wave >> 1) * 64;
  const int wn = (wave & 1) * 64;
  const int fm = lane & 15;
  const int k8 = (lane >> 4) * 8;
  const int srow = tid >> 1;
  const int scol = (tid & 1) * 16;

  f32x4 acc[4][4] = {};
  for (int k0 = 0; k0 < K; k0 += 32) {
    int arow = row0 + srow;
    int acol = k0;
    if (tapped) { arow += (k0 >> 8) - 1; acol = k0 & 255; }
    const bool av = (arow >= 0 && arow < M);
    __syncthreads();
    if (flags & FLAG_ABF16) {
      const short* ga = (const short*)Av + (long long)arow * lda + acol + scol;
      short8 z;
#pragma unroll
      for (int u = 0; u < 8; u++) z[u] = 0;
      *(short8*)&Asl[srow][scol]     = av ? *(const short8*)(ga)     : z;
      *(short8*)&Asl[srow][scol + 8] = av ? *(const short8*)(ga + 8) : z;
    } else {
      const float* ga = (const float*)Av + (long long)arow * lda + acol + scol;
#pragma unroll
      for (int u = 0; u < 2; u++) {
        float4 f0 = make_float4(0.f, 0.f, 0.f, 0.f), f1 = f0;
        if (av) { f0 = *(const float4*)(ga + u * 8); f1 = *(const float4*)(ga + u * 8 + 4); }
        short8 v;
        v[0] = f2bf(f0.x); v[1] = f2bf(f0.y); v[2] = f2bf(f0.z); v[3] = f2bf(f0.w);
        v[4] = f2bf(f1.x); v[5] = f2bf(f1.y); v[6] = f2bf(f1.z); v[7] = f2bf(f1.w);
        *(short8*)&Asl[srow][scol + u * 8] = v;
      }
    }
    {
      const short* gb = Btb + (long long)(col0 + srow) * K + k0 + scol;
      *(short8*)&Bsl[srow][scol]     = *(const short8*)(gb);
      *(short8*)&Bsl[srow][scol + 8] = *(const short8*)(gb + 8);
    }
    __syncthreads();
    short8 af[4], bf[4];
#pragma unroll
    for (int i = 0; i < 4; i++) af[i] = *(short8*)&Asl[wm + i * 16 + fm][k8];
#pragma unroll
    for (int j = 0; j < 4; j++) bf[j] = *(short8*)&Bsl[wn + j * 16 + fm][k8];
#pragma unroll
    for (int i = 0; i < 4; i++)
#pragma unroll
      for (int j = 0; j < 4; j++)
        acc[i][j] = __builtin_amdgcn_mfma_f32_16x16x32_bf16(af[i], bf[j], acc[i][j], 0, 0, 0);
  }
#pragma unroll
  for (int i = 0; i < 4; i++) {
    const int mbase = row0 + wm + i * 16 + (lane >> 4) * 4;
#pragma unroll
    for (int j = 0; j < 4; j++) {
      const int n = col0 + wn + j * 16 + fm;
      const float bs = bias ? bias[n] : 0.f;
#pragma unroll
      for (int r = 0; r < 4; r++) {
        long long idx = (long long)(mbase + r) * N + n;
        float v = acc[i][j][r] + bs;
        if (residual) v += residual[idx];
        if (flags & FLAG_ACC)  v += ((const float*)Cv)[idx];
        if (flags & FLAG_RELU) v = fmaxf(v, 0.f);
        if (flags & FLAG_GELU) v = 0.5f * v * (1.f + erff(v * 0.70710678118654752f));
        if (flags & FLAG_OBF16) ((short*)Cv)[idx] = f2bf(v);
        else                    ((float*)Cv)[idx] = v;
      }
    }
  }
}

// ---------------- q+k fused bf16x3 GEMM, B pre-split, split-bf16 output ------------
__global__ __launch_bounds__(256) void gemm_qk(
    const float* __restrict__ A, const short* __restrict__ Bth,
    const short* __restrict__ Btl,
    short* __restrict__ Ch, short* __restrict__ Cl,
    const float* __restrict__ bias, int M, int N, int K)
{
  __shared__ __align__(16) char smem[40960];
  short (*Ahi)[40] = (short(*)[40])(smem);
  short (*Alo)[40] = (short(*)[40])(smem + 10240);
  short (*Bhi)[40] = (short(*)[40])(smem + 20480);
  short (*Blo)[40] = (short(*)[40])(smem + 30720);
  const int tid = threadIdx.x;
  const int row0 = blockIdx.y * 128;
  const int col0 = blockIdx.x * 128;
  const int lane = tid & 63;
  const int wave = tid >> 6;
  const int wm = (wave >> 1) * 64;
  const int wn = (wave & 1) * 64;
  const int fm = lane & 15;
  const int k8 = (lane >> 4) * 8;
  const int srow = tid >> 1;
  const int scol = (tid & 1) * 16;
  const float* ga0 = A + (long long)(row0 + srow) * K + scol;
  const short* gbh0 = Bth + (long long)(col0 + srow) * K + scol;
  const short* gbl0 = Btl + (long long)(col0 + srow) * K + scol;

  f32x4 acc[4][4] = {};
  for (int k0 = 0; k0 < K; k0 += 32) {
    __syncthreads();
#pragma unroll
    for (int u = 0; u < 4; u++) {
      float4 f = *(const float4*)(ga0 + k0 + u * 4);
      short4v h, l;
      h[0] = f2bf(f.x); h[1] = f2bf(f.y); h[2] = f2bf(f.z); h[3] = f2bf(f.w);
      l[0] = f2bf(f.x - bf2f(h[0])); l[1] = f2bf(f.y - bf2f(h[1]));
      l[2] = f2bf(f.z - bf2f(h[2])); l[3] = f2bf(f.w - bf2f(h[3]));
      *(short4v*)&Ahi[srow][scol + u * 4] = h;
      *(short4v*)&Alo[srow][scol + u * 4] = l;
    }
    *(short8*)&Bhi[srow][scol]     = *(const short8*)(gbh0 + k0);
    *(short8*)&Bhi[srow][scol + 8] = *(const short8*)(gbh0 + k0 + 8);
    *(short8*)&Blo[srow][scol]     = *(const short8*)(gbl0 + k0);
    *(short8*)&Blo[srow][scol + 8] = *(const short8*)(gbl0 + k0 + 8);
    __syncthreads();
    short8 ah[4], al[4], bh[4], bl[4];
#pragma unroll
    for (int i = 0; i < 4; i++) {
      ah[i] = *(short8*)&Ahi[wm + i * 16 + fm][k8];
      al[i] = *(short8*)&Alo[wm + i * 16 + fm][k8];
    }
#pragma unroll
    for (int j = 0; j < 4; j++) {
      bh[j] = *(short8*)&Bhi[wn + j * 16 + fm][k8];
      bl[j] = *(short8*)&Blo[wn + j * 16 + fm][k8];
    }
#pragma unroll
    for (int i = 0; i < 4; i++)
#pragma unroll
      for (int j = 0; j < 4; j++) {
        acc[i][j] = __builtin_amdgcn_mfma_f32_16x16x32_bf16(ah[i], bh[j], acc[i][j], 0, 0, 0);
        acc[i][j] = __builtin_amdgcn_mfma_f32_16x16x32_bf16(ah[i], bl[j], acc[i][j], 0, 0, 0);
        acc[i][j] = __builtin_amdgcn_mfma_f32_16x16x32_bf16(al[i], bh[j], acc[i][j], 0, 0, 0);
      }
  }
#pragma unroll
  for (int i = 0; i < 4; i++) {
    const int mbase = row0 + wm + i * 16 + (lane >> 4) * 4;
#pragma unroll
    for (int j = 0; j < 4; j++) {
      const int n = col0 + wn + j * 16 + fm;
      const float bs = bias ? bias[n] : 0.f;
#pragma unroll
      for (int r = 0; r < 4; r++) {
        long long idx = (long long)(mbase + r) * N + n;
        float v = acc[i][j][r] + bs;
        short h = f2bf(v);
        short l = f2bf(v - bf2f(h));
        Ch[idx] = h; Cl[idx] = l;
      }
    }
  }
}

// ------------- circular-correlation mean via MFMA, skewed-diagonal reduction -------
// S stored skewed: element (m,c) at Sf[m*128 + ((2m-c)&127)] -> column dd=(m-c)&127
// holds diagonals delta=dd (m>=dd) and delta=dd-128 (m<dd). 2 threads/column.
__global__ __launch_bounds__(256) void corr_mfma2(
    const short* __restrict__ qkh, const short* __restrict__ qkl, float* __restrict__ mv)
{
  __shared__ __align__(16) char smem[65536];
  short (*Ahi)[40] = (short(*)[40])(smem);
  short (*Alo)[40] = (short(*)[40])(smem + 10240);
  short (*Bhi)[40] = (short(*)[40])(smem + 20480);
  short (*Blo)[40] = (short(*)[40])(smem + 30720);
  float* Sf = (float*)smem;

  const int b  = blockIdx.z;
  const int t0 = blockIdx.y * 128;
  const int s0 = blockIdx.x * 128;
  const int tid = threadIdx.x;
  const int lane = tid & 63;
  const int wave = tid >> 6;
  const int wm = (wave >> 1) * 64;
  const int wn = (wave & 1) * 64;
  const int fm = lane & 15;
  const int k8 = (lane >> 4) * 8;
  const int srow = tid >> 1;
  const int scol = (tid & 1) * 16;
  const long long bb = (long long)b * 524288;
  const short* gqh = qkh + bb + (long long)(t0 + srow) * 512 + scol;
  const short* gql = qkl + bb + (long long)(t0 + srow) * 512 + scol;
  const short* gkh = qkh + bb + (long long)(s0 + srow) * 512 + 256 + scol;
  const short* gkl = qkl + bb + (long long)(s0 + srow) * 512 + 256 + scol;

  f32x4 acc[4][4] = {};
  for (int k0 = 0; k0 < 256; k0 += 32) {
    __syncthreads();
    *(short8*)&Ahi[srow][scol]     = *(const short8*)(gqh + k0);
    *(short8*)&Ahi[srow][scol + 8] = *(const short8*)(gqh + k0 + 8);
    *(short8*)&Alo[srow][scol]     = *(const short8*)(gql + k0);
    *(short8*)&Alo[srow][scol + 8] = *(const short8*)(gql + k0 + 8);
    *(short8*)&Bhi[srow][scol]     = *(const short8*)(gkh + k0);
    *(short8*)&Bhi[srow][scol + 8] = *(const short8*)(gkh + k0 + 8);
    *(short8*)&Blo[srow][scol]     = *(const short8*)(gkl + k0);
    *(short8*)&Blo[srow][scol + 8] = *(const short8*)(gkl + k0 + 8);
    __syncthreads();
    short8 ah[4], al[4], bh[4], bl[4];
#pragma unroll
    for (int i = 0; i < 4; i++) {
      ah[i] = *(short8*)&Ahi[wm + i * 16 + fm][k8];
      al[i] = *(short8*)&Alo[wm + i * 16 + fm][k8];
    }
#pragma unroll
    for (int j = 0; j < 4; j++) {
      bh[j] = *(short8*)&Bhi[wn + j * 16 + fm][k8];
      bl[j] = *(short8*)&Blo[wn + j * 16 + fm][k8];
    }
#pragma unroll
    for (int i = 0; i < 4; i++)
#pragma unroll
      for (int j = 0; j < 4; j++) {
        acc[i][j] = __builtin_amdgcn_mfma_f32_16x16x32_bf16(ah[i], bh[j], acc[i][j], 0, 0, 0);
        acc[i][j] = __builtin_amdgcn_mfma_f32_16x16x32_bf16(ah[i], bl[j], acc[i][j], 0, 0, 0);
        acc[i][j] = __builtin_amdgcn_mfma_f32_16x16x32_bf16(al[i], bh[j], acc[i][j], 0, 0, 0);
      }
  }
  __syncthreads();   // staging reads done; reuse LDS as skewed S
#pragma unroll
  for (int i = 0; i < 4; i++) {
    const int row = wm + i * 16 + (lane >> 4) * 4;
#pragma unroll
    for (int j = 0; j < 4; j++) {
      const int col = wn + j * 16 + fm;
#pragma unroll
      for (int r = 0; r < 4; r++)
        Sf[(row + r) * 128 + ((2 * (row + r) - col) & 127)] =
            acc[i][j][r] * (1.f / 256.f);
    }
  }
  __syncthreads();
  {
    const int dd = tid & 127;
    const int mb = (tid >> 7) * 64;
    float s_ge = 0.f, s_lt = 0.f;
    for (int mm = 0; mm < 64; mm++) {
      int m = mb + mm;
      float v = Sf[m * 128 + ((dd + m) & 127)];
      if (m >= dd) s_ge += v; else s_lt += v;
    }
    atomicAdd(&mv[b * 1024 + ((t0 - s0 + dd) & 1023)], s_ge);
    atomicAdd(&mv[b * 1024 + ((t0 - s0 + dd - 128) & 1023)], s_lt);
  }
}

// ------------- one-shot weight prep: all B operands -> bf16 (+ QKT hi/lo split) ----
__global__ void prep_weights(
    const float* __restrict__ conv2_w, const float* __restrict__ Wq,
    const float* __restrict__ Wk, const float* __restrict__ Wv,
    const float* __restrict__ Wo, const float* __restrict__ Wff1,
    const float* __restrict__ Wff2,
    const float* __restrict__ bq, const float* __restrict__ bk,
    short* __restrict__ CB2Tb, short* __restrict__ QKTH, short* __restrict__ QKTL,
    short* __restrict__ WVTb, short* __restrict__ WOTb,
    short* __restrict__ WFF1b, short* __restrict__ WFF2b, float* __restrict__ BQK)
{
  const int total = 196608 + 262144 + 131072 + 131072 + 524288 + 524288 + 1024;
  for (int idx = blockIdx.x * 256 + threadIdx.x; idx < total;
       idx += gridDim.x * 256) {
    int t = idx;
    if (t < 196608) {                       // CB2Tb[o][kk*256+i]
      int o = t / 768, rem = t % 768, kk = rem >> 8, i = rem & 255;
      CB2Tb[t] = f2bf(conv2_w[(o * 256 + i) * 3 + kk]);
    } else if ((t -= 196608) < 262144) {    // QKT hi+lo [L][512][256]
      int L = t >> 17, rem = t & 131071, r = rem >> 8, k = rem & 255;
      float val = (r < 256) ? Wq[L * 65536 + k * 256 + r]
                            : Wk[L * 65536 + k * 256 + (r - 256)];
      short h = f2bf(val);
      QKTH[t] = h;
      QKTL[t] = f2bf(val - bf2f(h));
    } else if ((t -= 262144) < 131072) {    // WVTb[L][n][k]
      int L = t >> 16, rem = t & 65535, n = rem >> 8, k = rem & 255;
      WVTb[t] = f2bf(Wv[L * 65536 + k * 256 + n]);
    } else if ((t -= 131072) < 131072) {    // WOTb[L][n][k]
      int L = t >> 16, rem = t & 65535, n = rem >> 8, k = rem & 255;
      WOTb[t] = f2bf(Wo[L * 65536 + k * 256 + n]);
    } else if ((t -= 131072) < 524288) {    // WFF1b: native [L][1024][256]
      WFF1b[t] = f2bf(Wff1[t]);
    } else if ((t -= 524288) < 524288) {    // WFF2b: native [L][256][1024]
      WFF2b[t] = f2bf(Wff2[t]);
    } else {                                // BQK[L][512]
      t -= 524288;
      int L = t >> 9, j = t & 511;
      BQK[t] = (j < 256) ? bq[L * 256 + j] : bk[L * 256 + (j - 256)];
    }
  }
}

// ------------- conv1 direct -> bf16 out ------------------------------------------
__global__ __launch_bounds__(256) void conv1_direct(
    const float* __restrict__ x, const float* __restrict__ w,
    const float* __restrict__ bias, short* __restrict__ out)
{
  __shared__ float xs[66][16];
  const int b = blockIdx.y, lg = blockIdx.x, tid = threadIdx.x;
  const int l0 = lg * 64;
  for (int idx = tid; idx < 1056; idx += 256) {
    int r = idx >> 4, c = idx & 15;
    int l = l0 + r - 1;
    xs[r][c] = (l >= 0 && l < 1024) ? x[((long long)b * 1024 + l) * 16 + c] : 0.f;
  }
  float wr[48];
#pragma unroll
  for (int u = 0; u < 48; u++) wr[u] = w[tid * 48 + u];
  const float bs = bias[tid];
  __syncthreads();
  for (int r = 0; r < 64; r++) {
    float acc = bs;
#pragma unroll
    for (int i = 0; i < 16; i++) {
      acc += xs[r + 0][i] * wr[i * 3 + 0];
      acc += xs[r + 1][i] * wr[i * 3 + 1];
      acc += xs[r + 2][i] * wr[i * 3 + 2];
    }
    out[((long long)b * 1024 + l0 + r) * 256 + tid] = f2bf(fmaxf(acc, 0.f));
  }
}

// ------------- conv2 batch-edge fixup (bf16 src rows) ------------------------------
__global__ void fixup_conv_b(float* __restrict__ h, const short* __restrict__ src,
                             const float* __restrict__ w, const float* __restrict__ bias)
{
  int b = blockIdx.x >> 1;
  int l = (blockIdx.x & 1) ? 1023 : 0;
  int o = threadIdx.x;
  float acc = bias[o];
  for (int kk = 0; kk < 3; kk++) {
    int t = l + kk - 1;
    if (t < 0 || t > 1023) continue;
    const short* srow = src + ((long long)b * 1024 + t) * 256;
    const float* wrow = w + (long long)o * 256 * 3 + kk;
    for (int i = 0; i < 256; i++) acc += bf2f(srow[i]) * wrow[(long long)i * 3];
  }
  h[((long long)b * 1024 + l) * 256 + o] = fmaxf(acc, 0.f);
}

// ------------- LayerNorm over 256 channels, one wave per row, float4 ---------------
__global__ __launch_bounds__(256) void ln_rows4(
    const float* __restrict__ in, float* __restrict__ out,
    const float* __restrict__ g, const float* __restrict__ b,
    int prerelu, int out_stride, int out_off)
{
  const int row = blockIdx.x * 4 + (threadIdx.x >> 6);
  const int lane = threadIdx.x & 63;
  float4 x = ((const float4*)(in + (long long)row * 256))[lane];
  if (prerelu) {
    x.x = fmaxf(x.x, 0.f); x.y = fmaxf(x.y, 0.f);
    x.z = fmaxf(x.z, 0.f); x.w = fmaxf(x.w, 0.f);
  }
  float s = x.x + x.y + x.z + x.w;
#pragma unroll
  for (int o = 32; o > 0; o >>= 1) s += __shfl_xor(s, o, 64);
  float mean = s * (1.f / 256.f);
  float4 d = make_float4(x.x - mean, x.y - mean, x.z - mean, x.w - mean);
  float s2 = d.x * d.x + d.y * d.y + d.z * d.z + d.w * d.w;
#pragma unroll
  for (int o = 32; o > 0; o >>= 1) s2 += __shfl_xor(s2, o, 64);
  float rsd = rsqrtf(s2 * (1.f / 256.f) + 1e-5f);
  float4 gg = ((const float4*)g)[lane];
  float4 bb = ((const float4*)b)[lane];
  float4 o4 = make_float4(d.x * rsd * gg.x + bb.x, d.y * rsd * gg.y + bb.y,
                          d.z * rsd * gg.z + bb.z, d.w * rsd * gg.w + bb.w);
  ((float4*)(out + (long long)row * out_stride + out_off))[lane] = o4;
}

// ------------- series_decomp, float4 -------------
__global__ void decomp4(const float* __restrict__ in, float* __restrict__ out)
{
  int g = blockIdx.x * 256 + threadIdx.x;
  int c4 = g & 63;
  int l  = (g >> 6) & 1023;
  int b  = g >> 16;
  const float4* base = (const float4*)(in + (long long)b * 262144);
  float4 s = make_float4(0.f, 0.f, 0.f, 0.f);
#pragma unroll
  for (int j = -12; j <= 12; j++) {
    int t = l + j;
    t = t < 0 ? 0 : (t > 1023 ? 1023 : t);
    float4 x = base[t * 64 + c4];
    s.x += x.x; s.y += x.y; s.z += x.z; s.w += x.w;
  }
  float4 x0 = base[l * 64 + c4];
  float4 o = make_float4(x0.x - s.x * (1.f / 25.f), x0.y - s.y * (1.f / 25.f),
                         x0.z - s.z * (1.f / 25.f), x0.w - s.w * (1.f / 25.f));
  ((float4*)(out + (long long)b * 262144))[l * 64 + c4] = o;
}

// ------------- top-20 + softmax, one wave per batch -------------
__global__ __launch_bounds__(64) void topk_softmax_wave(
    const float* __restrict__ mv, float* __restrict__ wts, int* __restrict__ dly)
{
  const int b = blockIdx.x, lane = threadIdx.x;
  float v[16];
#pragma unroll
  for (int j = 0; j < 16; j++) v[j] = mv[b * 1024 + lane + 64 * j];
  float selv = 0.f; int seli = 0;
  for (int it = 0; it < 20; it++) {
    float bv = -1e30f; int bi = 0x7fffffff;
#pragma unroll
    for (int j = 0; j < 16; j++) {
      float x = v[j]; int idx = lane + 64 * j;
      if (x > bv || (x == bv && idx < bi)) { bv = x; bi = idx; }
    }
#pragma unroll
    for (int off = 32; off > 0; off >>= 1) {
      float ov = __shfl_xor(bv, off, 64);
      int   oi = __shfl_xor(bi, off, 64);
      if (ov > bv || (ov == bv && oi < bi)) { bv = ov; bi = oi; }
    }
    if (lane == it) { selv = bv; seli = bi; }
    if ((bi & 63) == lane) v[bi >> 6] = -1e30f;
  }
  const float w0 = __shfl(selv, 0, 64);
  float e = (lane < 20) ? __expf(selv - w0) : 0.f;
  float s = e;
#pragma unroll
  for (int off = 32; off > 0; off >>= 1) s += __shfl_xor(s, off, 64);
  if (lane < 20) {
    wts[b * 20 + lane] = e / s;
    dly[b * 20 + lane] = seli;
  }
}

// ------------- delay aggregation, bf16 in/out, 4 rows/block -------------
__global__ void agg4b(const short* __restrict__ v, const float* __restrict__ wts,
                      const int* __restrict__ dly, short* __restrict__ out)
{
  const int b = blockIdx.y;
  const int l = blockIdx.x * 4 + (threadIdx.x >> 6);
  const int c4 = threadIdx.x & 63;
  const short4v* vb = (const short4v*)(v + (long long)b * 262144);
  float4 acc = make_float4(0.f, 0.f, 0.f, 0.f);
  for (int kk = 0; kk < 20; kk++) {
    int d = dly[b * 20 + kk];
    float w = wts[b * 20 + kk];
    short4v x = vb[((l + d) & 1023) * 64 + c4];
    acc.x += w * bf2f(x[0]); acc.y += w * bf2f(x[1]);
    acc.z += w * bf2f(x[2]); acc.w += w * bf2f(x[3]);
  }
  short4v o;
  o[0] = f2bf(acc.x); o[1] = f2bf(acc.y); o[2] = f2bf(acc.z); o[3] = f2bf(acc.w);
  ((short4v*)(out + (long long)b * 262144))[l * 64 + c4] = o;
}

// ------------- small helpers -------------
__global__ void pool_copy(const float* __restrict__ enc, float* __restrict__ fin, int off)
{
  int b = blockIdx.x, tid = threadIdx.x;
  fin[(long long)b * 768 + off + tid] = enc[((long long)b * 1024 + 1023) * 256 + tid];
}

__global__ void init_bias(float* __restrict__ C, const float* __restrict__ bias)
{
  C[(long long)blockIdx.x * 256 + threadIdx.x] = bias[threadIdx.x];
}

__global__ void rp2_kernel(const float* __restrict__ x, const float* __restrict__ w,
                           const float* __restrict__ bias, float* __restrict__ out)
{
  __shared__ float red[4];
  int b = blockIdx.x, tid = threadIdx.x;
  float p = x[b * 256 + tid] * w[tid];
#pragma unroll
  for (int o = 32; o > 0; o >>= 1) p += __shfl_down(p, o, 64);
  if ((tid & 63) == 0) red[tid >> 6] = p;
  __syncthreads();
  if (tid == 0) out[b] = red[0] + red[1] + red[2] + red[3] + bias[0];
}

// =========================== host launch ===========================
static inline void gemm(hipStream_t s, const float* A, const float* B, float* C,
                        int M, int N, int K, int shift, const float* bias,
                        const float* res, int flags, int splitz = 1)
{
  dim3 g((N + 63) / 64, (M + 63) / 64, splitz);
  gemm_f32<<<g, dim3(256), 0, s>>>(A, B, C, M, N, K, shift, bias, res, flags);
}

extern "C" void kernel_launch(void* const* d_in, const int* in_sizes, int n_in,
                              void* d_out, int out_size, void* d_ws, size_t ws_size,
                              hipStream_t stream)
{
  const float* x_enc  = (const float*)d_in[0];
  const float* conv1_w= (const float*)d_in[1];
  const float* conv1_b= (const float*)d_in[2];
  const float* conv2_w= (const float*)d_in[3];
  const float* conv2_b= (const float*)d_in[4];
  const float* cnn_g  = (const float*)d_in[5];
  const float* cnn_b  = (const float*)d_in[6];
  const float* proj_w = (const float*)d_in[7];
  const float* proj_b = (const float*)d_in[8];
  const float* pln_g  = (const float*)d_in[9];
  const float* pln_b  = (const float*)d_in[10];
  const float* Wq     = (const float*)d_in[11];
  const float* bq     = (const float*)d_in[12];
  const float* Wk     = (const float*)d_in[13];
  const float* bk     = (const float*)d_in[14];
  const float* Wv     = (const float*)d_in[15];
  const float* bv     = (const float*)d_in[16];
  const float* Wo     = (const float*)d_in[17];
  const float* bo     = (const float*)d_in[18];
  const float* Wff1   = (const float*)d_in[19];
  const float* Wff2   = (const float*)d_in[20];
  const float* rp1_w  = (const float*)d_in[21];
  const float* rp1_b  = (const float*)d_in[22];
  const float* rln_g  = (const float*)d_in[23];
  const float* rln_b  = (const float*)d_in[24];
  const float* rp2_w  = (const float*)d_in[25];
  const float* rp2_b  = (const float*)d_in[26];
  (void)in_sizes; (void)n_in;

  const size_t BLD = 64ull * 1024 * 256;
  size_t need;
  {
    size_t o = 3 * BLD
             + 98304 + 131072 + 131072 + 65536 + 65536 + 262144 + 262144 + 1024
             + 65536 + 1280 + 1280 + 16384 + 49152 + 16384 + 16384;
    need = o * sizeof(float);
  }
  if (ws_size < need) {
    hipMemsetAsync(d_out, 0, (size_t)out_size * sizeof(float), stream);
    return;
  }

  float* ws = (float*)d_ws;
  size_t off = 0;
  auto alloc = [&](size_t n) { float* p = ws + off; off += n; return p; };
  float* BUF0 = alloc(BLD);   // conv1 out (bf16) / QKH / v (bf16) / x / ffn out
  float* BUF1 = alloc(BLD);   // conv2 out / QKL / agg (bf16) / xd
  float* BUF2 = alloc(BLD);   // enc / ffn hidden (bf16)
  short* CB2Tb = (short*)alloc(98304);
  short* QKTH  = (short*)alloc(131072);
  short* QKTL  = (short*)alloc(131072);
  short* WVTb  = (short*)alloc(65536);
  short* WOTb  = (short*)alloc(65536);
  short* WFF1b = (short*)alloc(262144);
  short* WFF2b = (short*)alloc(262144);
  float* BQK  = alloc(1024);
  float* MV   = alloc(65536);
  float* WTS  = alloc(1280);
  int*   DLY  = (int*)alloc(1280);
  float* PE   = alloc(16384);
  float* FIN  = alloc(49152);
  float* O1   = alloc(16384);
  float* O2   = alloc(16384);

  const int M = 65536;
  dim3 blk(256);

  prep_weights<<<1024, blk, 0, stream>>>(conv2_w, Wq, Wk, Wv, Wo, Wff1, Wff2, bq, bk,
                                         CB2Tb, QKTH, QKTL, WVTb, WOTb,
                                         WFF1b, WFF2b, BQK);

  // --- CNN frontend: conv1 direct -> bf16; conv2 single tapped bf16 GEMM (K=768) ---
  conv1_direct<<<dim3(16, 64), blk, 0, stream>>>(x_enc, conv1_w, conv1_b, (short*)BUF0);
  gemm_bf16_bt<<<dim3(2, 512), blk, 0, stream>>>(
      BUF0, CB2Tb, BUF1, nullptr, conv2_b, M, 256, 768, 256,
      FLAG_ABF16 | FLAG_RELU, 1);
  fixup_conv_b<<<128, blk, 0, stream>>>(BUF1, (const short*)BUF0, conv2_w, conv2_b);
  ln_rows4<<<16384, blk, 0, stream>>>(BUF1, BUF2, cnn_g, cnn_b, 0, 256, 0);

  // --- encoder layers (enc in BUF2) ---
  for (int i = 0; i < 2; i++) {
    short* QKH = (short*)BUF0;
    short* QKL = (short*)BUF1;
    gemm_qk<<<dim3(4, 512), blk, 0, stream>>>(
        BUF2, QKTH + (size_t)i * 131072, QKTL + (size_t)i * 131072,
        QKH, QKL, BQK + i * 512, M, 512, 256);
    hipMemsetAsync(MV, 0, 64 * 1024 * sizeof(float), stream);
    corr_mfma2<<<dim3(8, 8, 64), blk, 0, stream>>>(QKH, QKL, MV);
    topk_softmax_wave<<<64, dim3(64), 0, stream>>>(MV, WTS, DLY);
    // v (bf16 out) -> agg (bf16) -> o (ABF16, fp32 out with residual)
    gemm_bf16_bt<<<dim3(2, 512), blk, 0, stream>>>(
        BUF2, WVTb + (size_t)i * 65536, BUF0, nullptr, bv + i * 256,
        M, 256, 256, 256, FLAG_OBF16, 0);
    agg4b<<<dim3(256, 64), blk, 0, stream>>>((const short*)BUF0, WTS, DLY, (short*)BUF1);
    gemm_bf16_bt<<<dim3(2, 512), blk, 0, stream>>>(
        BUF1, WOTb + (size_t)i * 65536, BUF0, BUF2, bo + i * 256,
        M, 256, 256, 256, FLAG_ABF16, 0);
    decomp4<<<16384, blk, 0, stream>>>(BUF0, BUF1);   // xd -> BUF1 (fp32)
    // FFN: 2 chunks of 32768 rows; hidden bf16 in BUF2
    for (int c = 0; c < 2; c++) {
      const float* xd = BUF1 + (size_t)c * 32768 * 256;
      gemm_bf16_bt<<<dim3(8, 256), blk, 0, stream>>>(
          xd, WFF1b + (size_t)i * 262144, BUF2, nullptr, nullptr,
          32768, 1024, 256, 256, FLAG_GELU | FLAG_OBF16, 0);
      gemm_bf16_bt<<<dim3(2, 256), blk, 0, stream>>>(
          BUF2, WFF2b + (size_t)i * 262144, BUF0 + (size_t)c * 32768 * 256, xd, nullptr,
          32768, 256, 1024, 1024, FLAG_ABF16, 0);
    }
    decomp4<<<16384, blk, 0, stream>>>(BUF0, BUF2);   // new enc -> BUF2
    pool_copy<<<64, blk, 0, stream>>>(BUF2, FIN, i * 256);
  }

  // --- head (fp32, exact) ---
  init_bias<<<64, blk, 0, stream>>>(PE, proj_b);
  gemm(stream, x_enc, proj_w, PE, 64, 256, 16384, 0, nullptr, nullptr, 0, 32);
  ln_rows4<<<16, blk, 0, stream>>>(PE, FIN, pln_g, pln_b, 1, 768, 512);
  init_bias<<<64, blk, 0, stream>>>(O1, rp1_b);
  gemm(stream, FIN, rp1_w, O1, 64, 256, 768, 0, nullptr, nullptr, 0, 4);
  ln_rows4<<<16, blk, 0, stream>>>(O1, O2, rln_g, rln_b, 1, 256, 0);
  rp2_kernel<<<64, blk, 0, stream>>>(O2, rp2_w, rp2_b, (float*)d_out);
}

// Round 9
// 1959.466 us; speedup vs baseline: 6.3187x; 1.0745x over previous
//
#include <hip/hip_runtime.h>
#include <math.h>

#define FLAG_ACC    1
#define FLAG_RELU   2
#define FLAG_GELU   4
#define FLAG_ABF16  8
#define FLAG_OBF16 16

typedef __attribute__((ext_vector_type(8))) short short8;
typedef __attribute__((ext_vector_type(4))) short short4v;
typedef __attribute__((ext_vector_type(4))) float f32x4;

__device__ __forceinline__ short f2bf(float f) {
  unsigned u = __builtin_bit_cast(unsigned, f);
  unsigned r = u + 0x7fffu + ((u >> 16) & 1u);
  return (short)(r >> 16);
}
__device__ __forceinline__ float bf2f(short s) {
  unsigned u = ((unsigned)(unsigned short)s) << 16;
  return __builtin_bit_cast(float, u);
}
// async global->LDS, 16B per lane; LDS dest = wave-uniform base + lane*16
__device__ __forceinline__ void load_lds16(const void* g, void* lds) {
  __builtin_amdgcn_global_load_lds(
      (const __attribute__((address_space(1))) void*)g,
      (__attribute__((address_space(3))) void*)lds, 16, 0, 0);
}

// ---------------- generic fp32 tiled GEMM (head + W_vo prep) ----------------
__global__ __launch_bounds__(256) void gemm_f32(
    const float* __restrict__ A, const float* __restrict__ B, float* __restrict__ C,
    int M, int N, int K, int a_shift,
    const float* __restrict__ bias, const float* __restrict__ residual, int flags)
{
  __shared__ float As[16][65];
  __shared__ float Bs[16][64];
  const int tid = threadIdx.x;
  const int tx = tid & 15, ty = tid >> 4;
  const int row0 = blockIdx.y * 64;
  const int col0 = blockIdx.x * 64;
  int kbeg = 0, kend = K;
  if ((int)gridDim.z > 1) {
    int kchunk = ((K + (int)gridDim.z - 1) / (int)gridDim.z + 15) & ~15;
    kbeg = (int)blockIdx.z * kchunk;
    kend = min(K, kbeg + kchunk);
  }
  float acc[4][4] = {};
  const int a_m = tid >> 2;
  const int a_k = (tid & 3) << 2;
  const int b_n = (tid & 15) << 2;
  const int b_k = tid >> 4;
  for (int k0 = kbeg; k0 < kend; k0 += 16) {
    int srow = row0 + a_m + a_shift;
    float4 av = make_float4(0.f, 0.f, 0.f, 0.f);
    if (srow >= 0 && srow < M)
      av = *reinterpret_cast<const float4*>(A + (long long)srow * K + (k0 + a_k));
    As[a_k + 0][a_m] = av.x; As[a_k + 1][a_m] = av.y;
    As[a_k + 2][a_m] = av.z; As[a_k + 3][a_m] = av.w;
    float4 bv = make_float4(0.f, 0.f, 0.f, 0.f);
    int brow = k0 + b_k;
    if (brow < K)
      bv = *reinterpret_cast<const float4*>(B + (long long)brow * N + (col0 + b_n));
    Bs[b_k][b_n + 0] = bv.x; Bs[b_k][b_n + 1] = bv.y;
    Bs[b_k][b_n + 2] = bv.z; Bs[b_k][b_n + 3] = bv.w;
    __syncthreads();
#pragma unroll
    for (int kk = 0; kk < 16; kk++) {
      float ar[4], br[4];
#pragma unroll
      for (int i = 0; i < 4; i++) ar[i] = As[kk][ty * 4 + i];
#pragma unroll
      for (int j = 0; j < 4; j++) br[j] = Bs[kk][tx * 4 + j];
#pragma unroll
      for (int i = 0; i < 4; i++)
#pragma unroll
        for (int j = 0; j < 4; j++)
          acc[i][j] += ar[i] * br[j];
    }
    __syncthreads();
  }
  if ((int)gridDim.z > 1) {
#pragma unroll
    for (int i = 0; i < 4; i++) {
      int r = row0 + ty * 4 + i; if (r >= M) continue;
#pragma unroll
      for (int j = 0; j < 4; j++) {
        int c = col0 + tx * 4 + j; if (c >= N) continue;
        atomicAdd(&C[(long long)r * N + c], acc[i][j]);
      }
    }
    return;
  }
#pragma unroll
  for (int i = 0; i < 4; i++) {
    int r = row0 + ty * 4 + i; if (r >= M) continue;
#pragma unroll
    for (int j = 0; j < 4; j++) {
      int c = col0 + tx * 4 + j; if (c >= N) continue;
      float v = acc[i][j];
      if (bias)     v += bias[c];
      if (residual) v += residual[(long long)r * N + c];
      if (flags & FLAG_ACC)  v += C[(long long)r * N + c];
      if (flags & FLAG_RELU) v = fmaxf(v, 0.f);
      if (flags & FLAG_GELU) v = 0.5f * v * (1.f + erff(v * 0.70710678118654752f));
      C[(long long)r * N + c] = v;
    }
  }
}

// ---------------- bf16 MFMA GEMM: C[M,N] = A[M,K] @ Btb[N,K]^T (B pre-bf16) --------
// Swizzled LDS: 16B chunk (r,kc) stored at phys r*4 + (kc ^ ((r>>1)&3)).
// B always DMA'd (global_load_lds). A: DMA if ABF16 && !tapped, else manual.
__global__ __launch_bounds__(256) void gemm_bf16_bt(
    const void* __restrict__ Av, const short* __restrict__ Btb, void* __restrict__ Cv,
    const float* __restrict__ residual, const float* __restrict__ bias,
    int M, int N, int K, int lda, int flags, int tapped)
{
  __shared__ __align__(16) short Asl[4096];   // 128 rows x 4 chunks x 8 shorts
  __shared__ __align__(16) short Bsl[4096];
  const int tid = threadIdx.x;
  const int row0 = blockIdx.y * 128;
  const int col0 = blockIdx.x * 128;
  const int lane = tid & 63;
  const int wave = tid >> 6;
  const int wm = (wave >> 1) * 64;
  const int wn = (wave & 1) * 64;
  const int fm = lane & 15;
  const int k8c = lane >> 4;
  const int mr = tid >> 1;          // manual staging row
  const int mkc = (tid & 1) * 2;    // manual staging chunk pair base
  const int msw = (mr >> 1) & 3;
  const bool a_dma = (flags & FLAG_ABF16) && !tapped;

  f32x4 acc[4][4] = {};
  for (int k0 = 0; k0 < K; k0 += 32) {
    __syncthreads();
#pragma unroll
    for (int u = 0; u < 2; u++) {           // B via DMA
      int p = (wave + u * 4) * 64 + lane;
      int r = p >> 2;
      int kc = (p & 3) ^ ((r >> 1) & 3);
      load_lds16(Btb + (long long)(col0 + r) * K + k0 + kc * 8,
                 (char*)Bsl + (wave + u * 4) * 1024);
    }
    if (a_dma) {
      const short* Ab = (const short*)Av;
#pragma unroll
      for (int u = 0; u < 2; u++) {
        int p = (wave + u * 4) * 64 + lane;
        int r = p >> 2;
        int kc = (p & 3) ^ ((r >> 1) & 3);
        load_lds16(Ab + (long long)(row0 + r) * lda + k0 + kc * 8,
                   (char*)Asl + (wave + u * 4) * 1024);
      }
    } else {
      int arow = row0 + mr + (tapped ? (k0 >> 8) - 1 : 0);
      int acol = tapped ? (k0 & 255) : k0;
      bool ok = (arow >= 0 && arow < M);
      short8 v0, v1;
      if (flags & FLAG_ABF16) {
        const short* ga = (const short*)Av + (long long)arow * lda + acol + mkc * 8;
        short8 z;
#pragma unroll
        for (int u = 0; u < 8; u++) z[u] = 0;
        v0 = ok ? *(const short8*)(ga) : z;
        v1 = ok ? *(const short8*)(ga + 8) : z;
      } else {
        const float* ga = (const float*)Av + (long long)arow * lda + acol + mkc * 8;
        float4 f0 = make_float4(0.f,0.f,0.f,0.f), f1 = f0, f2 = f0, f3 = f0;
        if (ok) {
          f0 = *(const float4*)(ga);     f1 = *(const float4*)(ga + 4);
          f2 = *(const float4*)(ga + 8); f3 = *(const float4*)(ga + 12);
        }
        v0[0]=f2bf(f0.x); v0[1]=f2bf(f0.y); v0[2]=f2bf(f0.z); v0[3]=f2bf(f0.w);
        v0[4]=f2bf(f1.x); v0[5]=f2bf(f1.y); v0[6]=f2bf(f1.z); v0[7]=f2bf(f1.w);
        v1[0]=f2bf(f2.x); v1[1]=f2bf(f2.y); v1[2]=f2bf(f2.z); v1[3]=f2bf(f2.w);
        v1[4]=f2bf(f3.x); v1[5]=f2bf(f3.y); v1[6]=f2bf(f3.z); v1[7]=f2bf(f3.w);
      }
      *(short8*)&Asl[(mr * 4 + (mkc ^ msw)) * 8] = v0;
      *(short8*)&Asl[(mr * 4 + ((mkc + 1) ^ msw)) * 8] = v1;
    }
    __syncthreads();
    short8 af[4], bf[4];
#pragma unroll
    for (int i = 0; i < 4; i++) {
      int r = wm + i * 16 + fm;
      af[i] = *(short8*)&Asl[(r * 4 + (k8c ^ ((r >> 1) & 3))) * 8];
    }
#pragma unroll
    for (int j = 0; j < 4; j++) {
      int r = wn + j * 16 + fm;
      bf[j] = *(short8*)&Bsl[(r * 4 + (k8c ^ ((r >> 1) & 3))) * 8];
    }
#pragma unroll
    for (int i = 0; i < 4; i++)
#pragma unroll
      for (int j = 0; j < 4; j++)
        acc[i][j] = __builtin_amdgcn_mfma_f32_16x16x32_bf16(af[i], bf[j], acc[i][j], 0, 0, 0);
  }
#pragma unroll
  for (int i = 0; i < 4; i++) {
    const int mbase = row0 + wm + i * 16 + (lane >> 4) * 4;
#pragma unroll
    for (int j = 0; j < 4; j++) {
      const int n = col0 + wn + j * 16 + fm;
      const float bs = bias ? bias[n] : 0.f;
#pragma unroll
      for (int r = 0; r < 4; r++) {
        long long idx = (long long)(mbase + r) * N + n;
        float v = acc[i][j][r] + bs;
        if (residual) v += residual[idx];
        if (flags & FLAG_ACC)  v += ((const float*)Cv)[idx];
        if (flags & FLAG_RELU) v = fmaxf(v, 0.f);
        if (flags & FLAG_GELU) v = 0.5f * v * (1.f + erff(v * 0.70710678118654752f));
        if (flags & FLAG_OBF16) ((short*)Cv)[idx] = f2bf(v);
        else                    ((float*)Cv)[idx] = v;
      }
    }
  }
}

// ---------------- q+k fused bf16x3 GEMM, B pre-split+DMA, split-bf16 output --------
__global__ __launch_bounds__(256) void gemm_qk(
    const float* __restrict__ A, const short* __restrict__ Bth,
    const short* __restrict__ Btl,
    short* __restrict__ Ch, short* __restrict__ Cl,
    const float* __restrict__ bias, int M, int N, int K)
{
  __shared__ __align__(16) char smem[32768];
  short* Ahi = (short*)smem;
  short* Alo = (short*)(smem + 8192);
  short* Bhi = (short*)(smem + 16384);
  short* Blo = (short*)(smem + 24576);
  const int tid = threadIdx.x;
  const int row0 = blockIdx.y * 128;
  const int col0 = blockIdx.x * 128;
  const int lane = tid & 63;
  const int wave = tid >> 6;
  const int wm = (wave >> 1) * 64;
  const int wn = (wave & 1) * 64;
  const int fm = lane & 15;
  const int k8c = lane >> 4;
  const int mr = tid >> 1;
  const int mkc = (tid & 1) * 2;
  const int msw = (mr >> 1) & 3;

  f32x4 acc[4][4] = {};
  for (int k0 = 0; k0 < K; k0 += 32) {
    __syncthreads();
#pragma unroll
    for (int u = 0; u < 2; u++) {
      int p = (wave + u * 4) * 64 + lane;
      int r = p >> 2;
      int kc = (p & 3) ^ ((r >> 1) & 3);
      long long go = (long long)(col0 + r) * K + k0 + kc * 8;
      int lo = (wave + u * 4) * 1024;
      load_lds16(Bth + go, (char*)Bhi + lo);
      load_lds16(Btl + go, (char*)Blo + lo);
    }
    {
      const float* ga = A + (long long)(row0 + mr) * K + k0 + mkc * 8;
      float4 f0 = *(const float4*)(ga),     f1 = *(const float4*)(ga + 4);
      float4 f2 = *(const float4*)(ga + 8), f3 = *(const float4*)(ga + 12);
      short8 h0, l0, h1, l1;
      h0[0]=f2bf(f0.x); h0[1]=f2bf(f0.y); h0[2]=f2bf(f0.z); h0[3]=f2bf(f0.w);
      h0[4]=f2bf(f1.x); h0[5]=f2bf(f1.y); h0[6]=f2bf(f1.z); h0[7]=f2bf(f1.w);
      l0[0]=f2bf(f0.x-bf2f(h0[0])); l0[1]=f2bf(f0.y-bf2f(h0[1]));
      l0[2]=f2bf(f0.z-bf2f(h0[2])); l0[3]=f2bf(f0.w-bf2f(h0[3]));
      l0[4]=f2bf(f1.x-bf2f(h0[4])); l0[5]=f2bf(f1.y-bf2f(h0[5]));
      l0[6]=f2bf(f1.z-bf2f(h0[6])); l0[7]=f2bf(f1.w-bf2f(h0[7]));
      h1[0]=f2bf(f2.x); h1[1]=f2bf(f2.y); h1[2]=f2bf(f2.z); h1[3]=f2bf(f2.w);
      h1[4]=f2bf(f3.x); h1[5]=f2bf(f3.y); h1[6]=f2bf(f3.z); h1[7]=f2bf(f3.w);
      l1[0]=f2bf(f2.x-bf2f(h1[0])); l1[1]=f2bf(f2.y-bf2f(h1[1]));
      l1[2]=f2bf(f2.z-bf2f(h1[2])); l1[3]=f2bf(f2.w-bf2f(h1[3]));
      l1[4]=f2bf(f3.x-bf2f(h1[4])); l1[5]=f2bf(f3.y-bf2f(h1[5]));
      l1[6]=f2bf(f3.z-bf2f(h1[6])); l1[7]=f2bf(f3.w-bf2f(h1[7]));
      int p0 = (mr * 4 + (mkc ^ msw)) * 8;
      int p1 = (mr * 4 + ((mkc + 1) ^ msw)) * 8;
      *(short8*)&Ahi[p0] = h0; *(short8*)&Ahi[p1] = h1;
      *(short8*)&Alo[p0] = l0; *(short8*)&Alo[p1] = l1;
    }
    __syncthreads();
    short8 ah[4], al[4], bh[4], bl[4];
#pragma unroll
    for (int i = 0; i < 4; i++) {
      int r = wm + i * 16 + fm;
      int p = (r * 4 + (k8c ^ ((r >> 1) & 3))) * 8;
      ah[i] = *(short8*)&Ahi[p];
      al[i] = *(short8*)&Alo[p];
    }
#pragma unroll
    for (int j = 0; j < 4; j++) {
      int r = wn + j * 16 + fm;
      int p = (r * 4 + (k8c ^ ((r >> 1) & 3))) * 8;
      bh[j] = *(short8*)&Bhi[p];
      bl[j] = *(short8*)&Blo[p];
    }
#pragma unroll
    for (int i = 0; i < 4; i++)
#pragma unroll
      for (int j = 0; j < 4; j++) {
        acc[i][j] = __builtin_amdgcn_mfma_f32_16x16x32_bf16(ah[i], bh[j], acc[i][j], 0, 0, 0);
        acc[i][j] = __builtin_amdgcn_mfma_f32_16x16x32_bf16(ah[i], bl[j], acc[i][j], 0, 0, 0);
        acc[i][j] = __builtin_amdgcn_mfma_f32_16x16x32_bf16(al[i], bh[j], acc[i][j], 0, 0, 0);
      }
  }
#pragma unroll
  for (int i = 0; i < 4; i++) {
    const int mbase = row0 + wm + i * 16 + (lane >> 4) * 4;
#pragma unroll
    for (int j = 0; j < 4; j++) {
      const int n = col0 + wn + j * 16 + fm;
      const float bs = bias ? bias[n] : 0.f;
#pragma unroll
      for (int r = 0; r < 4; r++) {
        long long idx = (long long)(mbase + r) * N + n;
        float v = acc[i][j][r] + bs;
        short h = f2bf(v);
        short l = f2bf(v - bf2f(h));
        Ch[idx] = h; Cl[idx] = l;
      }
    }
  }
}

// ------------- circular-correlation mean: all-DMA staging + skewed reduction -------
__global__ __launch_bounds__(256) void corr_mfma2(
    const short* __restrict__ qkh, const short* __restrict__ qkl, float* __restrict__ mv)
{
  __shared__ __align__(16) char smem[65536];
  short* Ahi = (short*)smem;
  short* Alo = (short*)(smem + 8192);
  short* Bhi = (short*)(smem + 16384);
  short* Blo = (short*)(smem + 24576);
  float* Sf = (float*)smem;

  const int b  = blockIdx.z;
  const int t0 = blockIdx.y * 128;
  const int s0 = blockIdx.x * 128;
  const int tid = threadIdx.x;
  const int lane = tid & 63;
  const int wave = tid >> 6;
  const int wm = (wave >> 1) * 64;
  const int wn = (wave & 1) * 64;
  const int fm = lane & 15;
  const int k8c = lane >> 4;
  const long long bb = (long long)b * 524288;

  f32x4 acc[4][4] = {};
  for (int k0 = 0; k0 < 256; k0 += 32) {
    __syncthreads();
#pragma unroll
    for (int u = 0; u < 2; u++) {
      int p = (wave + u * 4) * 64 + lane;
      int r = p >> 2;
      int kc = (p & 3) ^ ((r >> 1) & 3);
      long long qo = bb + (long long)(t0 + r) * 512 + k0 + kc * 8;
      long long ko = bb + (long long)(s0 + r) * 512 + 256 + k0 + kc * 8;
      int lo = (wave + u * 4) * 1024;
      load_lds16(qkh + qo, (char*)Ahi + lo);
      load_lds16(qkl + qo, (char*)Alo + lo);
      load_lds16(qkh + ko, (char*)Bhi + lo);
      load_lds16(qkl + ko, (char*)Blo + lo);
    }
    __syncthreads();
    short8 ah[4], al[4], bh[4], bl[4];
#pragma unroll
    for (int i = 0; i < 4; i++) {
      int r = wm + i * 16 + fm;
      int p = (r * 4 + (k8c ^ ((r >> 1) & 3))) * 8;
      ah[i] = *(short8*)&Ahi[p];
      al[i] = *(short8*)&Alo[p];
    }
#pragma unroll
    for (int j = 0; j < 4; j++) {
      int r = wn + j * 16 + fm;
      int p = (r * 4 + (k8c ^ ((r >> 1) & 3))) * 8;
      bh[j] = *(short8*)&Bhi[p];
      bl[j] = *(short8*)&Blo[p];
    }
#pragma unroll
    for (int i = 0; i < 4; i++)
#pragma unroll
      for (int j = 0; j < 4; j++) {
        acc[i][j] = __builtin_amdgcn_mfma_f32_16x16x32_bf16(ah[i], bh[j], acc[i][j], 0, 0, 0);
        acc[i][j] = __builtin_amdgcn_mfma_f32_16x16x32_bf16(ah[i], bl[j], acc[i][j], 0, 0, 0);
        acc[i][j] = __builtin_amdgcn_mfma_f32_16x16x32_bf16(al[i], bh[j], acc[i][j], 0, 0, 0);
      }
  }
  __syncthreads();   // staging reads done; reuse LDS as skewed S
#pragma unroll
  for (int i = 0; i < 4; i++) {
    const int row = wm + i * 16 + (lane >> 4) * 4;
#pragma unroll
    for (int j = 0; j < 4; j++) {
      const int col = wn + j * 16 + fm;
#pragma unroll
      for (int r = 0; r < 4; r++)
        Sf[(row + r) * 128 + ((2 * (row + r) - col) & 127)] =
            acc[i][j][r] * (1.f / 256.f);
    }
  }
  __syncthreads();
  {
    const int dd = tid & 127;
    const int mb = (tid >> 7) * 64;
    float s_ge = 0.f, s_lt = 0.f;
    for (int mm = 0; mm < 64; mm++) {
      int m = mb + mm;
      float v = Sf[m * 128 + ((dd + m) & 127)];
      if (m >= dd) s_ge += v; else s_lt += v;
    }
    atomicAdd(&mv[b * 1024 + ((t0 - s0 + dd) & 1023)], s_ge);
    atomicAdd(&mv[b * 1024 + ((t0 - s0 + dd - 128) & 1023)], s_lt);
  }
}

// ------------- one-shot weight prep -------------
__global__ void prep_weights(
    const float* __restrict__ conv2_w, const float* __restrict__ Wq,
    const float* __restrict__ Wk, const float* __restrict__ Wff1,
    const float* __restrict__ Wff2,
    const float* __restrict__ bq, const float* __restrict__ bk,
    short* __restrict__ CB2Tb, short* __restrict__ QKTH, short* __restrict__ QKTL,
    short* __restrict__ WFF1b, short* __restrict__ WFF2b, float* __restrict__ BQK)
{
  const int total = 196608 + 262144 + 524288 + 524288 + 1024;
  for (int idx = blockIdx.x * 256 + threadIdx.x; idx < total;
       idx += gridDim.x * 256) {
    int t = idx;
    if (t < 196608) {
      int o = t / 768, rem = t % 768, kk = rem >> 8, i = rem & 255;
      CB2Tb[t] = f2bf(conv2_w[(o * 256 + i) * 3 + kk]);
    } else if ((t -= 196608) < 262144) {
      int L = t >> 17, rem = t & 131071, r = rem >> 8, k = rem & 255;
      float val = (r < 256) ? Wq[L * 65536 + k * 256 + r]
                            : Wk[L * 65536 + k * 256 + (r - 256)];
      short h = f2bf(val);
      QKTH[t] = h;
      QKTL[t] = f2bf(val - bf2f(h));
    } else if ((t -= 262144) < 524288) {
      WFF1b[t] = f2bf(Wff1[t]);
    } else if ((t -= 524288) < 524288) {
      WFF2b[t] = f2bf(Wff2[t]);
    } else {
      t -= 524288;
      int L = t >> 9, j = t & 511;
      BQK[t] = (j < 256) ? bq[L * 256 + j] : bk[L * 256 + (j - 256)];
    }
  }
}

// ------------- W_vo finish: transpose+bf16 W_vo, fused bias b_vo -------------
__global__ void vo_finish(const float* __restrict__ WVO, const float* __restrict__ Wo,
                          const float* __restrict__ bv, const float* __restrict__ bo,
                          short* __restrict__ WVOTb, float* __restrict__ BVO)
{
  const int total = 131072 + 512;
  for (int idx = blockIdx.x * 256 + threadIdx.x; idx < total;
       idx += gridDim.x * 256) {
    if (idx < 131072) {
      int L = idx >> 16, rem = idx & 65535, n = rem >> 8, k = rem & 255;
      WVOTb[idx] = f2bf(WVO[L * 65536 + k * 256 + n]);
    } else {
      int j = idx - 131072;
      int L = j >> 8, n = j & 255;
      float acc = bo[L * 256 + n];
      for (int k = 0; k < 256; k++)
        acc += bv[L * 256 + k] * Wo[(long long)L * 65536 + k * 256 + n];
      BVO[j] = acc;
    }
  }
}

// ------------- conv1 direct -> bf16 out -------------
__global__ __launch_bounds__(256) void conv1_direct(
    const float* __restrict__ x, const float* __restrict__ w,
    const float* __restrict__ bias, short* __restrict__ out)
{
  __shared__ float xs[66][16];
  const int b = blockIdx.y, lg = blockIdx.x, tid = threadIdx.x;
  const int l0 = lg * 64;
  for (int idx = tid; idx < 1056; idx += 256) {
    int r = idx >> 4, c = idx & 15;
    int l = l0 + r - 1;
    xs[r][c] = (l >= 0 && l < 1024) ? x[((long long)b * 1024 + l) * 16 + c] : 0.f;
  }
  float wr[48];
#pragma unroll
  for (int u = 0; u < 48; u++) wr[u] = w[tid * 48 + u];
  const float bs = bias[tid];
  __syncthreads();
  for (int r = 0; r < 64; r++) {
    float acc = bs;
#pragma unroll
    for (int i = 0; i < 16; i++) {
      acc += xs[r + 0][i] * wr[i * 3 + 0];
      acc += xs[r + 1][i] * wr[i * 3 + 1];
      acc += xs[r + 2][i] * wr[i * 3 + 2];
    }
    out[((long long)b * 1024 + l0 + r) * 256 + tid] = f2bf(fmaxf(acc, 0.f));
  }
}

// ------------- conv2 batch-edge fixup (bf16 src rows) -------------
__global__ void fixup_conv_b(float* __restrict__ h, const short* __restrict__ src,
                             const float* __restrict__ w, const float* __restrict__ bias)
{
  int b = blockIdx.x >> 1;
  int l = (blockIdx.x & 1) ? 1023 : 0;
  int o = threadIdx.x;
  float acc = bias[o];
  for (int kk = 0; kk < 3; kk++) {
    int t = l + kk - 1;
    if (t < 0 || t > 1023) continue;
    const short* srow = src + ((long long)b * 1024 + t) * 256;
    const float* wrow = w + (long long)o * 256 * 3 + kk;
    for (int i = 0; i < 256; i++) acc += bf2f(srow[i]) * wrow[(long long)i * 3];
  }
  h[((long long)b * 1024 + l) * 256 + o] = fmaxf(acc, 0.f);
}

// ------------- LayerNorm, one wave per row, float4 -------------
__global__ __launch_bounds__(256) void ln_rows4(
    const float* __restrict__ in, float* __restrict__ out,
    const float* __restrict__ g, const float* __restrict__ b,
    int prerelu, int out_stride, int out_off)
{
  const int row = blockIdx.x * 4 + (threadIdx.x >> 6);
  const int lane = threadIdx.x & 63;
  float4 x = ((const float4*)(in + (long long)row * 256))[lane];
  if (prerelu) {
    x.x = fmaxf(x.x, 0.f); x.y = fmaxf(x.y, 0.f);
    x.z = fmaxf(x.z, 0.f); x.w = fmaxf(x.w, 0.f);
  }
  float s = x.x + x.y + x.z + x.w;
#pragma unroll
  for (int o = 32; o > 0; o >>= 1) s += __shfl_xor(s, o, 64);
  float mean = s * (1.f / 256.f);
  float4 d = make_float4(x.x - mean, x.y - mean, x.z - mean, x.w - mean);
  float s2 = d.x * d.x + d.y * d.y + d.z * d.z + d.w * d.w;
#pragma unroll
  for (int o = 32; o > 0; o >>= 1) s2 += __shfl_xor(s2, o, 64);
  float rsd = rsqrtf(s2 * (1.f / 256.f) + 1e-5f);
  float4 gg = ((const float4*)g)[lane];
  float4 bb = ((const float4*)b)[lane];
  float4 o4 = make_float4(d.x * rsd * gg.x + bb.x, d.y * rsd * gg.y + bb.y,
                          d.z * rsd * gg.z + bb.z, d.w * rsd * gg.w + bb.w);
  ((float4*)(out + (long long)row * out_stride + out_off))[lane] = o4;
}

// ------------- series_decomp, float4 -------------
__global__ void decomp4(const float* __restrict__ in, float* __restrict__ out)
{
  int g = blockIdx.x * 256 + threadIdx.x;
  int c4 = g & 63;
  int l  = (g >> 6) & 1023;
  int b  = g >> 16;
  const float4* base = (const float4*)(in + (long long)b * 262144);
  float4 s = make_float4(0.f, 0.f, 0.f, 0.f);
#pragma unroll
  for (int j = -12; j <= 12; j++) {
    int t = l + j;
    t = t < 0 ? 0 : (t > 1023 ? 1023 : t);
    float4 x = base[t * 64 + c4];
    s.x += x.x; s.y += x.y; s.z += x.z; s.w += x.w;
  }
  float4 x0 = base[l * 64 + c4];
  float4 o = make_float4(x0.x - s.x * (1.f / 25.f), x0.y - s.y * (1.f / 25.f),
                         x0.z - s.z * (1.f / 25.f), x0.w - s.w * (1.f / 25.f));
  ((float4*)(out + (long long)b * 262144))[l * 64 + c4] = o;
}

// ------------- top-20 + softmax, one wave per batch -------------
__global__ __launch_bounds__(64) void topk_softmax_wave(
    const float* __restrict__ mv, float* __restrict__ wts, int* __restrict__ dly)
{
  const int b = blockIdx.x, lane = threadIdx.x;
  float v[16];
#pragma unroll
  for (int j = 0; j < 16; j++) v[j] = mv[b * 1024 + lane + 64 * j];
  float selv = 0.f; int seli = 0;
  for (int it = 0; it < 20; it++) {
    float bv = -1e30f; int bi = 0x7fffffff;
#pragma unroll
    for (int j = 0; j < 16; j++) {
      float x = v[j]; int idx = lane + 64 * j;
      if (x > bv || (x == bv && idx < bi)) { bv = x; bi = idx; }
    }
#pragma unroll
    for (int off = 32; off > 0; off >>= 1) {
      float ov = __shfl_xor(bv, off, 64);
      int   oi = __shfl_xor(bi, off, 64);
      if (ov > bv || (ov == bv && oi < bi)) { bv = ov; bi = oi; }
    }
    if (lane == it) { selv = bv; seli = bi; }
    if ((bi & 63) == lane) v[bi >> 6] = -1e30f;
  }
  const float w0 = __shfl(selv, 0, 64);
  float e = (lane < 20) ? __expf(selv - w0) : 0.f;
  float s = e;
#pragma unroll
  for (int off = 32; off > 0; off >>= 1) s += __shfl_xor(s, off, 64);
  if (lane < 20) {
    wts[b * 20 + lane] = e / s;
    dly[b * 20 + lane] = seli;
  }
}

// ------------- delay aggregation on enc (fp32 in, bf16 out) -------------
__global__ void agg4e(const float* __restrict__ enc, const float* __restrict__ wts,
                      const int* __restrict__ dly, short* __restrict__ out)
{
  const int b = blockIdx.y;
  const int l = blockIdx.x * 4 + (threadIdx.x >> 6);
  const int c4 = threadIdx.x & 63;
  const float4* vb = (const float4*)(enc + (long long)b * 262144);
  float4 acc = make_float4(0.f, 0.f, 0.f, 0.f);
  for (int kk = 0; kk < 20; kk++) {
    int d = dly[b * 20 + kk];
    float w = wts[b * 20 + kk];
    float4 x = vb[((l + d) & 1023) * 64 + c4];
    acc.x += w * x.x; acc.y += w * x.y; acc.z += w * x.z; acc.w += w * x.w;
  }
  short4v o;
  o[0] = f2bf(acc.x); o[1] = f2bf(acc.y); o[2] = f2bf(acc.z); o[3] = f2bf(acc.w);
  ((short4v*)(out + (long long)b * 262144))[l * 64 + c4] = o;
}

// ------------- small helpers -------------
__global__ void pool_copy(const float* __restrict__ enc, float* __restrict__ fin, int off)
{
  int b = blockIdx.x, tid = threadIdx.x;
  fin[(long long)b * 768 + off + tid] = enc[((long long)b * 1024 + 1023) * 256 + tid];
}

__global__ void init_bias(float* __restrict__ C, const float* __restrict__ bias)
{
  C[(long long)blockIdx.x * 256 + threadIdx.x] = bias[threadIdx.x];
}

__global__ void rp2_kernel(const float* __restrict__ x, const float* __restrict__ w,
                           const float* __restrict__ bias, float* __restrict__ out)
{
  __shared__ float red[4];
  int b = blockIdx.x, tid = threadIdx.x;
  float p = x[b * 256 + tid] * w[tid];
#pragma unroll
  for (int o = 32; o > 0; o >>= 1) p += __shfl_down(p, o, 64);
  if ((tid & 63) == 0) red[tid >> 6] = p;
  __syncthreads();
  if (tid == 0) out[b] = red[0] + red[1] + red[2] + red[3] + bias[0];
}

// =========================== host launch ===========================
static inline void gemm(hipStream_t s, const float* A, const float* B, float* C,
                        int M, int N, int K, int shift, const float* bias,
                        const float* res, int flags, int splitz = 1)
{
  dim3 g((N + 63) / 64, (M + 63) / 64, splitz);
  gemm_f32<<<g, dim3(256), 0, s>>>(A, B, C, M, N, K, shift, bias, res, flags);
}

extern "C" void kernel_launch(void* const* d_in, const int* in_sizes, int n_in,
                              void* d_out, int out_size, void* d_ws, size_t ws_size,
                              hipStream_t stream)
{
  const float* x_enc  = (const float*)d_in[0];
  const float* conv1_w= (const float*)d_in[1];
  const float* conv1_b= (const float*)d_in[2];
  const float* conv2_w= (const float*)d_in[3];
  const float* conv2_b= (const float*)d_in[4];
  const float* cnn_g  = (const float*)d_in[5];
  const float* cnn_b  = (const float*)d_in[6];
  const float* proj_w = (const float*)d_in[7];
  const float* proj_b = (const float*)d_in[8];
  const float* pln_g  = (const float*)d_in[9];
  const float* pln_b  = (const float*)d_in[10];
  const float* Wq     = (const float*)d_in[11];
  const float* bq     = (const float*)d_in[12];
  const float* Wk     = (const float*)d_in[13];
  const float* bk     = (const float*)d_in[14];
  const float* Wv     = (const float*)d_in[15];
  const float* bv     = (const float*)d_in[16];
  const float* Wo     = (const float*)d_in[17];
  const float* bo     = (const float*)d_in[18];
  const float* Wff1   = (const float*)d_in[19];
  const float* Wff2   = (const float*)d_in[20];
  const float* rp1_w  = (const float*)d_in[21];
  const float* rp1_b  = (const float*)d_in[22];
  const float* rln_g  = (const float*)d_in[23];
  const float* rln_b  = (const float*)d_in[24];
  const float* rp2_w  = (const float*)d_in[25];
  const float* rp2_b  = (const float*)d_in[26];
  (void)in_sizes; (void)n_in;

  const size_t BLD = 64ull * 1024 * 256;
  size_t need;
  {
    size_t o = 3 * BLD
             + 98304 + 131072 + 131072 + 262144 + 262144   // CB2Tb,QKTH,QKTL,WFF1b,WFF2b (float-units)
             + 65536 + 512 + 1024                           // WVOTb, BVO, BQK
             + 65536 + 1280 + 1280 + 16384 + 49152 + 16384 + 16384;
    need = o * sizeof(float);
  }
  if (ws_size < need) {
    hipMemsetAsync(d_out, 0, (size_t)out_size * sizeof(float), stream);
    return;
  }

  float* ws = (float*)d_ws;
  size_t off = 0;
  auto alloc = [&](size_t n) { float* p = ws + off; off += n; return p; };
  float* BUF0 = alloc(BLD);   // conv1(bf16)/QKH/aggE(bf16)/xd/ffn-residual; WVO scratch at start
  float* BUF1 = alloc(BLD);   // conv2/QKL/x/ffn out
  float* BUF2 = alloc(BLD);   // enc / ffn hidden (bf16)
  short* CB2Tb = (short*)alloc(98304);
  short* QKTH  = (short*)alloc(131072);
  short* QKTL  = (short*)alloc(131072);
  short* WFF1b = (short*)alloc(262144);
  short* WFF2b = (short*)alloc(262144);
  short* WVOTb = (short*)alloc(65536);
  float* BVO  = alloc(512);
  float* BQK  = alloc(1024);
  float* MV   = alloc(65536);
  float* WTS  = alloc(1280);
  int*   DLY  = (int*)alloc(1280);
  float* PE   = alloc(16384);
  float* FIN  = alloc(49152);
  float* O1   = alloc(16384);
  float* O2   = alloc(16384);
  float* WVO  = BUF0;   // 2*65536 fp32 scratch, dead before conv1 writes BUF0

  const int M = 65536;
  dim3 blk(256);

  prep_weights<<<1024, blk, 0, stream>>>(conv2_w, Wq, Wk, Wff1, Wff2, bq, bk,
                                         CB2Tb, QKTH, QKTL, WFF1b, WFF2b, BQK);
  // W_vo = Wv @ Wo per layer (fp32), then transpose+bf16 + fused bias
  for (int i = 0; i < 2; i++)
    gemm(stream, Wv + (size_t)i * 65536, Wo + (size_t)i * 65536,
         WVO + (size_t)i * 65536, 256, 256, 256, 0, nullptr, nullptr, 0);
  vo_finish<<<516, blk, 0, stream>>>(WVO, Wo, bv, bo, WVOTb, BVO);

  // --- CNN frontend ---
  conv1_direct<<<dim3(16, 64), blk, 0, stream>>>(x_enc, conv1_w, conv1_b, (short*)BUF0);
  gemm_bf16_bt<<<dim3(2, 512), blk, 0, stream>>>(
      BUF0, CB2Tb, BUF1, nullptr, conv2_b, M, 256, 768, 256,
      FLAG_ABF16 | FLAG_RELU, 1);
  fixup_conv_b<<<128, blk, 0, stream>>>(BUF1, (const short*)BUF0, conv2_w, conv2_b);
  ln_rows4<<<16384, blk, 0, stream>>>(BUF1, BUF2, cnn_g, cnn_b, 0, 256, 0);

  // --- encoder layers (enc in BUF2) ---
  for (int i = 0; i < 2; i++) {
    short* QKH = (short*)BUF0;
    short* QKL = (short*)BUF1;
    gemm_qk<<<dim3(4, 512), blk, 0, stream>>>(
        BUF2, QKTH + (size_t)i * 131072, QKTL + (size_t)i * 131072,
        QKH, QKL, BQK + i * 512, M, 512, 256);
    hipMemsetAsync(MV, 0, 64 * 1024 * sizeof(float), stream);
    corr_mfma2<<<dim3(8, 8, 64), blk, 0, stream>>>(QKH, QKL, MV);
    topk_softmax_wave<<<64, dim3(64), 0, stream>>>(MV, WTS, DLY);
    // fused v+o: x = enc + agg(enc) @ W_vo + b_vo
    agg4e<<<dim3(256, 64), blk, 0, stream>>>(BUF2, WTS, DLY, (short*)BUF0);
    gemm_bf16_bt<<<dim3(2, 512), blk, 0, stream>>>(
        BUF0, WVOTb + (size_t)i * 65536, BUF1, BUF2, BVO + i * 256,
        M, 256, 256, 256, FLAG_ABF16, 0);
    decomp4<<<16384, blk, 0, stream>>>(BUF1, BUF0);   // xd -> BUF0 (fp32)
    // FFN: 2 chunks of 32768 rows; hidden bf16 in BUF2 (enc dead)
    for (int c = 0; c < 2; c++) {
      const float* xd = BUF0 + (size_t)c * 32768 * 256;
      gemm_bf16_bt<<<dim3(8, 256), blk, 0, stream>>>(
          xd, WFF1b + (size_t)i * 262144, BUF2, nullptr, nullptr,
          32768, 1024, 256, 256, FLAG_GELU | FLAG_OBF16, 0);
      gemm_bf16_bt<<<dim3(2, 256), blk, 0, stream>>>(
          BUF2, WFF2b + (size_t)i * 262144, BUF1 + (size_t)c * 32768 * 256, xd, nullptr,
          32768, 256, 1024, 1024, FLAG_ABF16, 0);
    }
    decomp4<<<16384, blk, 0, stream>>>(BUF1, BUF2);   // new enc -> BUF2
    pool_copy<<<64, blk, 0, stream>>>(BUF2, FIN, i * 256);
  }

  // --- head (fp32, exact) ---
  init_bias<<<64, blk, 0, stream>>>(PE, proj_b);
  gemm(stream, x_enc, proj_w, PE, 64, 256, 16384, 0, nullptr, nullptr, 0, 32);
  ln_rows4<<<16, blk, 0, stream>>>(PE, FIN, pln_g, pln_b, 1, 768, 512);
  init_bias<<<64, blk, 0, stream>>>(O1, rp1_b);
  gemm(stream, FIN, rp1_w, O1, 64, 256, 768, 0, nullptr, nullptr, 0, 4);
  ln_rows4<<<16, blk, 0, stream>>>(O1, O2, rln_g, rln_b, 1, 256, 0);
  rp2_kernel<<<64, blk, 0, stream>>>(O2, rp2_w, rp2_b, (float*)d_out);
}

// Round 10
// 1918.770 us; speedup vs baseline: 6.4527x; 1.0212x over previous
//
#include <hip/hip_runtime.h>
#include <math.h>

#define FLAG_ACC    1
#define FLAG_RELU   2
#define FLAG_GELU   4
#define FLAG_ABF16  8
#define FLAG_OBF16 16

typedef __attribute__((ext_vector_type(8))) short short8;
typedef __attribute__((ext_vector_type(4))) short short4v;
typedef __attribute__((ext_vector_type(4))) float f32x4;

__device__ __forceinline__ short f2bf(float f) {
  unsigned u = __builtin_bit_cast(unsigned, f);
  unsigned r = u + 0x7fffu + ((u >> 16) & 1u);
  return (short)(r >> 16);
}
__device__ __forceinline__ float bf2f(short s) {
  unsigned u = ((unsigned)(unsigned short)s) << 16;
  return __builtin_bit_cast(float, u);
}
// async global->LDS, 16B per lane; LDS dest = wave-uniform base + lane*16
__device__ __forceinline__ void load_lds16(const void* g, void* lds) {
  __builtin_amdgcn_global_load_lds(
      (const __attribute__((address_space(1))) void*)g,
      (__attribute__((address_space(3))) void*)lds, 16, 0, 0);
}

// ---------------- generic fp32 tiled GEMM (head + W_vo prep) ----------------
__global__ __launch_bounds__(256) void gemm_f32(
    const float* __restrict__ A, const float* __restrict__ B, float* __restrict__ C,
    int M, int N, int K, int a_shift,
    const float* __restrict__ bias, const float* __restrict__ residual, int flags)
{
  __shared__ float As[16][65];
  __shared__ float Bs[16][64];
  const int tid = threadIdx.x;
  const int tx = tid & 15, ty = tid >> 4;
  const int row0 = blockIdx.y * 64;
  const int col0 = blockIdx.x * 64;
  int kbeg = 0, kend = K;
  if ((int)gridDim.z > 1) {
    int kchunk = ((K + (int)gridDim.z - 1) / (int)gridDim.z + 15) & ~15;
    kbeg = (int)blockIdx.z * kchunk;
    kend = min(K, kbeg + kchunk);
  }
  float acc[4][4] = {};
  const int a_m = tid >> 2;
  const int a_k = (tid & 3) << 2;
  const int b_n = (tid & 15) << 2;
  const int b_k = tid >> 4;
  for (int k0 = kbeg; k0 < kend; k0 += 16) {
    int srow = row0 + a_m + a_shift;
    float4 av = make_float4(0.f, 0.f, 0.f, 0.f);
    if (srow >= 0 && srow < M)
      av = *reinterpret_cast<const float4*>(A + (long long)srow * K + (k0 + a_k));
    As[a_k + 0][a_m] = av.x; As[a_k + 1][a_m] = av.y;
    As[a_k + 2][a_m] = av.z; As[a_k + 3][a_m] = av.w;
    float4 bv = make_float4(0.f, 0.f, 0.f, 0.f);
    int brow = k0 + b_k;
    if (brow < K)
      bv = *reinterpret_cast<const float4*>(B + (long long)brow * N + (col0 + b_n));
    Bs[b_k][b_n + 0] = bv.x; Bs[b_k][b_n + 1] = bv.y;
    Bs[b_k][b_n + 2] = bv.z; Bs[b_k][b_n + 3] = bv.w;
    __syncthreads();
#pragma unroll
    for (int kk = 0; kk < 16; kk++) {
      float ar[4], br[4];
#pragma unroll
      for (int i = 0; i < 4; i++) ar[i] = As[kk][ty * 4 + i];
#pragma unroll
      for (int j = 0; j < 4; j++) br[j] = Bs[kk][tx * 4 + j];
#pragma unroll
      for (int i = 0; i < 4; i++)
#pragma unroll
        for (int j = 0; j < 4; j++)
          acc[i][j] += ar[i] * br[j];
    }
    __syncthreads();
  }
  if ((int)gridDim.z > 1) {
#pragma unroll
    for (int i = 0; i < 4; i++) {
      int r = row0 + ty * 4 + i; if (r >= M) continue;
#pragma unroll
      for (int j = 0; j < 4; j++) {
        int c = col0 + tx * 4 + j; if (c >= N) continue;
        atomicAdd(&C[(long long)r * N + c], acc[i][j]);
      }
    }
    return;
  }
#pragma unroll
  for (int i = 0; i < 4; i++) {
    int r = row0 + ty * 4 + i; if (r >= M) continue;
#pragma unroll
    for (int j = 0; j < 4; j++) {
      int c = col0 + tx * 4 + j; if (c >= N) continue;
      float v = acc[i][j];
      if (bias)     v += bias[c];
      if (residual) v += residual[(long long)r * N + c];
      if (flags & FLAG_ACC)  v += C[(long long)r * N + c];
      if (flags & FLAG_RELU) v = fmaxf(v, 0.f);
      if (flags & FLAG_GELU) v = 0.5f * v * (1.f + erff(v * 0.70710678118654752f));
      C[(long long)r * N + c] = v;
    }
  }
}

// ---------------- bf16 MFMA GEMM: C[M,N] = A[M,K] @ Btb[N,K]^T (B pre-bf16) --------
// XCD-aware axis order: blockIdx.x = ROW tile, blockIdx.y = COL tile. Same-row
// blocks are gridDim.x apart (multiple of 8) -> same XCD -> A-tile L2 reuse.
__global__ __launch_bounds__(256) void gemm_bf16_bt(
    const void* __restrict__ Av, const short* __restrict__ Btb, void* __restrict__ Cv,
    const float* __restrict__ residual, const float* __restrict__ bias,
    int M, int N, int K, int lda, int flags, int tapped)
{
  __shared__ __align__(16) short Asl[4096];   // 128 rows x 4 chunks x 8 shorts
  __shared__ __align__(16) short Bsl[4096];
  const int tid = threadIdx.x;
  const int row0 = blockIdx.x * 128;
  const int col0 = blockIdx.y * 128;
  const int lane = tid & 63;
  const int wave = tid >> 6;
  const int wm = (wave >> 1) * 64;
  const int wn = (wave & 1) * 64;
  const int fm = lane & 15;
  const int k8c = lane >> 4;
  const int mr = tid >> 1;          // manual staging row
  const int mkc = (tid & 1) * 2;    // manual staging chunk pair base
  const int msw = (mr >> 1) & 3;
  const bool a_dma = (flags & FLAG_ABF16) && !tapped;

  f32x4 acc[4][4] = {};
  for (int k0 = 0; k0 < K; k0 += 32) {
    __syncthreads();
#pragma unroll
    for (int u = 0; u < 2; u++) {           // B via DMA
      int p = (wave + u * 4) * 64 + lane;
      int r = p >> 2;
      int kc = (p & 3) ^ ((r >> 1) & 3);
      load_lds16(Btb + (long long)(col0 + r) * K + k0 + kc * 8,
                 (char*)Bsl + (wave + u * 4) * 1024);
    }
    if (a_dma) {
      const short* Ab = (const short*)Av;
#pragma unroll
      for (int u = 0; u < 2; u++) {
        int p = (wave + u * 4) * 64 + lane;
        int r = p >> 2;
        int kc = (p & 3) ^ ((r >> 1) & 3);
        load_lds16(Ab + (long long)(row0 + r) * lda + k0 + kc * 8,
                   (char*)Asl + (wave + u * 4) * 1024);
      }
    } else {
      int arow = row0 + mr + (tapped ? (k0 >> 8) - 1 : 0);
      int acol = tapped ? (k0 & 255) : k0;
      bool ok = (arow >= 0 && arow < M);
      short8 v0, v1;
      if (flags & FLAG_ABF16) {
        const short* ga = (const short*)Av + (long long)arow * lda + acol + mkc * 8;
        short8 z;
#pragma unroll
        for (int u = 0; u < 8; u++) z[u] = 0;
        v0 = ok ? *(const short8*)(ga) : z;
        v1 = ok ? *(const short8*)(ga + 8) : z;
      } else {
        const float* ga = (const float*)Av + (long long)arow * lda + acol + mkc * 8;
        float4 f0 = make_float4(0.f,0.f,0.f,0.f), f1 = f0, f2 = f0, f3 = f0;
        if (ok) {
          f0 = *(const float4*)(ga);     f1 = *(const float4*)(ga + 4);
          f2 = *(const float4*)(ga + 8); f3 = *(const float4*)(ga + 12);
        }
        v0[0]=f2bf(f0.x); v0[1]=f2bf(f0.y); v0[2]=f2bf(f0.z); v0[3]=f2bf(f0.w);
        v0[4]=f2bf(f1.x); v0[5]=f2bf(f1.y); v0[6]=f2bf(f1.z); v0[7]=f2bf(f1.w);
        v1[0]=f2bf(f2.x); v1[1]=f2bf(f2.y); v1[2]=f2bf(f2.z); v1[3]=f2bf(f2.w);
        v1[4]=f2bf(f3.x); v1[5]=f2bf(f3.y); v1[6]=f2bf(f3.z); v1[7]=f2bf(f3.w);
      }
      *(short8*)&Asl[(mr * 4 + (mkc ^ msw)) * 8] = v0;
      *(short8*)&Asl[(mr * 4 + ((mkc + 1) ^ msw)) * 8] = v1;
    }
    __syncthreads();
    short8 af[4], bf[4];
#pragma unroll
    for (int i = 0; i < 4; i++) {
      int r = wm + i * 16 + fm;
      af[i] = *(short8*)&Asl[(r * 4 + (k8c ^ ((r >> 1) & 3))) * 8];
    }
#pragma unroll
    for (int j = 0; j < 4; j++) {
      int r = wn + j * 16 + fm;
      bf[j] = *(short8*)&Bsl[(r * 4 + (k8c ^ ((r >> 1) & 3))) * 8];
    }
#pragma unroll
    for (int i = 0; i < 4; i++)
#pragma unroll
      for (int j = 0; j < 4; j++)
        acc[i][j] = __builtin_amdgcn_mfma_f32_16x16x32_bf16(af[i], bf[j], acc[i][j], 0, 0, 0);
  }
#pragma unroll
  for (int i = 0; i < 4; i++) {
    const int mbase = row0 + wm + i * 16 + (lane >> 4) * 4;
#pragma unroll
    for (int j = 0; j < 4; j++) {
      const int n = col0 + wn + j * 16 + fm;
      const float bs = bias ? bias[n] : 0.f;
#pragma unroll
      for (int r = 0; r < 4; r++) {
        long long idx = (long long)(mbase + r) * N + n;
        float v = acc[i][j][r] + bs;
        if (residual) v += residual[idx];
        if (flags & FLAG_ACC)  v += ((const float*)Cv)[idx];
        if (flags & FLAG_RELU) v = fmaxf(v, 0.f);
        if (flags & FLAG_GELU) v = 0.5f * v * (1.f + erff(v * 0.70710678118654752f));
        if (flags & FLAG_OBF16) ((short*)Cv)[idx] = f2bf(v);
        else                    ((float*)Cv)[idx] = v;
      }
    }
  }
}

// ---------------- q+k fused bf16x3 GEMM, B pre-split+DMA, split-bf16 output --------
// XCD-aware axis order: blockIdx.x = ROW tile (512 of them), blockIdx.y = COL tile.
__global__ __launch_bounds__(256) void gemm_qk(
    const float* __restrict__ A, const short* __restrict__ Bth,
    const short* __restrict__ Btl,
    short* __restrict__ Ch, short* __restrict__ Cl,
    const float* __restrict__ bias, int M, int N, int K)
{
  __shared__ __align__(16) char smem[32768];
  short* Ahi = (short*)smem;
  short* Alo = (short*)(smem + 8192);
  short* Bhi = (short*)(smem + 16384);
  short* Blo = (short*)(smem + 24576);
  const int tid = threadIdx.x;
  const int row0 = blockIdx.x * 128;
  const int col0 = blockIdx.y * 128;
  const int lane = tid & 63;
  const int wave = tid >> 6;
  const int wm = (wave >> 1) * 64;
  const int wn = (wave & 1) * 64;
  const int fm = lane & 15;
  const int k8c = lane >> 4;
  const int mr = tid >> 1;
  const int mkc = (tid & 1) * 2;
  const int msw = (mr >> 1) & 3;

  f32x4 acc[4][4] = {};
  for (int k0 = 0; k0 < K; k0 += 32) {
    __syncthreads();
#pragma unroll
    for (int u = 0; u < 2; u++) {
      int p = (wave + u * 4) * 64 + lane;
      int r = p >> 2;
      int kc = (p & 3) ^ ((r >> 1) & 3);
      long long go = (long long)(col0 + r) * K + k0 + kc * 8;
      int lo = (wave + u * 4) * 1024;
      load_lds16(Bth + go, (char*)Bhi + lo);
      load_lds16(Btl + go, (char*)Blo + lo);
    }
    {
      const float* ga = A + (long long)(row0 + mr) * K + k0 + mkc * 8;
      float4 f0 = *(const float4*)(ga),     f1 = *(const float4*)(ga + 4);
      float4 f2 = *(const float4*)(ga + 8), f3 = *(const float4*)(ga + 12);
      short8 h0, l0, h1, l1;
      h0[0]=f2bf(f0.x); h0[1]=f2bf(f0.y); h0[2]=f2bf(f0.z); h0[3]=f2bf(f0.w);
      h0[4]=f2bf(f1.x); h0[5]=f2bf(f1.y); h0[6]=f2bf(f1.z); h0[7]=f2bf(f1.w);
      l0[0]=f2bf(f0.x-bf2f(h0[0])); l0[1]=f2bf(f0.y-bf2f(h0[1]));
      l0[2]=f2bf(f0.z-bf2f(h0[2])); l0[3]=f2bf(f0.w-bf2f(h0[3]));
      l0[4]=f2bf(f1.x-bf2f(h0[4])); l0[5]=f2bf(f1.y-bf2f(h0[5]));
      l0[6]=f2bf(f1.z-bf2f(h0[6])); l0[7]=f2bf(f1.w-bf2f(h0[7]));
      h1[0]=f2bf(f2.x); h1[1]=f2bf(f2.y); h1[2]=f2bf(f2.z); h1[3]=f2bf(f2.w);
      h1[4]=f2bf(f3.x); h1[5]=f2bf(f3.y); h1[6]=f2bf(f3.z); h1[7]=f2bf(f3.w);
      l1[0]=f2bf(f2.x-bf2f(h1[0])); l1[1]=f2bf(f2.y-bf2f(h1[1]));
      l1[2]=f2bf(f2.z-bf2f(h1[2])); l1[3]=f2bf(f2.w-bf2f(h1[3]));
      l1[4]=f2bf(f3.x-bf2f(h1[4])); l1[5]=f2bf(f3.y-bf2f(h1[5]));
      l1[6]=f2bf(f3.z-bf2f(h1[6])); l1[7]=f2bf(f3.w-bf2f(h1[7]));
      int p0 = (mr * 4 + (mkc ^ msw)) * 8;
      int p1 = (mr * 4 + ((mkc + 1) ^ msw)) * 8;
      *(short8*)&Ahi[p0] = h0; *(short8*)&Ahi[p1] = h1;
      *(short8*)&Alo[p0] = l0; *(short8*)&Alo[p1] = l1;
    }
    __syncthreads();
    short8 ah[4], al[4], bh[4], bl[4];
#pragma unroll
    for (int i = 0; i < 4; i++) {
      int r = wm + i * 16 + fm;
      int p = (r * 4 + (k8c ^ ((r >> 1) & 3))) * 8;
      ah[i] = *(short8*)&Ahi[p];
      al[i] = *(short8*)&Alo[p];
    }
#pragma unroll
    for (int j = 0; j < 4; j++) {
      int r = wn + j * 16 + fm;
      int p = (r * 4 + (k8c ^ ((r >> 1) & 3))) * 8;
      bh[j] = *(short8*)&Bhi[p];
      bl[j] = *(short8*)&Blo[p];
    }
#pragma unroll
    for (int i = 0; i < 4; i++)
#pragma unroll
      for (int j = 0; j < 4; j++) {
        acc[i][j] = __builtin_amdgcn_mfma_f32_16x16x32_bf16(ah[i], bh[j], acc[i][j], 0, 0, 0);
        acc[i][j] = __builtin_amdgcn_mfma_f32_16x16x32_bf16(ah[i], bl[j], acc[i][j], 0, 0, 0);
        acc[i][j] = __builtin_amdgcn_mfma_f32_16x16x32_bf16(al[i], bh[j], acc[i][j], 0, 0, 0);
      }
  }
#pragma unroll
  for (int i = 0; i < 4; i++) {
    const int mbase = row0 + wm + i * 16 + (lane >> 4) * 4;
#pragma unroll
    for (int j = 0; j < 4; j++) {
      const int n = col0 + wn + j * 16 + fm;
      const float bs = bias ? bias[n] : 0.f;
#pragma unroll
      for (int r = 0; r < 4; r++) {
        long long idx = (long long)(mbase + r) * N + n;
        float v = acc[i][j][r] + bs;
        short h = f2bf(v);
        short l = f2bf(v - bf2f(h));
        Ch[idx] = h; Cl[idx] = l;
      }
    }
  }
}

// ------------- circular-correlation mean: XCD-aware 1D grid --------------------
// id -> c=id&7 (XCD), b = c + 8*(id>>9), tile=(id>>3)&63. All 64 tiles of one b
// run on one XCD, temporally clustered; per-b working set 2 MB fits 4 MB L2.
__global__ __launch_bounds__(256) void corr_mfma2(
    const short* __restrict__ qkh, const short* __restrict__ qkl, float* __restrict__ mv)
{
  __shared__ __align__(16) char smem[65536];
  short* Ahi = (short*)smem;
  short* Alo = (short*)(smem + 8192);
  short* Bhi = (short*)(smem + 16384);
  short* Blo = (short*)(smem + 24576);
  float* Sf = (float*)smem;

  const int id = blockIdx.x;
  const int b  = (id & 7) + 8 * (id >> 9);
  const int tile = (id >> 3) & 63;
  const int t0 = (tile >> 3) * 128;
  const int s0 = (tile & 7) * 128;
  const int tid = threadIdx.x;
  const int lane = tid & 63;
  const int wave = tid >> 6;
  const int wm = (wave >> 1) * 64;
  const int wn = (wave & 1) * 64;
  const int fm = lane & 15;
  const int k8c = lane >> 4;
  const long long bb = (long long)b * 524288;

  f32x4 acc[4][4] = {};
  for (int k0 = 0; k0 < 256; k0 += 32) {
    __syncthreads();
#pragma unroll
    for (int u = 0; u < 2; u++) {
      int p = (wave + u * 4) * 64 + lane;
      int r = p >> 2;
      int kc = (p & 3) ^ ((r >> 1) & 3);
      long long qo = bb + (long long)(t0 + r) * 512 + k0 + kc * 8;
      long long ko = bb + (long long)(s0 + r) * 512 + 256 + k0 + kc * 8;
      int lo = (wave + u * 4) * 1024;
      load_lds16(qkh + qo, (char*)Ahi + lo);
      load_lds16(qkl + qo, (char*)Alo + lo);
      load_lds16(qkh + ko, (char*)Bhi + lo);
      load_lds16(qkl + ko, (char*)Blo + lo);
    }
    __syncthreads();
    short8 ah[4], al[4], bh[4], bl[4];
#pragma unroll
    for (int i = 0; i < 4; i++) {
      int r = wm + i * 16 + fm;
      int p = (r * 4 + (k8c ^ ((r >> 1) & 3))) * 8;
      ah[i] = *(short8*)&Ahi[p];
      al[i] = *(short8*)&Alo[p];
    }
#pragma unroll
    for (int j = 0; j < 4; j++) {
      int r = wn + j * 16 + fm;
      int p = (r * 4 + (k8c ^ ((r >> 1) & 3))) * 8;
      bh[j] = *(short8*)&Bhi[p];
      bl[j] = *(short8*)&Blo[p];
    }
#pragma unroll
    for (int i = 0; i < 4; i++)
#pragma unroll
      for (int j = 0; j < 4; j++) {
        acc[i][j] = __builtin_amdgcn_mfma_f32_16x16x32_bf16(ah[i], bh[j], acc[i][j], 0, 0, 0);
        acc[i][j] = __builtin_amdgcn_mfma_f32_16x16x32_bf16(ah[i], bl[j], acc[i][j], 0, 0, 0);
        acc[i][j] = __builtin_amdgcn_mfma_f32_16x16x32_bf16(al[i], bh[j], acc[i][j], 0, 0, 0);
      }
  }
  __syncthreads();   // staging reads done; reuse LDS as skewed S
#pragma unroll
  for (int i = 0; i < 4; i++) {
    const int row = wm + i * 16 + (lane >> 4) * 4;
#pragma unroll
    for (int j = 0; j < 4; j++) {
      const int col = wn + j * 16 + fm;
#pragma unroll
      for (int r = 0; r < 4; r++)
        Sf[(row + r) * 128 + ((2 * (row + r) - col) & 127)] =
            acc[i][j][r] * (1.f / 256.f);
    }
  }
  __syncthreads();
  {
    const int dd = tid & 127;
    const int mb = (tid >> 7) * 64;
    float s_ge = 0.f, s_lt = 0.f;
    for (int mm = 0; mm < 64; mm++) {
      int m = mb + mm;
      float v = Sf[m * 128 + ((dd + m) & 127)];
      if (m >= dd) s_ge += v; else s_lt += v;
    }
    atomicAdd(&mv[b * 1024 + ((t0 - s0 + dd) & 1023)], s_ge);
    atomicAdd(&mv[b * 1024 + ((t0 - s0 + dd - 128) & 1023)], s_lt);
  }
}

// ------------- one-shot weight prep -------------
__global__ void prep_weights(
    const float* __restrict__ conv2_w, const float* __restrict__ Wq,
    const float* __restrict__ Wk, const float* __restrict__ Wff1,
    const float* __restrict__ Wff2,
    const float* __restrict__ bq, const float* __restrict__ bk,
    short* __restrict__ CB2Tb, short* __restrict__ QKTH, short* __restrict__ QKTL,
    short* __restrict__ WFF1b, short* __restrict__ WFF2b, float* __restrict__ BQK)
{
  const int total = 196608 + 262144 + 524288 + 524288 + 1024;
  for (int idx = blockIdx.x * 256 + threadIdx.x; idx < total;
       idx += gridDim.x * 256) {
    int t = idx;
    if (t < 196608) {
      int o = t / 768, rem = t % 768, kk = rem >> 8, i = rem & 255;
      CB2Tb[t] = f2bf(conv2_w[(o * 256 + i) * 3 + kk]);
    } else if ((t -= 196608) < 262144) {
      int L = t >> 17, rem = t & 131071, r = rem >> 8, k = rem & 255;
      float val = (r < 256) ? Wq[L * 65536 + k * 256 + r]
                            : Wk[L * 65536 + k * 256 + (r - 256)];
      short h = f2bf(val);
      QKTH[t] = h;
      QKTL[t] = f2bf(val - bf2f(h));
    } else if ((t -= 262144) < 524288) {
      WFF1b[t] = f2bf(Wff1[t]);
    } else if ((t -= 524288) < 524288) {
      WFF2b[t] = f2bf(Wff2[t]);
    } else {
      t -= 524288;
      int L = t >> 9, j = t & 511;
      BQK[t] = (j < 256) ? bq[L * 256 + j] : bk[L * 256 + (j - 256)];
    }
  }
}

// ------------- W_vo finish: transpose+bf16 W_vo, fused bias b_vo -------------
__global__ void vo_finish(const float* __restrict__ WVO, const float* __restrict__ Wo,
                          const float* __restrict__ bv, const float* __restrict__ bo,
                          short* __restrict__ WVOTb, float* __restrict__ BVO)
{
  const int total = 131072 + 512;
  for (int idx = blockIdx.x * 256 + threadIdx.x; idx < total;
       idx += gridDim.x * 256) {
    if (idx < 131072) {
      int L = idx >> 16, rem = idx & 65535, n = rem >> 8, k = rem & 255;
      WVOTb[idx] = f2bf(WVO[L * 65536 + k * 256 + n]);
    } else {
      int j = idx - 131072;
      int L = j >> 8, n = j & 255;
      float acc = bo[L * 256 + n];
      for (int k = 0; k < 256; k++)
        acc += bv[L * 256 + k] * Wo[(long long)L * 65536 + k * 256 + n];
      BVO[j] = acc;
    }
  }
}

// ------------- conv1 direct -> bf16 out -------------
__global__ __launch_bounds__(256) void conv1_direct(
    const float* __restrict__ x, const float* __restrict__ w,
    const float* __restrict__ bias, short* __restrict__ out)
{
  __shared__ float xs[66][16];
  const int b = blockIdx.y, lg = blockIdx.x, tid = threadIdx.x;
  const int l0 = lg * 64;
  for (int idx = tid; idx < 1056; idx += 256) {
    int r = idx >> 4, c = idx & 15;
    int l = l0 + r - 1;
    xs[r][c] = (l >= 0 && l < 1024) ? x[((long long)b * 1024 + l) * 16 + c] : 0.f;
  }
  float wr[48];
#pragma unroll
  for (int u = 0; u < 48; u++) wr[u] = w[tid * 48 + u];
  const float bs = bias[tid];
  __syncthreads();
  for (int r = 0; r < 64; r++) {
    float acc = bs;
#pragma unroll
    for (int i = 0; i < 16; i++) {
      acc += xs[r + 0][i] * wr[i * 3 + 0];
      acc += xs[r + 1][i] * wr[i * 3 + 1];
      acc += xs[r + 2][i] * wr[i * 3 + 2];
    }
    out[((long long)b * 1024 + l0 + r) * 256 + tid] = f2bf(fmaxf(acc, 0.f));
  }
}

// ------------- conv2 batch-edge fixup (bf16 src rows) -------------
__global__ void fixup_conv_b(float* __restrict__ h, const short* __restrict__ src,
                             const float* __restrict__ w, const float* __restrict__ bias)
{
  int b = blockIdx.x >> 1;
  int l = (blockIdx.x & 1) ? 1023 : 0;
  int o = threadIdx.x;
  float acc = bias[o];
  for (int kk = 0; kk < 3; kk++) {
    int t = l + kk - 1;
    if (t < 0 || t > 1023) continue;
    const short* srow = src + ((long long)b * 1024 + t) * 256;
    const float* wrow = w + (long long)o * 256 * 3 + kk;
    for (int i = 0; i < 256; i++) acc += bf2f(srow[i]) * wrow[(long long)i * 3];
  }
  h[((long long)b * 1024 + l) * 256 + o] = fmaxf(acc, 0.f);
}

// ------------- LayerNorm, one wave per row, float4 -------------
__global__ __launch_bounds__(256) void ln_rows4(
    const float* __restrict__ in, float* __restrict__ out,
    const float* __restrict__ g, const float* __restrict__ b,
    int prerelu, int out_stride, int out_off)
{
  const int row = blockIdx.x * 4 + (threadIdx.x >> 6);
  const int lane = threadIdx.x & 63;
  float4 x = ((const float4*)(in + (long long)row * 256))[lane];
  if (prerelu) {
    x.x = fmaxf(x.x, 0.f); x.y = fmaxf(x.y, 0.f);
    x.z = fmaxf(x.z, 0.f); x.w = fmaxf(x.w, 0.f);
  }
  float s = x.x + x.y + x.z + x.w;
#pragma unroll
  for (int o = 32; o > 0; o >>= 1) s += __shfl_xor(s, o, 64);
  float mean = s * (1.f / 256.f);
  float4 d = make_float4(x.x - mean, x.y - mean, x.z - mean, x.w - mean);
  float s2 = d.x * d.x + d.y * d.y + d.z * d.z + d.w * d.w;
#pragma unroll
  for (int o = 32; o > 0; o >>= 1) s2 += __shfl_xor(s2, o, 64);
  float rsd = rsqrtf(s2 * (1.f / 256.f) + 1e-5f);
  float4 gg = ((const float4*)g)[lane];
  float4 bb = ((const float4*)b)[lane];
  float4 o4 = make_float4(d.x * rsd * gg.x + bb.x, d.y * rsd * gg.y + bb.y,
                          d.z * rsd * gg.z + bb.z, d.w * rsd * gg.w + bb.w);
  ((float4*)(out + (long long)row * out_stride + out_off))[lane] = o4;
}

// ------------- series_decomp, float4 -------------
__global__ void decomp4(const float* __restrict__ in, float* __restrict__ out)
{
  int g = blockIdx.x * 256 + threadIdx.x;
  int c4 = g & 63;
  int l  = (g >> 6) & 1023;
  int b  = g >> 16;
  const float4* base = (const float4*)(in + (long long)b * 262144);
  float4 s = make_float4(0.f, 0.f, 0.f, 0.f);
#pragma unroll
  for (int j = -12; j <= 12; j++) {
    int t = l + j;
    t = t < 0 ? 0 : (t > 1023 ? 1023 : t);
    float4 x = base[t * 64 + c4];
    s.x += x.x; s.y += x.y; s.z += x.z; s.w += x.w;
  }
  float4 x0 = base[l * 64 + c4];
  float4 o = make_float4(x0.x - s.x * (1.f / 25.f), x0.y - s.y * (1.f / 25.f),
                         x0.z - s.z * (1.f / 25.f), x0.w - s.w * (1.f / 25.f));
  ((float4*)(out + (long long)b * 262144))[l * 64 + c4] = o;
}

// ------------- top-20 + softmax, one wave per batch -------------
__global__ __launch_bounds__(64) void topk_softmax_wave(
    const float* __restrict__ mv, float* __restrict__ wts, int* __restrict__ dly)
{
  const int b = blockIdx.x, lane = threadIdx.x;
  float v[16];
#pragma unroll
  for (int j = 0; j < 16; j++) v[j] = mv[b * 1024 + lane + 64 * j];
  float selv = 0.f; int seli = 0;
  for (int it = 0; it < 20; it++) {
    float bv = -1e30f; int bi = 0x7fffffff;
#pragma unroll
    for (int j = 0; j < 16; j++) {
      float x = v[j]; int idx = lane + 64 * j;
      if (x > bv || (x == bv && idx < bi)) { bv = x; bi = idx; }
    }
#pragma unroll
    for (int off = 32; off > 0; off >>= 1) {
      float ov = __shfl_xor(bv, off, 64);
      int   oi = __shfl_xor(bi, off, 64);
      if (ov > bv || (ov == bv && oi < bi)) { bv = ov; bi = oi; }
    }
    if (lane == it) { selv = bv; seli = bi; }
    if ((bi & 63) == lane) v[bi >> 6] = -1e30f;
  }
  const float w0 = __shfl(selv, 0, 64);
  float e = (lane < 20) ? __expf(selv - w0) : 0.f;
  float s = e;
#pragma unroll
  for (int off = 32; off > 0; off >>= 1) s += __shfl_xor(s, off, 64);
  if (lane < 20) {
    wts[b * 20 + lane] = e / s;
    dly[b * 20 + lane] = seli;
  }
}

// ------------- delay aggregation on enc (fp32 in, bf16 out) -------------
__global__ void agg4e(const float* __restrict__ enc, const float* __restrict__ wts,
                      const int* __restrict__ dly, short* __restrict__ out)
{
  const int b = blockIdx.y;
  const int l = blockIdx.x * 4 + (threadIdx.x >> 6);
  const int c4 = threadIdx.x & 63;
  const float4* vb = (const float4*)(enc + (long long)b * 262144);
  float4 acc = make_float4(0.f, 0.f, 0.f, 0.f);
  for (int kk = 0; kk < 20; kk++) {
    int d = dly[b * 20 + kk];
    float w = wts[b * 20 + kk];
    float4 x = vb[((l + d) & 1023) * 64 + c4];
    acc.x += w * x.x; acc.y += w * x.y; acc.z += w * x.z; acc.w += w * x.w;
  }
  short4v o;
  o[0] = f2bf(acc.x); o[1] = f2bf(acc.y); o[2] = f2bf(acc.z); o[3] = f2bf(acc.w);
  ((short4v*)(out + (long long)b * 262144))[l * 64 + c4] = o;
}

// ------------- small helpers -------------
__global__ void pool_copy(const float* __restrict__ enc, float* __restrict__ fin, int off)
{
  int b = blockIdx.x, tid = threadIdx.x;
  fin[(long long)b * 768 + off + tid] = enc[((long long)b * 1024 + 1023) * 256 + tid];
}

__global__ void init_bias(float* __restrict__ C, const float* __restrict__ bias)
{
  C[(long long)blockIdx.x * 256 + threadIdx.x] = bias[threadIdx.x];
}

__global__ void rp2_kernel(const float* __restrict__ x, const float* __restrict__ w,
                           const float* __restrict__ bias, float* __restrict__ out)
{
  __shared__ float red[4];
  int b = blockIdx.x, tid = threadIdx.x;
  float p = x[b * 256 + tid] * w[tid];
#pragma unroll
  for (int o = 32; o > 0; o >>= 1) p += __shfl_down(p, o, 64);
  if ((tid & 63) == 0) red[tid >> 6] = p;
  __syncthreads();
  if (tid == 0) out[b] = red[0] + red[1] + red[2] + red[3] + bias[0];
}

// =========================== host launch ===========================
static inline void gemm(hipStream_t s, const float* A, const float* B, float* C,
                        int M, int N, int K, int shift, const float* bias,
                        const float* res, int flags, int splitz = 1)
{
  dim3 g((N + 63) / 64, (M + 63) / 64, splitz);
  gemm_f32<<<g, dim3(256), 0, s>>>(A, B, C, M, N, K, shift, bias, res, flags);
}

extern "C" void kernel_launch(void* const* d_in, const int* in_sizes, int n_in,
                              void* d_out, int out_size, void* d_ws, size_t ws_size,
                              hipStream_t stream)
{
  const float* x_enc  = (const float*)d_in[0];
  const float* conv1_w= (const float*)d_in[1];
  const float* conv1_b= (const float*)d_in[2];
  const float* conv2_w= (const float*)d_in[3];
  const float* conv2_b= (const float*)d_in[4];
  const float* cnn_g  = (const float*)d_in[5];
  const float* cnn_b  = (const float*)d_in[6];
  const float* proj_w = (const float*)d_in[7];
  const float* proj_b = (const float*)d_in[8];
  const float* pln_g  = (const float*)d_in[9];
  const float* pln_b  = (const float*)d_in[10];
  const float* Wq     = (const float*)d_in[11];
  const float* bq     = (const float*)d_in[12];
  const float* Wk     = (const float*)d_in[13];
  const float* bk     = (const float*)d_in[14];
  const float* Wv     = (const float*)d_in[15];
  const float* bv     = (const float*)d_in[16];
  const float* Wo     = (const float*)d_in[17];
  const float* bo     = (const float*)d_in[18];
  const float* Wff1   = (const float*)d_in[19];
  const float* Wff2   = (const float*)d_in[20];
  const float* rp1_w  = (const float*)d_in[21];
  const float* rp1_b  = (const float*)d_in[22];
  const float* rln_g  = (const float*)d_in[23];
  const float* rln_b  = (const float*)d_in[24];
  const float* rp2_w  = (const float*)d_in[25];
  const float* rp2_b  = (const float*)d_in[26];
  (void)in_sizes; (void)n_in;

  const size_t BLD = 64ull * 1024 * 256;
  size_t need;
  {
    size_t o = 3 * BLD
             + 98304 + 131072 + 131072 + 262144 + 262144
             + 65536 + 512 + 1024
             + 65536 + 1280 + 1280 + 16384 + 49152 + 16384 + 16384;
    need = o * sizeof(float);
  }
  if (ws_size < need) {
    hipMemsetAsync(d_out, 0, (size_t)out_size * sizeof(float), stream);
    return;
  }

  float* ws = (float*)d_ws;
  size_t off = 0;
  auto alloc = [&](size_t n) { float* p = ws + off; off += n; return p; };
  float* BUF0 = alloc(BLD);   // conv1(bf16)/QKH/aggE(bf16)/xd; WVO scratch at start
  float* BUF1 = alloc(BLD);   // conv2/QKL/x/ffn out
  float* BUF2 = alloc(BLD);   // enc / ffn hidden (bf16)
  short* CB2Tb = (short*)alloc(98304);
  short* QKTH  = (short*)alloc(131072);
  short* QKTL  = (short*)alloc(131072);
  short* WFF1b = (short*)alloc(262144);
  short* WFF2b = (short*)alloc(262144);
  short* WVOTb = (short*)alloc(65536);
  float* BVO  = alloc(512);
  float* BQK  = alloc(1024);
  float* MV   = alloc(65536);
  float* WTS  = alloc(1280);
  int*   DLY  = (int*)alloc(1280);
  float* PE   = alloc(16384);
  float* FIN  = alloc(49152);
  float* O1   = alloc(16384);
  float* O2   = alloc(16384);
  float* WVO  = BUF0;   // 2*65536 fp32 scratch, dead before conv1 writes BUF0

  const int M = 65536;
  dim3 blk(256);

  prep_weights<<<1024, blk, 0, stream>>>(conv2_w, Wq, Wk, Wff1, Wff2, bq, bk,
                                         CB2Tb, QKTH, QKTL, WFF1b, WFF2b, BQK);
  for (int i = 0; i < 2; i++)
    gemm(stream, Wv + (size_t)i * 65536, Wo + (size_t)i * 65536,
         WVO + (size_t)i * 65536, 256, 256, 256, 0, nullptr, nullptr, 0);
  vo_finish<<<516, blk, 0, stream>>>(WVO, Wo, bv, bo, WVOTb, BVO);

  // --- CNN frontend ---
  conv1_direct<<<dim3(16, 64), blk, 0, stream>>>(x_enc, conv1_w, conv1_b, (short*)BUF0);
  gemm_bf16_bt<<<dim3(512, 2), blk, 0, stream>>>(
      BUF0, CB2Tb, BUF1, nullptr, conv2_b, M, 256, 768, 256,
      FLAG_ABF16 | FLAG_RELU, 1);
  fixup_conv_b<<<128, blk, 0, stream>>>(BUF1, (const short*)BUF0, conv2_w, conv2_b);
  ln_rows4<<<16384, blk, 0, stream>>>(BUF1, BUF2, cnn_g, cnn_b, 0, 256, 0);

  // --- encoder layers (enc in BUF2) ---
  for (int i = 0; i < 2; i++) {
    short* QKH = (short*)BUF0;
    short* QKL = (short*)BUF1;
    gemm_qk<<<dim3(512, 4), blk, 0, stream>>>(
        BUF2, QKTH + (size_t)i * 131072, QKTL + (size_t)i * 131072,
        QKH, QKL, BQK + i * 512, M, 512, 256);
    hipMemsetAsync(MV, 0, 64 * 1024 * sizeof(float), stream);
    corr_mfma2<<<dim3(4096), blk, 0, stream>>>(QKH, QKL, MV);
    topk_softmax_wave<<<64, dim3(64), 0, stream>>>(MV, WTS, DLY);
    // fused v+o: x = enc + agg(enc) @ W_vo + b_vo
    agg4e<<<dim3(256, 64), blk, 0, stream>>>(BUF2, WTS, DLY, (short*)BUF0);
    gemm_bf16_bt<<<dim3(512, 2), blk, 0, stream>>>(
        BUF0, WVOTb + (size_t)i * 65536, BUF1, BUF2, BVO + i * 256,
        M, 256, 256, 256, FLAG_ABF16, 0);
    decomp4<<<16384, blk, 0, stream>>>(BUF1, BUF0);   // xd -> BUF0 (fp32)
    // FFN: 2 chunks of 32768 rows; hidden bf16 in BUF2 (enc dead)
    for (int c = 0; c < 2; c++) {
      const float* xd = BUF0 + (size_t)c * 32768 * 256;
      gemm_bf16_bt<<<dim3(256, 8), blk, 0, stream>>>(
          xd, WFF1b + (size_t)i * 262144, BUF2, nullptr, nullptr,
          32768, 1024, 256, 256, FLAG_GELU | FLAG_OBF16, 0);
      gemm_bf16_bt<<<dim3(256, 2), blk, 0, stream>>>(
          BUF2, WFF2b + (size_t)i * 262144, BUF1 + (size_t)c * 32768 * 256, xd, nullptr,
          32768, 256, 1024, 1024, FLAG_ABF16, 0);
    }
    decomp4<<<16384, blk, 0, stream>>>(BUF1, BUF2);   // new enc -> BUF2
    pool_copy<<<64, blk, 0, stream>>>(BUF2, FIN, i * 256);
  }

  // --- head (fp32, exact) ---
  init_bias<<<64, blk, 0, stream>>>(PE, proj_b);
  gemm(stream, x_enc, proj_w, PE, 64, 256, 16384, 0, nullptr, nullptr, 0, 32);
  ln_rows4<<<16, blk, 0, stream>>>(PE, FIN, pln_g, pln_b, 1, 768, 512);
  init_bias<<<64, blk, 0, stream>>>(O1, rp1_b);
  gemm(stream, FIN, rp1_w, O1, 64, 256, 768, 0, nullptr, nullptr, 0, 4);
  ln_rows4<<<16, blk, 0, stream>>>(O1, O2, rln_g, rln_b, 1, 256, 0);
  rp2_kernel<<<64, blk, 0, stream>>>(O2, rp2_w, rp2_b, (float*)d_out);
}

// Round 11
// 1729.259 us; speedup vs baseline: 7.1599x; 1.1096x over previous
//
#include <hip/hip_runtime.h>
#include <math.h>

#define FLAG_ACC     1
#define FLAG_RELU    2
#define FLAG_GELU    4
#define FLAG_ABF16   8
#define FLAG_OBF16  16
#define FLAG_RESB16 32

typedef __attribute__((ext_vector_type(8))) short short8;
typedef __attribute__((ext_vector_type(4))) short short4v;
typedef __attribute__((ext_vector_type(4))) float f32x4;

__device__ __forceinline__ short f2bf(float f) {
  unsigned u = __builtin_bit_cast(unsigned, f);
  unsigned r = u + 0x7fffu + ((u >> 16) & 1u);
  return (short)(r >> 16);
}
__device__ __forceinline__ float bf2f(short s) {
  unsigned u = ((unsigned)(unsigned short)s) << 16;
  return __builtin_bit_cast(float, u);
}
// async global->LDS, 16B per lane; LDS dest = wave-uniform base + lane*16
__device__ __forceinline__ void load_lds16(const void* g, void* lds) {
  __builtin_amdgcn_global_load_lds(
      (const __attribute__((address_space(1))) void*)g,
      (__attribute__((address_space(3))) void*)lds, 16, 0, 0);
}

// ---------------- generic fp32 tiled GEMM (head + W_vo prep) ----------------
__global__ __launch_bounds__(256) void gemm_f32(
    const float* __restrict__ A, const float* __restrict__ B, float* __restrict__ C,
    int M, int N, int K, int a_shift,
    const float* __restrict__ bias, const float* __restrict__ residual, int flags)
{
  __shared__ float As[16][65];
  __shared__ float Bs[16][64];
  const int tid = threadIdx.x;
  const int tx = tid & 15, ty = tid >> 4;
  const int row0 = blockIdx.y * 64;
  const int col0 = blockIdx.x * 64;
  int kbeg = 0, kend = K;
  if ((int)gridDim.z > 1) {
    int kchunk = ((K + (int)gridDim.z - 1) / (int)gridDim.z + 15) & ~15;
    kbeg = (int)blockIdx.z * kchunk;
    kend = min(K, kbeg + kchunk);
  }
  float acc[4][4] = {};
  const int a_m = tid >> 2;
  const int a_k = (tid & 3) << 2;
  const int b_n = (tid & 15) << 2;
  const int b_k = tid >> 4;
  for (int k0 = kbeg; k0 < kend; k0 += 16) {
    int srow = row0 + a_m + a_shift;
    float4 av = make_float4(0.f, 0.f, 0.f, 0.f);
    if (srow >= 0 && srow < M)
      av = *reinterpret_cast<const float4*>(A + (long long)srow * K + (k0 + a_k));
    As[a_k + 0][a_m] = av.x; As[a_k + 1][a_m] = av.y;
    As[a_k + 2][a_m] = av.z; As[a_k + 3][a_m] = av.w;
    float4 bv = make_float4(0.f, 0.f, 0.f, 0.f);
    int brow = k0 + b_k;
    if (brow < K)
      bv = *reinterpret_cast<const float4*>(B + (long long)brow * N + (col0 + b_n));
    Bs[b_k][b_n + 0] = bv.x; Bs[b_k][b_n + 1] = bv.y;
    Bs[b_k][b_n + 2] = bv.z; Bs[b_k][b_n + 3] = bv.w;
    __syncthreads();
#pragma unroll
    for (int kk = 0; kk < 16; kk++) {
      float ar[4], br[4];
#pragma unroll
      for (int i = 0; i < 4; i++) ar[i] = As[kk][ty * 4 + i];
#pragma unroll
      for (int j = 0; j < 4; j++) br[j] = Bs[kk][tx * 4 + j];
#pragma unroll
      for (int i = 0; i < 4; i++)
#pragma unroll
        for (int j = 0; j < 4; j++)
          acc[i][j] += ar[i] * br[j];
    }
    __syncthreads();
  }
  if ((int)gridDim.z > 1) {
#pragma unroll
    for (int i = 0; i < 4; i++) {
      int r = row0 + ty * 4 + i; if (r >= M) continue;
#pragma unroll
      for (int j = 0; j < 4; j++) {
        int c = col0 + tx * 4 + j; if (c >= N) continue;
        atomicAdd(&C[(long long)r * N + c], acc[i][j]);
      }
    }
    return;
  }
#pragma unroll
  for (int i = 0; i < 4; i++) {
    int r = row0 + ty * 4 + i; if (r >= M) continue;
#pragma unroll
    for (int j = 0; j < 4; j++) {
      int c = col0 + tx * 4 + j; if (c >= N) continue;
      float v = acc[i][j];
      if (bias)     v += bias[c];
      if (residual) v += residual[(long long)r * N + c];
      if (flags & FLAG_ACC)  v += C[(long long)r * N + c];
      if (flags & FLAG_RELU) v = fmaxf(v, 0.f);
      if (flags & FLAG_GELU) v = 0.5f * v * (1.f + erff(v * 0.70710678118654752f));
      C[(long long)r * N + c] = v;
    }
  }
}

// ---------------- bf16 MFMA GEMM: C[M,N] = A[M,K] @ Btb[N,K]^T (B pre-bf16) --------
// XCD-aware axis order: blockIdx.x = ROW tile, blockIdx.y = COL tile.
__global__ __launch_bounds__(256) void gemm_bf16_bt(
    const void* __restrict__ Av, const short* __restrict__ Btb, void* __restrict__ Cv,
    const float* __restrict__ residual, const float* __restrict__ bias,
    int M, int N, int K, int lda, int flags, int tapped)
{
  __shared__ __align__(16) short Asl[4096];   // 128 rows x 4 chunks x 8 shorts
  __shared__ __align__(16) short Bsl[4096];
  const int tid = threadIdx.x;
  const int row0 = blockIdx.x * 128;
  const int col0 = blockIdx.y * 128;
  const int lane = tid & 63;
  const int wave = tid >> 6;
  const int wm = (wave >> 1) * 64;
  const int wn = (wave & 1) * 64;
  const int fm = lane & 15;
  const int k8c = lane >> 4;
  const int mr = tid >> 1;          // manual staging row
  const int mkc = (tid & 1) * 2;    // manual staging chunk pair base
  const int msw = (mr >> 1) & 3;
  const bool a_dma = (flags & FLAG_ABF16) && !tapped;

  f32x4 acc[4][4] = {};
  for (int k0 = 0; k0 < K; k0 += 32) {
    __syncthreads();
#pragma unroll
    for (int u = 0; u < 2; u++) {           // B via DMA
      int p = (wave + u * 4) * 64 + lane;
      int r = p >> 2;
      int kc = (p & 3) ^ ((r >> 1) & 3);
      load_lds16(Btb + (long long)(col0 + r) * K + k0 + kc * 8,
                 (char*)Bsl + (wave + u * 4) * 1024);
    }
    if (a_dma) {
      const short* Ab = (const short*)Av;
#pragma unroll
      for (int u = 0; u < 2; u++) {
        int p = (wave + u * 4) * 64 + lane;
        int r = p >> 2;
        int kc = (p & 3) ^ ((r >> 1) & 3);
        load_lds16(Ab + (long long)(row0 + r) * lda + k0 + kc * 8,
                   (char*)Asl + (wave + u * 4) * 1024);
      }
    } else {
      int arow = row0 + mr + (tapped ? (k0 >> 8) - 1 : 0);
      int acol = tapped ? (k0 & 255) : k0;
      bool ok = (arow >= 0 && arow < M);
      short8 v0, v1;
      if (flags & FLAG_ABF16) {
        const short* ga = (const short*)Av + (long long)arow * lda + acol + mkc * 8;
        short8 z;
#pragma unroll
        for (int u = 0; u < 8; u++) z[u] = 0;
        v0 = ok ? *(const short8*)(ga) : z;
        v1 = ok ? *(const short8*)(ga + 8) : z;
      } else {
        const float* ga = (const float*)Av + (long long)arow * lda + acol + mkc * 8;
        float4 f0 = make_float4(0.f,0.f,0.f,0.f), f1 = f0, f2 = f0, f3 = f0;
        if (ok) {
          f0 = *(const float4*)(ga);     f1 = *(const float4*)(ga + 4);
          f2 = *(const float4*)(ga + 8); f3 = *(const float4*)(ga + 12);
        }
        v0[0]=f2bf(f0.x); v0[1]=f2bf(f0.y); v0[2]=f2bf(f0.z); v0[3]=f2bf(f0.w);
        v0[4]=f2bf(f1.x); v0[5]=f2bf(f1.y); v0[6]=f2bf(f1.z); v0[7]=f2bf(f1.w);
        v1[0]=f2bf(f2.x); v1[1]=f2bf(f2.y); v1[2]=f2bf(f2.z); v1[3]=f2bf(f2.w);
        v1[4]=f2bf(f3.x); v1[5]=f2bf(f3.y); v1[6]=f2bf(f3.z); v1[7]=f2bf(f3.w);
      }
      *(short8*)&Asl[(mr * 4 + (mkc ^ msw)) * 8] = v0;
      *(short8*)&Asl[(mr * 4 + ((mkc + 1) ^ msw)) * 8] = v1;
    }
    __syncthreads();
    short8 af[4], bf[4];
#pragma unroll
    for (int i = 0; i < 4; i++) {
      int r = wm + i * 16 + fm;
      af[i] = *(short8*)&Asl[(r * 4 + (k8c ^ ((r >> 1) & 3))) * 8];
    }
#pragma unroll
    for (int j = 0; j < 4; j++) {
      int r = wn + j * 16 + fm;
      bf[j] = *(short8*)&Bsl[(r * 4 + (k8c ^ ((r >> 1) & 3))) * 8];
    }
#pragma unroll
    for (int i = 0; i < 4; i++)
#pragma unroll
      for (int j = 0; j < 4; j++)
        acc[i][j] = __builtin_amdgcn_mfma_f32_16x16x32_bf16(af[i], bf[j], acc[i][j], 0, 0, 0);
  }
#pragma unroll
  for (int i = 0; i < 4; i++) {
    const int mbase = row0 + wm + i * 16 + (lane >> 4) * 4;
#pragma unroll
    for (int j = 0; j < 4; j++) {
      const int n = col0 + wn + j * 16 + fm;
      const float bs = bias ? bias[n] : 0.f;
#pragma unroll
      for (int r = 0; r < 4; r++) {
        long long idx = (long long)(mbase + r) * N + n;
        float v = acc[i][j][r] + bs;
        if (residual) {
          if (flags & FLAG_RESB16) v += bf2f(((const short*)residual)[idx]);
          else                     v += residual[idx];
        }
        if (flags & FLAG_ACC)  v += ((const float*)Cv)[idx];
        if (flags & FLAG_RELU) v = fmaxf(v, 0.f);
        if (flags & FLAG_GELU) v = 0.5f * v * (1.f + erff(v * 0.70710678118654752f));
        if (flags & FLAG_OBF16) ((short*)Cv)[idx] = f2bf(v);
        else                    ((float*)Cv)[idx] = v;
      }
    }
  }
}

// ---------------- q+k fused bf16x3 GEMM, B pre-split+DMA, split-bf16 output --------
__global__ __launch_bounds__(256) void gemm_qk(
    const float* __restrict__ A, const short* __restrict__ Bth,
    const short* __restrict__ Btl,
    short* __restrict__ Ch, short* __restrict__ Cl,
    const float* __restrict__ bias, int M, int N, int K)
{
  __shared__ __align__(16) char smem[32768];
  short* Ahi = (short*)smem;
  short* Alo = (short*)(smem + 8192);
  short* Bhi = (short*)(smem + 16384);
  short* Blo = (short*)(smem + 24576);
  const int tid = threadIdx.x;
  const int row0 = blockIdx.x * 128;
  const int col0 = blockIdx.y * 128;
  const int lane = tid & 63;
  const int wave = tid >> 6;
  const int wm = (wave >> 1) * 64;
  const int wn = (wave & 1) * 64;
  const int fm = lane & 15;
  const int k8c = lane >> 4;
  const int mr = tid >> 1;
  const int mkc = (tid & 1) * 2;
  const int msw = (mr >> 1) & 3;

  f32x4 acc[4][4] = {};
  for (int k0 = 0; k0 < K; k0 += 32) {
    __syncthreads();
#pragma unroll
    for (int u = 0; u < 2; u++) {
      int p = (wave + u * 4) * 64 + lane;
      int r = p >> 2;
      int kc = (p & 3) ^ ((r >> 1) & 3);
      long long go = (long long)(col0 + r) * K + k0 + kc * 8;
      int lo = (wave + u * 4) * 1024;
      load_lds16(Bth + go, (char*)Bhi + lo);
      load_lds16(Btl + go, (char*)Blo + lo);
    }
    {
      const float* ga = A + (long long)(row0 + mr) * K + k0 + mkc * 8;
      float4 f0 = *(const float4*)(ga),     f1 = *(const float4*)(ga + 4);
      float4 f2 = *(const float4*)(ga + 8), f3 = *(const float4*)(ga + 12);
      short8 h0, l0, h1, l1;
      h0[0]=f2bf(f0.x); h0[1]=f2bf(f0.y); h0[2]=f2bf(f0.z); h0[3]=f2bf(f0.w);
      h0[4]=f2bf(f1.x); h0[5]=f2bf(f1.y); h0[6]=f2bf(f1.z); h0[7]=f2bf(f1.w);
      l0[0]=f2bf(f0.x-bf2f(h0[0])); l0[1]=f2bf(f0.y-bf2f(h0[1]));
      l0[2]=f2bf(f0.z-bf2f(h0[2])); l0[3]=f2bf(f0.w-bf2f(h0[3]));
      l0[4]=f2bf(f1.x-bf2f(h0[4])); l0[5]=f2bf(f1.y-bf2f(h0[5]));
      l0[6]=f2bf(f1.z-bf2f(h0[6])); l0[7]=f2bf(f1.w-bf2f(h0[7]));
      h1[0]=f2bf(f2.x); h1[1]=f2bf(f2.y); h1[2]=f2bf(f2.z); h1[3]=f2bf(f2.w);
      h1[4]=f2bf(f3.x); h1[5]=f2bf(f3.y); h1[6]=f2bf(f3.z); h1[7]=f2bf(f3.w);
      l1[0]=f2bf(f2.x-bf2f(h1[0])); l1[1]=f2bf(f2.y-bf2f(h1[1]));
      l1[2]=f2bf(f2.z-bf2f(h1[2])); l1[3]=f2bf(f2.w-bf2f(h1[3]));
      l1[4]=f2bf(f3.x-bf2f(h1[4])); l1[5]=f2bf(f3.y-bf2f(h1[5]));
      l1[6]=f2bf(f3.z-bf2f(h1[6])); l1[7]=f2bf(f3.w-bf2f(h1[7]));
      int p0 = (mr * 4 + (mkc ^ msw)) * 8;
      int p1 = (mr * 4 + ((mkc + 1) ^ msw)) * 8;
      *(short8*)&Ahi[p0] = h0; *(short8*)&Ahi[p1] = h1;
      *(short8*)&Alo[p0] = l0; *(short8*)&Alo[p1] = l1;
    }
    __syncthreads();
    short8 ah[4], al[4], bh[4], bl[4];
#pragma unroll
    for (int i = 0; i < 4; i++) {
      int r = wm + i * 16 + fm;
      int p = (r * 4 + (k8c ^ ((r >> 1) & 3))) * 8;
      ah[i] = *(short8*)&Ahi[p];
      al[i] = *(short8*)&Alo[p];
    }
#pragma unroll
    for (int j = 0; j < 4; j++) {
      int r = wn + j * 16 + fm;
      int p = (r * 4 + (k8c ^ ((r >> 1) & 3))) * 8;
      bh[j] = *(short8*)&Bhi[p];
      bl[j] = *(short8*)&Blo[p];
    }
#pragma unroll
    for (int i = 0; i < 4; i++)
#pragma unroll
      for (int j = 0; j < 4; j++) {
        acc[i][j] = __builtin_amdgcn_mfma_f32_16x16x32_bf16(ah[i], bh[j], acc[i][j], 0, 0, 0);
        acc[i][j] = __builtin_amdgcn_mfma_f32_16x16x32_bf16(ah[i], bl[j], acc[i][j], 0, 0, 0);
        acc[i][j] = __builtin_amdgcn_mfma_f32_16x16x32_bf16(al[i], bh[j], acc[i][j], 0, 0, 0);
      }
  }
#pragma unroll
  for (int i = 0; i < 4; i++) {
    const int mbase = row0 + wm + i * 16 + (lane >> 4) * 4;
#pragma unroll
    for (int j = 0; j < 4; j++) {
      const int n = col0 + wn + j * 16 + fm;
      const float bs = bias ? bias[n] : 0.f;
#pragma unroll
      for (int r = 0; r < 4; r++) {
        long long idx = (long long)(mbase + r) * N + n;
        float v = acc[i][j][r] + bs;
        short h = f2bf(v);
        short l = f2bf(v - bf2f(h));
        Ch[idx] = h; Cl[idx] = l;
      }
    }
  }
}

// ------------- circular-correlation mean: XCD-aware 1D grid --------------------
__global__ __launch_bounds__(256) void corr_mfma2(
    const short* __restrict__ qkh, const short* __restrict__ qkl, float* __restrict__ mv)
{
  __shared__ __align__(16) char smem[65536];
  short* Ahi = (short*)smem;
  short* Alo = (short*)(smem + 8192);
  short* Bhi = (short*)(smem + 16384);
  short* Blo = (short*)(smem + 24576);
  float* Sf = (float*)smem;

  const int id = blockIdx.x;
  const int b  = (id & 7) + 8 * (id >> 9);
  const int tile = (id >> 3) & 63;
  const int t0 = (tile >> 3) * 128;
  const int s0 = (tile & 7) * 128;
  const int tid = threadIdx.x;
  const int lane = tid & 63;
  const int wave = tid >> 6;
  const int wm = (wave >> 1) * 64;
  const int wn = (wave & 1) * 64;
  const int fm = lane & 15;
  const int k8c = lane >> 4;
  const long long bb = (long long)b * 524288;

  f32x4 acc[4][4] = {};
  for (int k0 = 0; k0 < 256; k0 += 32) {
    __syncthreads();
#pragma unroll
    for (int u = 0; u < 2; u++) {
      int p = (wave + u * 4) * 64 + lane;
      int r = p >> 2;
      int kc = (p & 3) ^ ((r >> 1) & 3);
      long long qo = bb + (long long)(t0 + r) * 512 + k0 + kc * 8;
      long long ko = bb + (long long)(s0 + r) * 512 + 256 + k0 + kc * 8;
      int lo = (wave + u * 4) * 1024;
      load_lds16(qkh + qo, (char*)Ahi + lo);
      load_lds16(qkl + qo, (char*)Alo + lo);
      load_lds16(qkh + ko, (char*)Bhi + lo);
      load_lds16(qkl + ko, (char*)Blo + lo);
    }
    __syncthreads();
    short8 ah[4], al[4], bh[4], bl[4];
#pragma unroll
    for (int i = 0; i < 4; i++) {
      int r = wm + i * 16 + fm;
      int p = (r * 4 + (k8c ^ ((r >> 1) & 3))) * 8;
      ah[i] = *(short8*)&Ahi[p];
      al[i] = *(short8*)&Alo[p];
    }
#pragma unroll
    for (int j = 0; j < 4; j++) {
      int r = wn + j * 16 + fm;
      int p = (r * 4 + (k8c ^ ((r >> 1) & 3))) * 8;
      bh[j] = *(short8*)&Bhi[p];
      bl[j] = *(short8*)&Blo[p];
    }
#pragma unroll
    for (int i = 0; i < 4; i++)
#pragma unroll
      for (int j = 0; j < 4; j++) {
        acc[i][j] = __builtin_amdgcn_mfma_f32_16x16x32_bf16(ah[i], bh[j], acc[i][j], 0, 0, 0);
        acc[i][j] = __builtin_amdgcn_mfma_f32_16x16x32_bf16(ah[i], bl[j], acc[i][j], 0, 0, 0);
        acc[i][j] = __builtin_amdgcn_mfma_f32_16x16x32_bf16(al[i], bh[j], acc[i][j], 0, 0, 0);
      }
  }
  __syncthreads();   // staging reads done; reuse LDS as skewed S
#pragma unroll
  for (int i = 0; i < 4; i++) {
    const int row = wm + i * 16 + (lane >> 4) * 4;
#pragma unroll
    for (int j = 0; j < 4; j++) {
      const int col = wn + j * 16 + fm;
#pragma unroll
      for (int r = 0; r < 4; r++)
        Sf[(row + r) * 128 + ((2 * (row + r) - col) & 127)] =
            acc[i][j][r] * (1.f / 256.f);
    }
  }
  __syncthreads();
  {
    const int dd = tid & 127;
    const int mb = (tid >> 7) * 64;
    float s_ge = 0.f, s_lt = 0.f;
    for (int mm = 0; mm < 64; mm++) {
      int m = mb + mm;
      float v = Sf[m * 128 + ((dd + m) & 127)];
      if (m >= dd) s_ge += v; else s_lt += v;
    }
    atomicAdd(&mv[b * 1024 + ((t0 - s0 + dd) & 1023)], s_ge);
    atomicAdd(&mv[b * 1024 + ((t0 - s0 + dd - 128) & 1023)], s_lt);
  }
}

// ------------- one-shot weight prep -------------
__global__ void prep_weights(
    const float* __restrict__ conv2_w, const float* __restrict__ Wq,
    const float* __restrict__ Wk, const float* __restrict__ Wff1,
    const float* __restrict__ Wff2,
    const float* __restrict__ bq, const float* __restrict__ bk,
    short* __restrict__ CB2Tb, short* __restrict__ QKTH, short* __restrict__ QKTL,
    short* __restrict__ WFF1b, short* __restrict__ WFF2b, float* __restrict__ BQK)
{
  const int total = 196608 + 262144 + 524288 + 524288 + 1024;
  for (int idx = blockIdx.x * 256 + threadIdx.x; idx < total;
       idx += gridDim.x * 256) {
    int t = idx;
    if (t < 196608) {
      int o = t / 768, rem = t % 768, kk = rem >> 8, i = rem & 255;
      CB2Tb[t] = f2bf(conv2_w[(o * 256 + i) * 3 + kk]);
    } else if ((t -= 196608) < 262144) {
      int L = t >> 17, rem = t & 131071, r = rem >> 8, k = rem & 255;
      float val = (r < 256) ? Wq[L * 65536 + k * 256 + r]
                            : Wk[L * 65536 + k * 256 + (r - 256)];
      short h = f2bf(val);
      QKTH[t] = h;
      QKTL[t] = f2bf(val - bf2f(h));
    } else if ((t -= 262144) < 524288) {
      WFF1b[t] = f2bf(Wff1[t]);
    } else if ((t -= 524288) < 524288) {
      WFF2b[t] = f2bf(Wff2[t]);
    } else {
      t -= 524288;
      int L = t >> 9, j = t & 511;
      BQK[t] = (j < 256) ? bq[L * 256 + j] : bk[L * 256 + (j - 256)];
    }
  }
}

// ------------- W_vo finish: transpose+bf16 W_vo, fused bias b_vo -------------
__global__ void vo_finish(const float* __restrict__ WVO, const float* __restrict__ Wo,
                          const float* __restrict__ bv, const float* __restrict__ bo,
                          short* __restrict__ WVOTb, float* __restrict__ BVO)
{
  const int total = 131072 + 512;
  for (int idx = blockIdx.x * 256 + threadIdx.x; idx < total;
       idx += gridDim.x * 256) {
    if (idx < 131072) {
      int L = idx >> 16, rem = idx & 65535, n = rem >> 8, k = rem & 255;
      WVOTb[idx] = f2bf(WVO[L * 65536 + k * 256 + n]);
    } else {
      int j = idx - 131072;
      int L = j >> 8, n = j & 255;
      float acc = bo[L * 256 + n];
      for (int k = 0; k < 256; k++)
        acc += bv[L * 256 + k] * Wo[(long long)L * 65536 + k * 256 + n];
      BVO[j] = acc;
    }
  }
}

// ------------- conv1 direct -> bf16 out -------------
__global__ __launch_bounds__(256) void conv1_direct(
    const float* __restrict__ x, const float* __restrict__ w,
    const float* __restrict__ bias, short* __restrict__ out)
{
  __shared__ float xs[66][16];
  const int b = blockIdx.y, lg = blockIdx.x, tid = threadIdx.x;
  const int l0 = lg * 64;
  for (int idx = tid; idx < 1056; idx += 256) {
    int r = idx >> 4, c = idx & 15;
    int l = l0 + r - 1;
    xs[r][c] = (l >= 0 && l < 1024) ? x[((long long)b * 1024 + l) * 16 + c] : 0.f;
  }
  float wr[48];
#pragma unroll
  for (int u = 0; u < 48; u++) wr[u] = w[tid * 48 + u];
  const float bs = bias[tid];
  __syncthreads();
  for (int r = 0; r < 64; r++) {
    float acc = bs;
#pragma unroll
    for (int i = 0; i < 16; i++) {
      acc += xs[r + 0][i] * wr[i * 3 + 0];
      acc += xs[r + 1][i] * wr[i * 3 + 1];
      acc += xs[r + 2][i] * wr[i * 3 + 2];
    }
    out[((long long)b * 1024 + l0 + r) * 256 + tid] = f2bf(fmaxf(acc, 0.f));
  }
}

// ------------- conv2 batch-edge fixup (bf16 src rows) -------------
__global__ void fixup_conv_b(float* __restrict__ h, const short* __restrict__ src,
                             const float* __restrict__ w, const float* __restrict__ bias)
{
  int b = blockIdx.x >> 1;
  int l = (blockIdx.x & 1) ? 1023 : 0;
  int o = threadIdx.x;
  float acc = bias[o];
  for (int kk = 0; kk < 3; kk++) {
    int t = l + kk - 1;
    if (t < 0 || t > 1023) continue;
    const short* srow = src + ((long long)b * 1024 + t) * 256;
    const float* wrow = w + (long long)o * 256 * 3 + kk;
    for (int i = 0; i < 256; i++) acc += bf2f(srow[i]) * wrow[(long long)i * 3];
  }
  h[((long long)b * 1024 + l) * 256 + o] = fmaxf(acc, 0.f);
}

// ------------- LayerNorm, one wave per row, float4 -------------
__global__ __launch_bounds__(256) void ln_rows4(
    const float* __restrict__ in, float* __restrict__ out,
    const float* __restrict__ g, const float* __restrict__ b,
    int prerelu, int out_stride, int out_off)
{
  const int row = blockIdx.x * 4 + (threadIdx.x >> 6);
  const int lane = threadIdx.x & 63;
  float4 x = ((const float4*)(in + (long long)row * 256))[lane];
  if (prerelu) {
    x.x = fmaxf(x.x, 0.f); x.y = fmaxf(x.y, 0.f);
    x.z = fmaxf(x.z, 0.f); x.w = fmaxf(x.w, 0.f);
  }
  float s = x.x + x.y + x.z + x.w;
#pragma unroll
  for (int o = 32; o > 0; o >>= 1) s += __shfl_xor(s, o, 64);
  float mean = s * (1.f / 256.f);
  float4 d = make_float4(x.x - mean, x.y - mean, x.z - mean, x.w - mean);
  float s2 = d.x * d.x + d.y * d.y + d.z * d.z + d.w * d.w;
#pragma unroll
  for (int o = 32; o > 0; o >>= 1) s2 += __shfl_xor(s2, o, 64);
  float rsd = rsqrtf(s2 * (1.f / 256.f) + 1e-5f);
  float4 gg = ((const float4*)g)[lane];
  float4 bb = ((const float4*)b)[lane];
  float4 o4 = make_float4(d.x * rsd * gg.x + bb.x, d.y * rsd * gg.y + bb.y,
                          d.z * rsd * gg.z + bb.z, d.w * rsd * gg.w + bb.w);
  ((float4*)(out + (long long)row * out_stride + out_off))[lane] = o4;
}

// ------------- series_decomp fp32->fp32, XCD-clustered 1D grid -------------
__global__ void decomp4(const float* __restrict__ in, float* __restrict__ out)
{
  const int id = blockIdx.x;
  const int c = id & 7;
  const int s = id >> 3;
  const int b = c + 8 * (s >> 8);
  const int lg = s & 255;
  const int l = lg * 4 + (threadIdx.x >> 6);
  const int c4 = threadIdx.x & 63;
  const float4* base = (const float4*)(in + (long long)b * 262144);
  float4 acc = make_float4(0.f, 0.f, 0.f, 0.f);
#pragma unroll
  for (int j = -12; j <= 12; j++) {
    int t = l + j;
    t = t < 0 ? 0 : (t > 1023 ? 1023 : t);
    float4 x = base[t * 64 + c4];
    acc.x += x.x; acc.y += x.y; acc.z += x.z; acc.w += x.w;
  }
  float4 x0 = base[l * 64 + c4];
  float4 o = make_float4(x0.x - acc.x * (1.f / 25.f), x0.y - acc.y * (1.f / 25.f),
                         x0.z - acc.z * (1.f / 25.f), x0.w - acc.w * (1.f / 25.f));
  ((float4*)(out + (long long)b * 262144))[l * 64 + c4] = o;
}

// ------------- series_decomp bf16->bf16, XCD-clustered 1D grid -------------
__global__ void decomp4b(const short* __restrict__ in, short* __restrict__ out)
{
  const int id = blockIdx.x;
  const int c = id & 7;
  const int s = id >> 3;
  const int b = c + 8 * (s >> 8);
  const int lg = s & 255;
  const int l = lg * 4 + (threadIdx.x >> 6);
  const int c4 = threadIdx.x & 63;
  const short4v* base = (const short4v*)(in + (long long)b * 262144);
  float4 acc = make_float4(0.f, 0.f, 0.f, 0.f);
#pragma unroll
  for (int j = -12; j <= 12; j++) {
    int t = l + j;
    t = t < 0 ? 0 : (t > 1023 ? 1023 : t);
    short4v x = base[t * 64 + c4];
    acc.x += bf2f(x[0]); acc.y += bf2f(x[1]);
    acc.z += bf2f(x[2]); acc.w += bf2f(x[3]);
  }
  short4v x0 = base[l * 64 + c4];
  short4v o;
  o[0] = f2bf(bf2f(x0[0]) - acc.x * (1.f / 25.f));
  o[1] = f2bf(bf2f(x0[1]) - acc.y * (1.f / 25.f));
  o[2] = f2bf(bf2f(x0[2]) - acc.z * (1.f / 25.f));
  o[3] = f2bf(bf2f(x0[3]) - acc.w * (1.f / 25.f));
  ((short4v*)(out + (long long)b * 262144))[l * 64 + c4] = o;
}

// ------------- top-20 + softmax, one wave per batch -------------
__global__ __launch_bounds__(64) void topk_softmax_wave(
    const float* __restrict__ mv, float* __restrict__ wts, int* __restrict__ dly)
{
  const int b = blockIdx.x, lane = threadIdx.x;
  float v[16];
#pragma unroll
  for (int j = 0; j < 16; j++) v[j] = mv[b * 1024 + lane + 64 * j];
  float selv = 0.f; int seli = 0;
  for (int it = 0; it < 20; it++) {
    float bv = -1e30f; int bi = 0x7fffffff;
#pragma unroll
    for (int j = 0; j < 16; j++) {
      float x = v[j]; int idx = lane + 64 * j;
      if (x > bv || (x == bv && idx < bi)) { bv = x; bi = idx; }
    }
#pragma unroll
    for (int off = 32; off > 0; off >>= 1) {
      float ov = __shfl_xor(bv, off, 64);
      int   oi = __shfl_xor(bi, off, 64);
      if (ov > bv || (ov == bv && oi < bi)) { bv = ov; bi = oi; }
    }
    if (lane == it) { selv = bv; seli = bi; }
    if ((bi & 63) == lane) v[bi >> 6] = -1e30f;
  }
  const float w0 = __shfl(selv, 0, 64);
  float e = (lane < 20) ? __expf(selv - w0) : 0.f;
  float s = e;
#pragma unroll
  for (int off = 32; off > 0; off >>= 1) s += __shfl_xor(s, off, 64);
  if (lane < 20) {
    wts[b * 20 + lane] = e / s;
    dly[b * 20 + lane] = seli;
  }
}

// ------------- delay aggregation on enc (fp32 in, bf16 out), XCD-clustered ---------
__global__ void agg4e(const float* __restrict__ enc, const float* __restrict__ wts,
                      const int* __restrict__ dly, short* __restrict__ out)
{
  const int id = blockIdx.x;
  const int c = id & 7;
  const int s = id >> 3;
  const int b = c + 8 * (s >> 8);
  const int lg = s & 255;
  const int l = lg * 4 + (threadIdx.x >> 6);
  const int c4 = threadIdx.x & 63;
  const float4* vb = (const float4*)(enc + (long long)b * 262144);
  float4 acc = make_float4(0.f, 0.f, 0.f, 0.f);
  for (int kk = 0; kk < 20; kk++) {
    int d = dly[b * 20 + kk];
    float w = wts[b * 20 + kk];
    float4 x = vb[((l + d) & 1023) * 64 + c4];
    acc.x += w * x.x; acc.y += w * x.y; acc.z += w * x.z; acc.w += w * x.w;
  }
  short4v o;
  o[0] = f2bf(acc.x); o[1] = f2bf(acc.y); o[2] = f2bf(acc.z); o[3] = f2bf(acc.w);
  ((short4v*)(out + (long long)b * 262144))[l * 64 + c4] = o;
}

// ------------- small helpers -------------
__global__ void pool_copy(const float* __restrict__ enc, float* __restrict__ fin, int off)
{
  int b = blockIdx.x, tid = threadIdx.x;
  fin[(long long)b * 768 + off + tid] = enc[((long long)b * 1024 + 1023) * 256 + tid];
}

__global__ void init_bias(float* __restrict__ C, const float* __restrict__ bias)
{
  C[(long long)blockIdx.x * 256 + threadIdx.x] = bias[threadIdx.x];
}

__global__ void rp2_kernel(const float* __restrict__ x, const float* __restrict__ w,
                           const float* __restrict__ bias, float* __restrict__ out)
{
  __shared__ float red[4];
  int b = blockIdx.x, tid = threadIdx.x;
  float p = x[b * 256 + tid] * w[tid];
#pragma unroll
  for (int o = 32; o > 0; o >>= 1) p += __shfl_down(p, o, 64);
  if ((tid & 63) == 0) red[tid >> 6] = p;
  __syncthreads();
  if (tid == 0) out[b] = red[0] + red[1] + red[2] + red[3] + bias[0];
}

// =========================== host launch ===========================
static inline void gemm(hipStream_t s, const float* A, const float* B, float* C,
                        int M, int N, int K, int shift, const float* bias,
                        const float* res, int flags, int splitz = 1)
{
  dim3 g((N + 63) / 64, (M + 63) / 64, splitz);
  gemm_f32<<<g, dim3(256), 0, s>>>(A, B, C, M, N, K, shift, bias, res, flags);
}

extern "C" void kernel_launch(void* const* d_in, const int* in_sizes, int n_in,
                              void* d_out, int out_size, void* d_ws, size_t ws_size,
                              hipStream_t stream)
{
  const float* x_enc  = (const float*)d_in[0];
  const float* conv1_w= (const float*)d_in[1];
  const float* conv1_b= (const float*)d_in[2];
  const float* conv2_w= (const float*)d_in[3];
  const float* conv2_b= (const float*)d_in[4];
  const float* cnn_g  = (const float*)d_in[5];
  const float* cnn_b  = (const float*)d_in[6];
  const float* proj_w = (const float*)d_in[7];
  const float* proj_b = (const float*)d_in[8];
  const float* pln_g  = (const float*)d_in[9];
  const float* pln_b  = (const float*)d_in[10];
  const float* Wq     = (const float*)d_in[11];
  const float* bq     = (const float*)d_in[12];
  const float* Wk     = (const float*)d_in[13];
  const float* bk     = (const float*)d_in[14];
  const float* Wv     = (const float*)d_in[15];
  const float* bv     = (const float*)d_in[16];
  const float* Wo     = (const float*)d_in[17];
  const float* bo     = (const float*)d_in[18];
  const float* Wff1   = (const float*)d_in[19];
  const float* Wff2   = (const float*)d_in[20];
  const float* rp1_w  = (const float*)d_in[21];
  const float* rp1_b  = (const float*)d_in[22];
  const float* rln_g  = (const float*)d_in[23];
  const float* rln_b  = (const float*)d_in[24];
  const float* rp2_w  = (const float*)d_in[25];
  const float* rp2_b  = (const float*)d_in[26];
  (void)in_sizes; (void)n_in;

  const size_t BLD = 64ull * 1024 * 256;
  size_t need;
  {
    size_t o = 3 * BLD
             + 98304 + 131072 + 131072 + 262144 + 262144
             + 65536 + 512 + 1024
             + 65536 + 1280 + 1280 + 16384 + 49152 + 16384 + 16384;
    need = o * sizeof(float);
  }
  if (ws_size < need) {
    hipMemsetAsync(d_out, 0, (size_t)out_size * sizeof(float), stream);
    return;
  }

  float* ws = (float*)d_ws;
  size_t off = 0;
  auto alloc = [&](size_t n) { float* p = ws + off; off += n; return p; };
  float* BUF0 = alloc(BLD);   // conv1(bf16)/QKH/aggE(bf16)/xd(bf16); WVO scratch
  float* BUF1 = alloc(BLD);   // conv2/QKL/x(bf16)/ffn out(fp32)
  float* BUF2 = alloc(BLD);   // enc(fp32) / ffn hidden (bf16)
  short* CB2Tb = (short*)alloc(98304);
  short* QKTH  = (short*)alloc(131072);
  short* QKTL  = (short*)alloc(131072);
  short* WFF1b = (short*)alloc(262144);
  short* WFF2b = (short*)alloc(262144);
  short* WVOTb = (short*)alloc(65536);
  float* BVO  = alloc(512);
  float* BQK  = alloc(1024);
  float* MV   = alloc(65536);
  float* WTS  = alloc(1280);
  int*   DLY  = (int*)alloc(1280);
  float* PE   = alloc(16384);
  float* FIN  = alloc(49152);
  float* O1   = alloc(16384);
  float* O2   = alloc(16384);
  float* WVO  = BUF0;   // 2*65536 fp32 scratch, dead before conv1 writes BUF0

  const int M = 65536;
  dim3 blk(256);

  prep_weights<<<1024, blk, 0, stream>>>(conv2_w, Wq, Wk, Wff1, Wff2, bq, bk,
                                         CB2Tb, QKTH, QKTL, WFF1b, WFF2b, BQK);
  for (int i = 0; i < 2; i++)
    gemm(stream, Wv + (size_t)i * 65536, Wo + (size_t)i * 65536,
         WVO + (size_t)i * 65536, 256, 256, 256, 0, nullptr, nullptr, 0);
  vo_finish<<<516, blk, 0, stream>>>(WVO, Wo, bv, bo, WVOTb, BVO);

  // --- CNN frontend ---
  conv1_direct<<<dim3(16, 64), blk, 0, stream>>>(x_enc, conv1_w, conv1_b, (short*)BUF0);
  gemm_bf16_bt<<<dim3(512, 2), blk, 0, stream>>>(
      BUF0, CB2Tb, BUF1, nullptr, conv2_b, M, 256, 768, 256,
      FLAG_ABF16 | FLAG_RELU, 1);
  fixup_conv_b<<<128, blk, 0, stream>>>(BUF1, (const short*)BUF0, conv2_w, conv2_b);
  ln_rows4<<<16384, blk, 0, stream>>>(BUF1, BUF2, cnn_g, cnn_b, 0, 256, 0);

  // --- encoder layers (enc fp32 in BUF2) ---
  for (int i = 0; i < 2; i++) {
    short* QKH = (short*)BUF0;
    short* QKL = (short*)BUF1;
    gemm_qk<<<dim3(512, 4), blk, 0, stream>>>(
        BUF2, QKTH + (size_t)i * 131072, QKTL + (size_t)i * 131072,
        QKH, QKL, BQK + i * 512, M, 512, 256);
    hipMemsetAsync(MV, 0, 64 * 1024 * sizeof(float), stream);
    corr_mfma2<<<dim3(4096), blk, 0, stream>>>(QKH, QKL, MV);
    topk_softmax_wave<<<64, dim3(64), 0, stream>>>(MV, WTS, DLY);
    // fused v+o: x = enc + agg(enc) @ W_vo + b_vo  (x stored bf16)
    agg4e<<<dim3(16384), blk, 0, stream>>>(BUF2, WTS, DLY, (short*)BUF0);
    gemm_bf16_bt<<<dim3(512, 2), blk, 0, stream>>>(
        BUF0, WVOTb + (size_t)i * 65536, BUF1, BUF2, BVO + i * 256,
        M, 256, 256, 256, FLAG_ABF16 | FLAG_OBF16, 0);
    decomp4b<<<16384, blk, 0, stream>>>((const short*)BUF1, (short*)BUF0); // xd bf16
    // FFN: 2 chunks of 32768 rows; hidden bf16 in BUF2 (enc dead); out fp32 BUF1
    for (int c = 0; c < 2; c++) {
      const short* xd = (const short*)BUF0 + (size_t)c * 32768 * 256;
      gemm_bf16_bt<<<dim3(256, 8), blk, 0, stream>>>(
          xd, WFF1b + (size_t)i * 262144, BUF2, nullptr, nullptr,
          32768, 1024, 256, 256, FLAG_ABF16 | FLAG_GELU | FLAG_OBF16, 0);
      gemm_bf16_bt<<<dim3(256, 2), blk, 0, stream>>>(
          BUF2, WFF2b + (size_t)i * 262144, BUF1 + (size_t)c * 32768 * 256,
          (const float*)xd, nullptr,
          32768, 256, 1024, 1024, FLAG_ABF16 | FLAG_RESB16, 0);
    }
    decomp4<<<16384, blk, 0, stream>>>(BUF1, BUF2);   // new enc (fp32) -> BUF2
    pool_copy<<<64, blk, 0, stream>>>(BUF2, FIN, i * 256);
  }

  // --- head (fp32, exact) ---
  init_bias<<<64, blk, 0, stream>>>(PE, proj_b);
  gemm(stream, x_enc, proj_w, PE, 64, 256, 16384, 0, nullptr, nullptr, 0, 32);
  ln_rows4<<<16, blk, 0, stream>>>(PE, FIN, pln_g, pln_b, 1, 768, 512);
  init_bias<<<64, blk, 0, stream>>>(O1, rp1_b);
  gemm(stream, FIN, rp1_w, O1, 64, 256, 768, 0, nullptr, nullptr, 0, 4);
  ln_rows4<<<16, blk, 0, stream>>>(O1, O2, rln_g, rln_b, 1, 256, 0);
  rp2_kernel<<<64, blk, 0, stream>>>(O2, rp2_w, rp2_b, (float*)d_out);
}